// Round 5
// baseline (794.205 us; speedup 1.0000x reference)
//
#include <hip/hip_runtime.h>
#include <hip/hip_bf16.h>
#include <math.h>

typedef unsigned short ushort_t;
typedef __attribute__((ext_vector_type(8))) short bfrag;   // 8 bf16 = 4 VGPRs
typedef __attribute__((ext_vector_type(4))) float ffrag;   // 4 fp32 acc

// ---------------- problem constants ----------------
constexpr int N_NODES = 100000;
constexpr int N_EDGES = 800000;
constexpr int NB      = 64;
constexpr int IN_F    = 256;
constexpr int HC1C    = 128;
constexpr int HC2C    = 32;
constexpr int SA_D    = 350;
constexpr float NEG   = 0.2f;

constexpr int SCAN_NBLK = (N_NODES + 255) / 256;  // 391
constexpr int MB128     = (N_NODES + 127) / 128;  // 782

// ---------------- workspace layout (float-sized slots) ----------------
constexpr size_t OFF_WT1    = 0;                                   // 2*(256*256) ush = 65536 f
constexpr size_t OFF_WT2    = OFF_WT1 + 65536;                     // 2*(128*128) ush = 16384 f
constexpr size_t OFF_WT3    = OFF_WT2 + 16384;                     // 2*(64*64) ush = 4096 f
constexpr size_t OFF_BC1    = OFF_WT3 + 4096;                      // 256
constexpr size_t OFF_BC2    = OFF_BC1 + 256;                       // 128
constexpr size_t OFF_BC3    = OFF_BC2 + 128;                       // 64
constexpr size_t OFF_XLR    = OFF_BC3 + 64;                        // N*256
constexpr size_t OFF_H      = OFF_XLR + (size_t)N_NODES * 256;     // N*128
constexpr size_t OFF_DEG    = OFF_H + (size_t)N_NODES * 128;       // N ints
constexpr size_t OFF_ROWPTR = OFF_DEG + N_NODES;                   // N+1 ints
constexpr size_t OFF_CURSOR = OFF_ROWPTR + N_NODES + 1;            // N ints
constexpr size_t OFF_BLKS   = OFF_CURSOR + N_NODES;                // 512 ints
constexpr size_t OFF_BLKO   = OFF_BLKS + 512;                      // 512 ints
constexpr size_t OFF_CSRSRC = OFF_BLKO + 512;                      // E ints
constexpr size_t OFF_POOLED = OFF_CSRSRC + N_EDGES;                // 64*32
constexpr size_t OFF_CNT    = OFF_POOLED + NB * HC2C;              // 64
constexpr size_t OFF_SX     = OFF_CNT + NB;                        // 64*32
constexpr size_t OFF_INFO   = OFF_SX + NB * HC2C;                  // 64*254
constexpr size_t OFF_T1     = OFF_INFO + (size_t)NB * (IN_F - 2);  // 128*64
constexpr size_t OFF_T2     = OFF_T1 + (size_t)HC1C * NB;          // 64*64
constexpr size_t OFF_TT     = OFF_T2 + (size_t)NB * NB;            // 64*32
constexpr size_t WS_FLOATS  = OFF_TT + NB * HC2C;

// ---------------- bf16 helpers ----------------
__device__ __forceinline__ ushort_t f2bf(float f) {  // RNE (prep kernels only)
  union { float f; unsigned int u; } a;
  a.f = f;
  unsigned int r = a.u + 0x7FFFu + ((a.u >> 16) & 1u);
  return (ushort_t)(r >> 16);
}
__device__ __forceinline__ float bf2f(ushort_t h) {
  union { unsigned int u; float f; } a;
  a.u = ((unsigned int)h) << 16;
  return a.f;
}
// Truncation split of 2 floats -> packed hi dword + packed lo dword (~3 ops/elem).
// hi = trunc16(v); lo = trunc16(v - hi).  hi*hi+hi*lo+lo*hi error ~2^-16 rel.
__device__ __forceinline__ void split2(float a, float b, unsigned int& hi, unsigned int& lo) {
  unsigned int ua = __float_as_uint(a), ub = __float_as_uint(b);
  float la = a - __uint_as_float(ua & 0xFFFF0000u);
  float lb = b - __uint_as_float(ub & 0xFFFF0000u);
  hi = __builtin_amdgcn_perm(ub, ua, 0x07060302u);
  lo = __builtin_amdgcn_perm(__float_as_uint(lb), __float_as_uint(la), 0x07060302u);
}

// ---------------- weight fold / pack (transposed, split hi/lo, RNE) ----------------
__global__ void k_wcomb(const float* __restrict__ Wv, const float* __restrict__ Wl1,
                        const float* __restrict__ Wr1, ushort_t* __restrict__ WT) {
  int t = blockIdx.x * blockDim.x + threadIdx.x;
  if (t >= 256 * 256) return;
  int n = t & 255;
  int k = t >> 8;
  const float* Wx = (n < 128) ? Wl1 : Wr1;
  int j = n & 127;
  float a = 0.f;
  for (int kk = 0; kk < SA_D; ++kk) a += Wv[k * SA_D + kk] * Wx[kk * 128 + j];
  ushort_t h = f2bf(a);
  WT[(size_t)n * 256 + k] = h;
  WT[65536 + (size_t)n * 256 + k] = f2bf(a - bf2f(h));
}

__global__ void k_bcomb(const float* __restrict__ bv, const float* __restrict__ Wl1,
                        const float* __restrict__ bl1, const float* __restrict__ Wr1,
                        const float* __restrict__ br1, float* __restrict__ bc) {
  int n = threadIdx.x;
  if (n >= 256) return;
  const float* Wx = (n < 128) ? Wl1 : Wr1;
  const float* bx = (n < 128) ? bl1 : br1;
  int j = n & 127;
  float a = bx[j];
  for (int kk = 0; kk < SA_D; ++kk) a += bv[kk] * Wx[kk * 128 + j];
  bc[n] = a;
}

template <int K, int C>
__global__ void k_wpack(const float* __restrict__ Wl, const float* __restrict__ bl,
                        const float* __restrict__ Wr, const float* __restrict__ br,
                        ushort_t* __restrict__ WT, float* __restrict__ bc) {
  constexpr int NN = 2 * C;
  int t = blockIdx.x * blockDim.x + threadIdx.x;
  if (t < NN) bc[t] = (t < C) ? bl[t] : br[t - C];
  if (t >= NN * K) return;
  int n = t % NN;
  int k = t / NN;
  float v = (n < C) ? Wl[k * C + n] : Wr[k * C + (n - C)];
  ushort_t h = f2bf(v);
  WT[(size_t)n * K + k] = h;
  WT[(size_t)NN * K + (size_t)n * K + k] = f2bf(v - bf2f(h));
}

// ---------------- CSR build ----------------
__global__ void k_hist(const int* __restrict__ dst, int* __restrict__ deg) {
  int e = blockIdx.x * blockDim.x + threadIdx.x;
  if (e < N_EDGES) atomicAdd(deg + dst[e], 1);
}

__global__ void k_scan_local(const int* __restrict__ deg, int* __restrict__ row_ptr,
                             int* __restrict__ blk_sum) {
  __shared__ int sh[256];
  int t = threadIdx.x;
  int i = blockIdx.x * 256 + t;
  int v = (i < N_NODES) ? deg[i] : 0;
  sh[t] = v;
  __syncthreads();
  for (int off = 1; off < 256; off <<= 1) {
    int add = (t >= off) ? sh[t - off] : 0;
    __syncthreads();
    sh[t] += add;
    __syncthreads();
  }
  if (i < N_NODES) row_ptr[i] = sh[t] - v;
  if (t == 255) blk_sum[blockIdx.x] = sh[255];
}

__global__ void k_scan_blk(const int* __restrict__ blk_sum, int* __restrict__ blk_off) {
  __shared__ int sh[512];
  int t = threadIdx.x;
  int v = (t < SCAN_NBLK) ? blk_sum[t] : 0;
  sh[t] = v;
  __syncthreads();
  for (int off = 1; off < 512; off <<= 1) {
    int add = (t >= off) ? sh[t - off] : 0;
    __syncthreads();
    sh[t] += add;
    __syncthreads();
  }
  blk_off[t] = sh[t] - v;
}

__global__ void k_scan_add(int* __restrict__ row_ptr, const int* __restrict__ blk_off,
                           int* __restrict__ cursor) {
  int i = blockIdx.x * blockDim.x + threadIdx.x;
  if (i < N_NODES) {
    int v = row_ptr[i] + blk_off[i >> 8];
    row_ptr[i] = v;
    cursor[i] = v;
  }
  if (i == 0) row_ptr[N_NODES] = N_EDGES;
}

__global__ void k_fill(const int* __restrict__ src, const int* __restrict__ dst,
                       int* __restrict__ cursor, int* __restrict__ csr_src) {
  int e = blockIdx.x * blockDim.x + threadIdx.x;
  if (e >= N_EDGES) return;
  int pos = atomicAdd(cursor + dst[e], 1);
  csr_src[pos] = src[e];
}

// ---------------- split-bf16 MFMA GEMM: out[m][NN] = x[m][K] @ W + bc ----------------
// BM=128 (4 waves x 2 row-tiles), BN=NN (full width: A converted once), BK=32.
// Each B fragment read from LDS is reused across 2 row-tiles -> LDS reads per
// MFMA drop ~2.3x vs the BM=64 version (which was LDS-throughput-bound at
// MfmaUtil 16%). A-split uses truncation+v_perm (~3 int-ops/elem).
template <int K, int NN>
__global__ __launch_bounds__(256) void k_gemm_mfma(const float* __restrict__ x,
                                                   const ushort_t* __restrict__ WT,
                                                   const float* __restrict__ bc,
                                                   float* __restrict__ out, int M) {
  constexpr int BM  = 128;
  constexpr int BK  = 32;
  constexpr int LDA = BK + 8;    // 80B row stride: 16B-aligned, <=2-way bank aliasing
  constexpr int NCT = NN / 16;
  __shared__ ushort_t As[2][BM * LDA];
  __shared__ ushort_t Bs[2][NN * LDA];
  const int tid  = threadIdx.x;
  const int wave = tid >> 6;
  const int lane = tid & 63;
  const int quad = lane >> 4;
  const int l16  = lane & 15;
  const int m0   = blockIdx.x * BM;

  ffrag acc[2][NCT];
#pragma unroll
  for (int rt = 0; rt < 2; ++rt)
#pragma unroll
    for (int i = 0; i < NCT; ++i) acc[rt][i] = ffrag{0.f, 0.f, 0.f, 0.f};

  for (int k0 = 0; k0 < K; k0 += BK) {
    __syncthreads();
    // stage A: 128 x 32 fp32 -> hi/lo bf16; thread owns 16 consecutive floats
    {
      int row = tid >> 1;
      int ks  = (tid & 1) * 16;
      int gm  = m0 + row;
      if (gm >= M) gm = M - 1;
      const float4* sp = (const float4*)(x + (size_t)gm * K + k0 + ks);
      float4 f0 = sp[0], f1 = sp[1], f2 = sp[2], f3 = sp[3];
      unsigned int hi[8], lo[8];
      split2(f0.x, f0.y, hi[0], lo[0]);
      split2(f0.z, f0.w, hi[1], lo[1]);
      split2(f1.x, f1.y, hi[2], lo[2]);
      split2(f1.z, f1.w, hi[3], lo[3]);
      split2(f2.x, f2.y, hi[4], lo[4]);
      split2(f2.z, f2.w, hi[5], lo[5]);
      split2(f3.x, f3.y, hi[6], lo[6]);
      split2(f3.z, f3.w, hi[7], lo[7]);
      *(uint4*)&As[0][row * LDA + ks]     = *(uint4*)&hi[0];
      *(uint4*)&As[0][row * LDA + ks + 8] = *(uint4*)&hi[4];
      *(uint4*)&As[1][row * LDA + ks]     = *(uint4*)&lo[0];
      *(uint4*)&As[1][row * LDA + ks + 8] = *(uint4*)&lo[4];
    }
    // stage B: NN x 32 hi/lo bf16 (16B copies)
#pragma unroll
    for (int i = tid; i < NN * 4; i += 256) {
      int n  = i >> 2;
      int ks = (i & 3) * 8;
      const ushort_t* gh = WT + (size_t)n * K + k0 + ks;
      *(bfrag*)&Bs[0][n * LDA + ks] = *(const bfrag*)gh;
      *(bfrag*)&Bs[1][n * LDA + ks] = *(const bfrag*)(gh + (size_t)NN * K);
    }
    __syncthreads();

    bfrag a_hi[2], a_lo[2];
#pragma unroll
    for (int rt = 0; rt < 2; ++rt) {
      int r = wave * 32 + rt * 16 + l16;
      a_hi[rt] = *(const bfrag*)&As[0][r * LDA + quad * 8];
      a_lo[rt] = *(const bfrag*)&As[1][r * LDA + quad * 8];
    }
#pragma unroll
    for (int ct = 0; ct < NCT; ++ct) {
      bfrag b_hi = *(const bfrag*)&Bs[0][(ct * 16 + l16) * LDA + quad * 8];
      bfrag b_lo = *(const bfrag*)&Bs[1][(ct * 16 + l16) * LDA + quad * 8];
#pragma unroll
      for (int rt = 0; rt < 2; ++rt) {
        acc[rt][ct] = __builtin_amdgcn_mfma_f32_16x16x32_bf16(a_hi[rt], b_hi, acc[rt][ct], 0, 0, 0);
        acc[rt][ct] = __builtin_amdgcn_mfma_f32_16x16x32_bf16(a_hi[rt], b_lo, acc[rt][ct], 0, 0, 0);
        acc[rt][ct] = __builtin_amdgcn_mfma_f32_16x16x32_bf16(a_lo[rt], b_hi, acc[rt][ct], 0, 0, 0);
      }
    }
  }

#pragma unroll
  for (int rt = 0; rt < 2; ++rt)
#pragma unroll
    for (int ct = 0; ct < NCT; ++ct) {
      int n = ct * 16 + l16;
      float b = bc[n];
#pragma unroll
      for (int r = 0; r < 4; ++r) {
        int m = m0 + wave * 32 + rt * 16 + quad * 4 + r;
        if (m < M) out[(size_t)m * NN + n] = acc[rt][ct][r] + b;
      }
    }
}

// ---------------- fused per-node GAT edge pass ----------------
template <int C>
__global__ void k_gat(const float* __restrict__ xlr, const int* __restrict__ row_ptr,
                      const int* __restrict__ csr_src, const float* __restrict__ att,
                      const float* __restrict__ bias, float* __restrict__ h) {
  constexpr int G = C / 4;
  constexpr int RS = 2 * C;
  int t = blockIdx.x * blockDim.x + threadIdx.x;
  int d = t / G;
  int lane = t - d * G;
  if (d >= N_NODES) return;
  const float4 xr = *(const float4*)(xlr + (size_t)d * RS + C + lane * 4);
  const float4 a4 = *(const float4*)(att + lane * 4);
  float4 acc = {0.f, 0.f, 0.f, 0.f};
  float den = 0.f;
  const int e0 = row_ptr[d], e1 = row_ptr[d + 1];
  for (int i = e0; i < e1; ++i) {
    int s = csr_src[i];
    float4 xl = *(const float4*)(xlr + (size_t)s * RS + lane * 4);
    float v, p = 0.f;
    v = xl.x + xr.x; v = v > 0.f ? v : NEG * v; p += a4.x * v;
    v = xl.y + xr.y; v = v > 0.f ? v : NEG * v; p += a4.y * v;
    v = xl.z + xr.z; v = v > 0.f ? v : NEG * v; p += a4.z * v;
    v = xl.w + xr.w; v = v > 0.f ? v : NEG * v; p += a4.w * v;
#pragma unroll
    for (int off = G / 2; off > 0; off >>= 1) p += __shfl_xor(p, off, 64);
    float ex = expf(p);
    den += ex;
    acc.x += ex * xl.x;
    acc.y += ex * xl.y;
    acc.z += ex * xl.z;
    acc.w += ex * xl.w;
  }
  float inv = 1.f / fmaxf(den, 1e-16f);
  const float4 b4 = *(const float4*)(bias + lane * 4);
  float4 o;
  o.x = fmaxf(acc.x * inv + b4.x, 0.f);
  o.y = fmaxf(acc.y * inv + b4.y, 0.f);
  o.z = fmaxf(acc.z * inv + b4.z, 0.f);
  o.w = fmaxf(acc.w * inv + b4.w, 0.f);
  *(float4*)(h + (size_t)d * C + lane * 4) = o;
}

// ---------------- pooling: sorted-batch run-accumulate ----------------
__global__ void k_pool(const float* __restrict__ h3, const int* __restrict__ batch,
                       float* __restrict__ pooled, float* __restrict__ cnt) {
  constexpr int NPB = 1024;
  constexpr int NPT = NPB / 8;
  int c = threadIdx.x & 31;
  int r = threadIdx.x >> 5;
  int base = blockIdx.x * NPB + r * NPT;
  if (base >= N_NODES) return;
  int end = base + NPT;
  if (end > N_NODES) end = N_NODES;
  int cur_b = batch[base];
  float acc = 0.f, count = 0.f;
  for (int n = base; n < end; ++n) {
    int b = batch[n];
    if (b != cur_b) {
      atomicAdd(pooled + cur_b * HC2C + c, acc);
      if (c == 0) atomicAdd(cnt + cur_b, count);
      cur_b = b;
      acc = 0.f;
      count = 0.f;
    }
    acc += h3[(size_t)n * HC2C + c];
    count += 1.f;
  }
  atomicAdd(pooled + cur_b * HC2C + c, acc);
  if (c == 0) atomicAdd(cnt + cur_b, count);
}

// ---------------- tail ----------------
__global__ void k_sx(const float* __restrict__ h3, const int* __restrict__ root,
                     const float* __restrict__ pooled, const float* __restrict__ cnt,
                     const float* __restrict__ linW, const float* __restrict__ linb,
                     float* __restrict__ sx) {
  int t = blockIdx.x * blockDim.x + threadIdx.x;
  if (t >= NB * HC2C) return;
  int b = t >> 5, j = t & 31;
  int r = root[b];
  float inv = 1.f / fmaxf(cnt[b], 1.0f);
  float a = linb[j];
  for (int c = 0; c < HC2C; ++c) a += h3[(size_t)r * HC2C + c] * linW[c * HC2C + j];
  for (int c = 0; c < HC2C; ++c) a += (pooled[b * HC2C + c] * inv) * linW[(HC2C + c) * HC2C + j];
  sx[t] = a > 0.f ? a : 0.f;
}

__global__ void k_info1(const float* __restrict__ X, const int* __restrict__ root,
                        const float* __restrict__ c1w, const float* __restrict__ c1b,
                        float* __restrict__ info) {
  constexpr int L = IN_F - 2;
  int t = blockIdx.x * blockDim.x + threadIdx.x;
  if (t >= NB * L) return;
  int b = t / L, i = t - (t / L) * L;
  const float* xr = X + (size_t)root[b] * IN_F;
  info[t] = c1w[0] * xr[i] + c1w[1] * xr[i + 1] + c1w[2] * xr[i + 2] + c1b[0];
}

__global__ void k_info2(const float* __restrict__ info, const float* __restrict__ c2W,
                        const float* __restrict__ c2b, float* __restrict__ t1) {
  constexpr int L = IN_F - 2;
  int t = blockIdx.x * blockDim.x + threadIdx.x;
  if (t >= HC1C * NB) return;
  int j = t >> 6, b = t & 63;
  float a = c2b[j];
  for (int i = 0; i < L; ++i) a += c2W[j * L + i] * info[b * L + i];
  t1[t] = a > 0.f ? a : 0.f;
}

__global__ void k_info3(const float* __restrict__ t1, const float* __restrict__ c3W,
                        const float* __restrict__ c3b, float* __restrict__ t2) {
  int t = blockIdx.x * blockDim.x + threadIdx.x;
  if (t >= NB * NB) return;
  int j = t >> 6, b = t & 63;
  float a = c3b[j];
  for (int i = 0; i < HC1C; ++i) a += c3W[j * HC1C + i] * t1[i * NB + b];
  t2[t] = a > 0.f ? a : 0.f;
}

__global__ void k_info4(const float* __restrict__ t2, float* __restrict__ tt) {
  int t = blockIdx.x * blockDim.x + threadIdx.x;
  if (t >= NB * HC2C) return;
  int b = t >> 5, c = t & 31;
  float v = 0.5f * (t2[(2 * c) * NB + b] + t2[(2 * c + 1) * NB + b]);
  tt[b * HC2C + c] = v > 0.f ? v : 0.f;
}

__global__ void k_final(const float* __restrict__ sx, const float* __restrict__ tt,
                        const float* __restrict__ aW1, const float* __restrict__ ab1,
                        const float* __restrict__ aW2, const float* __restrict__ mW1,
                        const float* __restrict__ mb1, const float* __restrict__ mW2,
                        const float* __restrict__ mb2, float* __restrict__ out) {
  int b = threadIdx.x;
  if (b >= NB) return;
  const float* e0 = sx + b * HC2C;
  const float* e1 = tt + b * HC2C;
  float w[2];
#pragma unroll
  for (int r = 0; r < 2; ++r) {
    const float* eb = (r == 0) ? e0 : e1;
    float acc = 0.f;
    for (int j = 0; j < 16; ++j) {
      float z = ab1[j];
      for (int c = 0; c < HC2C; ++c) z += eb[c] * aW1[c * 16 + j];
      acc += tanhf(z) * aW2[j];
    }
    w[r] = acc;
  }
  float mx = fmaxf(w[0], w[1]);
  float x0 = expf(w[0] - mx), x1 = expf(w[1] - mx);
  float inv = 1.f / (x0 + x1);
  float b0 = x0 * inv, b1 = x1 * inv;
  float t16[16];
  for (int j = 0; j < 16; ++j) {
    float z = mb1[j];
    for (int c = 0; c < HC2C; ++c) z += (b0 * e0[c] + b1 * e1[c]) * mW1[c * 16 + j];
    t16[j] = tanhf(z);
  }
  float l0 = mb2[0], l1 = mb2[1];
  for (int j = 0; j < 16; ++j) {
    l0 += t16[j] * mW2[j * 2 + 0];
    l1 += t16[j] * mW2[j * 2 + 1];
  }
  float m2 = fmaxf(l0, l1);
  float y0 = expf(l0 - m2), y1 = expf(l1 - m2);
  float is = 1.f / (y0 + y1);
  out[b * 2 + 0] = y0 * is;
  out[b * 2 + 1] = y1 * is;
}

// ---------------- launcher ----------------
extern "C" void kernel_launch(void* const* d_in, const int* in_sizes, int n_in, void* d_out,
                              int out_size, void* d_ws, size_t ws_size, hipStream_t stream) {
  if (ws_size < WS_FLOATS * sizeof(float)) return;

  const float* s_x   = (const float*)d_in[0];
  const int*   edge  = (const int*)d_in[1];
  const int*   batch = (const int*)d_in[2];
  const int*   root  = (const int*)d_in[3];
  const float* Wv    = (const float*)d_in[8];
  const float* bv    = (const float*)d_in[9];
  const float* Wl1   = (const float*)d_in[10];
  const float* bl1   = (const float*)d_in[11];
  const float* Wr1   = (const float*)d_in[12];
  const float* br1   = (const float*)d_in[13];
  const float* att1  = (const float*)d_in[14];
  const float* bias1 = (const float*)d_in[15];
  const float* Wl2   = (const float*)d_in[16];
  const float* bl2   = (const float*)d_in[17];
  const float* Wr2   = (const float*)d_in[18];
  const float* br2   = (const float*)d_in[19];
  const float* att2  = (const float*)d_in[20];
  const float* bias2 = (const float*)d_in[21];
  const float* Wl3   = (const float*)d_in[22];
  const float* bl3   = (const float*)d_in[23];
  const float* Wr3   = (const float*)d_in[24];
  const float* br3   = (const float*)d_in[25];
  const float* att3  = (const float*)d_in[26];
  const float* bias3 = (const float*)d_in[27];
  const float* c1w   = (const float*)d_in[28];
  const float* c1b   = (const float*)d_in[29];
  const float* c2W   = (const float*)d_in[30];
  const float* c2b   = (const float*)d_in[31];
  const float* c3W   = (const float*)d_in[32];
  const float* c3b   = (const float*)d_in[33];
  const float* linW  = (const float*)d_in[34];
  const float* linb  = (const float*)d_in[35];
  const float* aW1   = (const float*)d_in[36];
  const float* ab1   = (const float*)d_in[37];
  const float* aW2   = (const float*)d_in[38];
  const float* mW1   = (const float*)d_in[39];
  const float* mb1   = (const float*)d_in[40];
  const float* mW2   = (const float*)d_in[41];
  const float* mb2   = (const float*)d_in[42];

  const int* src = edge;
  const int* dst = edge + N_EDGES;

  float*    ws      = (float*)d_ws;
  ushort_t* WT1     = (ushort_t*)(ws + OFF_WT1);
  ushort_t* WT2     = (ushort_t*)(ws + OFF_WT2);
  ushort_t* WT3     = (ushort_t*)(ws + OFF_WT3);
  float*    bc1     = ws + OFF_BC1;
  float*    bc2     = ws + OFF_BC2;
  float*    bc3     = ws + OFF_BC3;
  float*    xlr     = ws + OFF_XLR;
  float*    hbuf    = ws + OFF_H;
  int*      deg     = (int*)(ws + OFF_DEG);
  int*      row_ptr = (int*)(ws + OFF_ROWPTR);
  int*      cursor  = (int*)(ws + OFF_CURSOR);
  int*      blks    = (int*)(ws + OFF_BLKS);
  int*      blko    = (int*)(ws + OFF_BLKO);
  int*      csr_src = (int*)(ws + OFF_CSRSRC);
  float*    pooled  = ws + OFF_POOLED;
  float*    cnt     = ws + OFF_CNT;
  float*    sx      = ws + OFF_SX;
  float*    info    = ws + OFF_INFO;
  float*    t1      = ws + OFF_T1;
  float*    t2      = ws + OFF_T2;
  float*    tt      = ws + OFF_TT;
  float*    out     = (float*)d_out;

  // ---- CSR build (by dst) ----
  hipMemsetAsync(deg, 0, N_NODES * sizeof(int), stream);
  k_hist<<<(N_EDGES + 255) / 256, 256, 0, stream>>>(dst, deg);
  k_scan_local<<<SCAN_NBLK, 256, 0, stream>>>(deg, row_ptr, blks);
  k_scan_blk<<<1, 512, 0, stream>>>(blks, blko);
  k_scan_add<<<SCAN_NBLK, 256, 0, stream>>>(row_ptr, blko, cursor);
  k_fill<<<(N_EDGES + 255) / 256, 256, 0, stream>>>(src, dst, cursor, csr_src);

  // ---- weight fold / pack ----
  k_wcomb<<<(256 * 256) / 256, 256, 0, stream>>>(Wv, Wl1, Wr1, WT1);
  k_bcomb<<<1, 256, 0, stream>>>(bv, Wl1, bl1, Wr1, br1, bc1);
  k_wpack<128, 64><<<(128 * 128 + 255) / 256, 256, 0, stream>>>(Wl2, bl2, Wr2, br2, WT2, bc2);
  k_wpack<64, 32><<<(64 * 64 + 255) / 256, 256, 0, stream>>>(Wl3, bl3, Wr3, br3, WT3, bc3);

  // ---- GAT layer 1 (K=256, N=256) ----
  k_gemm_mfma<256, 256><<<MB128, 256, 0, stream>>>(s_x, WT1, bc1, xlr, N_NODES);
  k_gat<128><<<(N_NODES * 32 + 255) / 256, 256, 0, stream>>>(xlr, row_ptr, csr_src, att1,
                                                             bias1, hbuf);

  // ---- GAT layer 2 (K=128, N=128) ----
  k_gemm_mfma<128, 128><<<MB128, 256, 0, stream>>>(hbuf, WT2, bc2, xlr, N_NODES);
  k_gat<64><<<(N_NODES * 16 + 255) / 256, 256, 0, stream>>>(xlr, row_ptr, csr_src, att2,
                                                            bias2, hbuf);

  // ---- GAT layer 3 (K=64, N=64) ----
  k_gemm_mfma<64, 64><<<MB128, 256, 0, stream>>>(hbuf, WT3, bc3, xlr, N_NODES);
  k_gat<32><<<(N_NODES * 8 + 255) / 256, 256, 0, stream>>>(xlr, row_ptr, csr_src, att3,
                                                           bias3, hbuf);

  // ---- pooling + root concat + lin ----
  hipMemsetAsync(pooled, 0, (NB * HC2C + NB) * sizeof(float), stream);
  k_pool<<<(N_NODES + 1023) / 1024, 256, 0, stream>>>(hbuf, batch, pooled, cnt);
  k_sx<<<(NB * HC2C + 255) / 256, 256, 0, stream>>>(hbuf, root, pooled, cnt, linW, linb, sx);

  // ---- info path ----
  k_info1<<<(NB * (IN_F - 2) + 255) / 256, 256, 0, stream>>>(s_x, root, c1w, c1b, info);
  k_info2<<<(HC1C * NB + 255) / 256, 256, 0, stream>>>(info, c2W, c2b, t1);
  k_info3<<<(NB * NB + 255) / 256, 256, 0, stream>>>(t1, c3W, c3b, t2);
  k_info4<<<(NB * HC2C + 255) / 256, 256, 0, stream>>>(t2, tt);

  // ---- attention combine + classifier ----
  k_final<<<1, NB, 0, stream>>>(sx, tt, aW1, ab1, aW2, mW1, mb1, mW2, mb2, out);
}

// Round 6
// 735.028 us; speedup vs baseline: 1.0805x; 1.0805x over previous
//
#include <hip/hip_runtime.h>
#include <hip/hip_bf16.h>
#include <math.h>

typedef unsigned short ushort_t;
typedef __attribute__((ext_vector_type(8))) short bfrag;   // 8 bf16 = 4 VGPRs
typedef __attribute__((ext_vector_type(4))) float ffrag;   // 4 fp32 acc

// ---------------- problem constants ----------------
constexpr int N_NODES = 100000;
constexpr int N_EDGES = 800000;
constexpr int NB      = 64;
constexpr int IN_F    = 256;
constexpr int HC1C    = 128;
constexpr int HC2C    = 32;
constexpr int SA_D    = 350;
constexpr float NEG   = 0.2f;

constexpr int SCAN_NBLK = (N_NODES + 255) / 256;  // 391
constexpr int MB128     = (N_NODES + 127) / 128;  // 782

// ---------------- workspace layout (float-sized slots) ----------------
constexpr size_t OFF_WT1    = 0;                                   // 2*(256*256) ush = 65536 f
constexpr size_t OFF_WT2    = OFF_WT1 + 65536;                     // 2*(128*128) ush = 16384 f
constexpr size_t OFF_WT3    = OFF_WT2 + 16384;                     // 2*(64*64) ush = 4096 f
constexpr size_t OFF_BC1    = OFF_WT3 + 4096;                      // 256
constexpr size_t OFF_BC2    = OFF_BC1 + 256;                       // 128
constexpr size_t OFF_BC3    = OFF_BC2 + 128;                       // 64
constexpr size_t OFF_XLR    = OFF_BC3 + 64;                        // N*256
constexpr size_t OFF_H      = OFF_XLR + (size_t)N_NODES * 256;     // N*128
constexpr size_t OFF_DEG    = OFF_H + (size_t)N_NODES * 128;       // N ints
constexpr size_t OFF_ROWPTR = OFF_DEG + N_NODES;                   // N+1 ints
constexpr size_t OFF_CURSOR = OFF_ROWPTR + N_NODES + 1;            // N ints
constexpr size_t OFF_BLKS   = OFF_CURSOR + N_NODES;                // 512 ints
constexpr size_t OFF_BLKO   = OFF_BLKS + 512;                      // 512 ints
constexpr size_t OFF_CSRSRC = OFF_BLKO + 512;                      // E ints
constexpr size_t OFF_POOLED = OFF_CSRSRC + N_EDGES;                // 64*32
constexpr size_t OFF_CNT    = OFF_POOLED + NB * HC2C;              // 64
constexpr size_t OFF_SX     = OFF_CNT + NB;                        // 64*32
constexpr size_t OFF_INFO   = OFF_SX + NB * HC2C;                  // 64*254
constexpr size_t OFF_T1     = OFF_INFO + (size_t)NB * (IN_F - 2);  // 128*64
constexpr size_t OFF_T2     = OFF_T1 + (size_t)HC1C * NB;          // 64*64
constexpr size_t OFF_TT     = OFF_T2 + (size_t)NB * NB;            // 64*32
constexpr size_t WS_FLOATS  = OFF_TT + NB * HC2C;

// ---------------- bf16 helpers ----------------
__device__ __forceinline__ ushort_t f2bf(float f) {  // RNE (prep kernels only)
  union { float f; unsigned int u; } a;
  a.f = f;
  unsigned int r = a.u + 0x7FFFu + ((a.u >> 16) & 1u);
  return (ushort_t)(r >> 16);
}
__device__ __forceinline__ float bf2f(ushort_t h) {
  union { unsigned int u; float f; } a;
  a.u = ((unsigned int)h) << 16;
  return a.f;
}
// Truncation split of 2 floats -> packed hi dword + packed lo dword (~3 ops/elem).
__device__ __forceinline__ void split2(float a, float b, unsigned int& hi, unsigned int& lo) {
  unsigned int ua = __float_as_uint(a), ub = __float_as_uint(b);
  float la = a - __uint_as_float(ua & 0xFFFF0000u);
  float lb = b - __uint_as_float(ub & 0xFFFF0000u);
  hi = __builtin_amdgcn_perm(ub, ua, 0x07060302u);
  lo = __builtin_amdgcn_perm(__float_as_uint(lb), __float_as_uint(la), 0x07060302u);
}

// ---------------- weight fold / pack (transposed, split hi/lo, RNE) ----------------
__global__ void k_wcomb(const float* __restrict__ Wv, const float* __restrict__ Wl1,
                        const float* __restrict__ Wr1, ushort_t* __restrict__ WT) {
  int t = blockIdx.x * blockDim.x + threadIdx.x;
  if (t >= 256 * 256) return;
  int n = t & 255;
  int k = t >> 8;
  const float* Wx = (n < 128) ? Wl1 : Wr1;
  int j = n & 127;
  float a = 0.f;
  for (int kk = 0; kk < SA_D; ++kk) a += Wv[k * SA_D + kk] * Wx[kk * 128 + j];
  ushort_t h = f2bf(a);
  WT[(size_t)n * 256 + k] = h;
  WT[65536 + (size_t)n * 256 + k] = f2bf(a - bf2f(h));
}

__global__ void k_bcomb(const float* __restrict__ bv, const float* __restrict__ Wl1,
                        const float* __restrict__ bl1, const float* __restrict__ Wr1,
                        const float* __restrict__ br1, float* __restrict__ bc) {
  int n = threadIdx.x;
  if (n >= 256) return;
  const float* Wx = (n < 128) ? Wl1 : Wr1;
  const float* bx = (n < 128) ? bl1 : br1;
  int j = n & 127;
  float a = bx[j];
  for (int kk = 0; kk < SA_D; ++kk) a += bv[kk] * Wx[kk * 128 + j];
  bc[n] = a;
}

template <int K, int C>
__global__ void k_wpack(const float* __restrict__ Wl, const float* __restrict__ bl,
                        const float* __restrict__ Wr, const float* __restrict__ br,
                        ushort_t* __restrict__ WT, float* __restrict__ bc) {
  constexpr int NN = 2 * C;
  int t = blockIdx.x * blockDim.x + threadIdx.x;
  if (t < NN) bc[t] = (t < C) ? bl[t] : br[t - C];
  if (t >= NN * K) return;
  int n = t % NN;
  int k = t / NN;
  float v = (n < C) ? Wl[k * C + n] : Wr[k * C + (n - C)];
  ushort_t h = f2bf(v);
  WT[(size_t)n * K + k] = h;
  WT[(size_t)NN * K + (size_t)n * K + k] = f2bf(v - bf2f(h));
}

// ---------------- CSR build ----------------
__global__ void k_hist(const int* __restrict__ dst, int* __restrict__ deg) {
  int e = blockIdx.x * blockDim.x + threadIdx.x;
  if (e < N_EDGES) atomicAdd(deg + dst[e], 1);
}

__global__ void k_scan_local(const int* __restrict__ deg, int* __restrict__ row_ptr,
                             int* __restrict__ blk_sum) {
  __shared__ int sh[256];
  int t = threadIdx.x;
  int i = blockIdx.x * 256 + t;
  int v = (i < N_NODES) ? deg[i] : 0;
  sh[t] = v;
  __syncthreads();
  for (int off = 1; off < 256; off <<= 1) {
    int add = (t >= off) ? sh[t - off] : 0;
    __syncthreads();
    sh[t] += add;
    __syncthreads();
  }
  if (i < N_NODES) row_ptr[i] = sh[t] - v;
  if (t == 255) blk_sum[blockIdx.x] = sh[255];
}

__global__ void k_scan_blk(const int* __restrict__ blk_sum, int* __restrict__ blk_off) {
  __shared__ int sh[512];
  int t = threadIdx.x;
  int v = (t < SCAN_NBLK) ? blk_sum[t] : 0;
  sh[t] = v;
  __syncthreads();
  for (int off = 1; off < 512; off <<= 1) {
    int add = (t >= off) ? sh[t - off] : 0;
    __syncthreads();
    sh[t] += add;
    __syncthreads();
  }
  blk_off[t] = sh[t] - v;
}

__global__ void k_scan_add(int* __restrict__ row_ptr, const int* __restrict__ blk_off,
                           int* __restrict__ cursor) {
  int i = blockIdx.x * blockDim.x + threadIdx.x;
  if (i < N_NODES) {
    int v = row_ptr[i] + blk_off[i >> 8];
    row_ptr[i] = v;
    cursor[i] = v;
  }
  if (i == 0) row_ptr[N_NODES] = N_EDGES;
}

__global__ void k_fill(const int* __restrict__ src, const int* __restrict__ dst,
                       int* __restrict__ cursor, int* __restrict__ csr_src) {
  int e = blockIdx.x * blockDim.x + threadIdx.x;
  if (e >= N_EDGES) return;
  int pos = atomicAdd(cursor + dst[e], 1);
  csr_src[pos] = src[e];
}

// ---------------- split-bf16 MFMA GEMM: out[m][NN] = x[m][K] @ W + bc ----------------
// Block: BM=128 x BN cols, 4 waves in a 2x2 grid. Wave: RT=4 row-tiles x CT=BN/32
// col-tiles -> acc[4][CT] (64 regs at CT=4, vs 128 in the failed BM=128xBN=256
// round-5 config that cratered occupancy to 1 wave/SIMD). Per wave/k-step at CT=4:
// 48 MFMA (~233 cyc) vs 16 ds_read_b128 (~192 cyc) -> MFMA-bound, ~150 regs,
// 40KB LDS -> ~12 waves/CU.
template <int K, int NN, int BN>
__global__ __launch_bounds__(256) void k_gemm_mfma(const float* __restrict__ x,
                                                   const ushort_t* __restrict__ WT,
                                                   const float* __restrict__ bc,
                                                   float* __restrict__ out, int M) {
  constexpr int BM  = 128;
  constexpr int BK  = 32;
  constexpr int LDA = BK + 8;    // 80B row stride: 16B-aligned, <=2-way bank aliasing
  constexpr int RT  = 4;         // row tiles per wave (2 wave-rows x 4 x 16 = 128)
  constexpr int CT  = BN / 32;   // col tiles per wave (2 wave-cols x CT x 16 = BN)
  __shared__ ushort_t As[2][BM * LDA];
  __shared__ ushort_t Bs[2][BN * LDA];
  const int tid  = threadIdx.x;
  const int wave = tid >> 6;
  const int wrow = wave >> 1;    // 0..1
  const int wcol = wave & 1;     // 0..1
  const int lane = tid & 63;
  const int quad = lane >> 4;
  const int l16  = lane & 15;
  const int m0   = blockIdx.x * BM;
  const int n0   = blockIdx.y * BN;

  ffrag acc[RT][CT];
#pragma unroll
  for (int rt = 0; rt < RT; ++rt)
#pragma unroll
    for (int ct = 0; ct < CT; ++ct) acc[rt][ct] = ffrag{0.f, 0.f, 0.f, 0.f};

  for (int k0 = 0; k0 < K; k0 += BK) {
    __syncthreads();
    // stage A: 128 x 32 fp32 -> hi/lo bf16; thread owns 16 consecutive floats
    {
      int row = tid >> 1;
      int ks  = (tid & 1) * 16;
      int gm  = m0 + row;
      if (gm >= M) gm = M - 1;
      const float4* sp = (const float4*)(x + (size_t)gm * K + k0 + ks);
      float4 f0 = sp[0], f1 = sp[1], f2 = sp[2], f3 = sp[3];
      unsigned int hi[8], lo[8];
      split2(f0.x, f0.y, hi[0], lo[0]);
      split2(f0.z, f0.w, hi[1], lo[1]);
      split2(f1.x, f1.y, hi[2], lo[2]);
      split2(f1.z, f1.w, hi[3], lo[3]);
      split2(f2.x, f2.y, hi[4], lo[4]);
      split2(f2.z, f2.w, hi[5], lo[5]);
      split2(f3.x, f3.y, hi[6], lo[6]);
      split2(f3.z, f3.w, hi[7], lo[7]);
      *(uint4*)&As[0][row * LDA + ks]     = *(uint4*)&hi[0];
      *(uint4*)&As[0][row * LDA + ks + 8] = *(uint4*)&hi[4];
      *(uint4*)&As[1][row * LDA + ks]     = *(uint4*)&lo[0];
      *(uint4*)&As[1][row * LDA + ks + 8] = *(uint4*)&lo[4];
    }
    // stage B: BN x 32 hi/lo bf16 (16B copies)
#pragma unroll
    for (int i = tid; i < BN * 4; i += 256) {
      int n  = i >> 2;
      int ks = (i & 3) * 8;
      const ushort_t* gh = WT + (size_t)(n0 + n) * K + k0 + ks;
      *(bfrag*)&Bs[0][n * LDA + ks] = *(const bfrag*)gh;
      *(bfrag*)&Bs[1][n * LDA + ks] = *(const bfrag*)(gh + (size_t)NN * K);
    }
    __syncthreads();

    bfrag a_hi[RT], a_lo[RT];
#pragma unroll
    for (int rt = 0; rt < RT; ++rt) {
      int r = wrow * 64 + rt * 16 + l16;
      a_hi[rt] = *(const bfrag*)&As[0][r * LDA + quad * 8];
      a_lo[rt] = *(const bfrag*)&As[1][r * LDA + quad * 8];
    }
#pragma unroll
    for (int ct = 0; ct < CT; ++ct) {
      int bn = wcol * (BN / 2) + ct * 16 + l16;
      bfrag b_hi = *(const bfrag*)&Bs[0][bn * LDA + quad * 8];
      bfrag b_lo = *(const bfrag*)&Bs[1][bn * LDA + quad * 8];
#pragma unroll
      for (int rt = 0; rt < RT; ++rt) {
        acc[rt][ct] = __builtin_amdgcn_mfma_f32_16x16x32_bf16(a_hi[rt], b_hi, acc[rt][ct], 0, 0, 0);
        acc[rt][ct] = __builtin_amdgcn_mfma_f32_16x16x32_bf16(a_hi[rt], b_lo, acc[rt][ct], 0, 0, 0);
        acc[rt][ct] = __builtin_amdgcn_mfma_f32_16x16x32_bf16(a_lo[rt], b_hi, acc[rt][ct], 0, 0, 0);
      }
    }
  }

#pragma unroll
  for (int rt = 0; rt < RT; ++rt)
#pragma unroll
    for (int ct = 0; ct < CT; ++ct) {
      int n = n0 + wcol * (BN / 2) + ct * 16 + l16;
      float b = bc[n];
#pragma unroll
      for (int r = 0; r < 4; ++r) {
        int m = m0 + wrow * 64 + rt * 16 + quad * 4 + r;
        if (m < M) out[(size_t)m * NN + n] = acc[rt][ct][r] + b;
      }
    }
}

// ---------------- fused per-node GAT edge pass ----------------
template <int C>
__global__ void k_gat(const float* __restrict__ xlr, const int* __restrict__ row_ptr,
                      const int* __restrict__ csr_src, const float* __restrict__ att,
                      const float* __restrict__ bias, float* __restrict__ h) {
  constexpr int G = C / 4;
  constexpr int RS = 2 * C;
  int t = blockIdx.x * blockDim.x + threadIdx.x;
  int d = t / G;
  int lane = t - d * G;
  if (d >= N_NODES) return;
  const float4 xr = *(const float4*)(xlr + (size_t)d * RS + C + lane * 4);
  const float4 a4 = *(const float4*)(att + lane * 4);
  float4 acc = {0.f, 0.f, 0.f, 0.f};
  float den = 0.f;
  const int e0 = row_ptr[d], e1 = row_ptr[d + 1];
  for (int i = e0; i < e1; ++i) {
    int s = csr_src[i];
    float4 xl = *(const float4*)(xlr + (size_t)s * RS + lane * 4);
    float v, p = 0.f;
    v = xl.x + xr.x; v = v > 0.f ? v : NEG * v; p += a4.x * v;
    v = xl.y + xr.y; v = v > 0.f ? v : NEG * v; p += a4.y * v;
    v = xl.z + xr.z; v = v > 0.f ? v : NEG * v; p += a4.z * v;
    v = xl.w + xr.w; v = v > 0.f ? v : NEG * v; p += a4.w * v;
#pragma unroll
    for (int off = G / 2; off > 0; off >>= 1) p += __shfl_xor(p, off, 64);
    float ex = expf(p);
    den += ex;
    acc.x += ex * xl.x;
    acc.y += ex * xl.y;
    acc.z += ex * xl.z;
    acc.w += ex * xl.w;
  }
  float inv = 1.f / fmaxf(den, 1e-16f);
  const float4 b4 = *(const float4*)(bias + lane * 4);
  float4 o;
  o.x = fmaxf(acc.x * inv + b4.x, 0.f);
  o.y = fmaxf(acc.y * inv + b4.y, 0.f);
  o.z = fmaxf(acc.z * inv + b4.z, 0.f);
  o.w = fmaxf(acc.w * inv + b4.w, 0.f);
  *(float4*)(h + (size_t)d * C + lane * 4) = o;
}

// ---------------- pooling: sorted-batch run-accumulate ----------------
__global__ void k_pool(const float* __restrict__ h3, const int* __restrict__ batch,
                       float* __restrict__ pooled, float* __restrict__ cnt) {
  constexpr int NPB = 1024;
  constexpr int NPT = NPB / 8;
  int c = threadIdx.x & 31;
  int r = threadIdx.x >> 5;
  int base = blockIdx.x * NPB + r * NPT;
  if (base >= N_NODES) return;
  int end = base + NPT;
  if (end > N_NODES) end = N_NODES;
  int cur_b = batch[base];
  float acc = 0.f, count = 0.f;
  for (int n = base; n < end; ++n) {
    int b = batch[n];
    if (b != cur_b) {
      atomicAdd(pooled + cur_b * HC2C + c, acc);
      if (c == 0) atomicAdd(cnt + cur_b, count);
      cur_b = b;
      acc = 0.f;
      count = 0.f;
    }
    acc += h3[(size_t)n * HC2C + c];
    count += 1.f;
  }
  atomicAdd(pooled + cur_b * HC2C + c, acc);
  if (c == 0) atomicAdd(cnt + cur_b, count);
}

// ---------------- tail ----------------
__global__ void k_sx(const float* __restrict__ h3, const int* __restrict__ root,
                     const float* __restrict__ pooled, const float* __restrict__ cnt,
                     const float* __restrict__ linW, const float* __restrict__ linb,
                     float* __restrict__ sx) {
  int t = blockIdx.x * blockDim.x + threadIdx.x;
  if (t >= NB * HC2C) return;
  int b = t >> 5, j = t & 31;
  int r = root[b];
  float inv = 1.f / fmaxf(cnt[b], 1.0f);
  float a = linb[j];
  for (int c = 0; c < HC2C; ++c) a += h3[(size_t)r * HC2C + c] * linW[c * HC2C + j];
  for (int c = 0; c < HC2C; ++c) a += (pooled[b * HC2C + c] * inv) * linW[(HC2C + c) * HC2C + j];
  sx[t] = a > 0.f ? a : 0.f;
}

__global__ void k_info1(const float* __restrict__ X, const int* __restrict__ root,
                        const float* __restrict__ c1w, const float* __restrict__ c1b,
                        float* __restrict__ info) {
  constexpr int L = IN_F - 2;
  int t = blockIdx.x * blockDim.x + threadIdx.x;
  if (t >= NB * L) return;
  int b = t / L, i = t - (t / L) * L;
  const float* xr = X + (size_t)root[b] * IN_F;
  info[t] = c1w[0] * xr[i] + c1w[1] * xr[i + 1] + c1w[2] * xr[i + 2] + c1b[0];
}

__global__ void k_info2(const float* __restrict__ info, const float* __restrict__ c2W,
                        const float* __restrict__ c2b, float* __restrict__ t1) {
  constexpr int L = IN_F - 2;
  int t = blockIdx.x * blockDim.x + threadIdx.x;
  if (t >= HC1C * NB) return;
  int j = t >> 6, b = t & 63;
  float a = c2b[j];
  for (int i = 0; i < L; ++i) a += c2W[j * L + i] * info[b * L + i];
  t1[t] = a > 0.f ? a : 0.f;
}

__global__ void k_info3(const float* __restrict__ t1, const float* __restrict__ c3W,
                        const float* __restrict__ c3b, float* __restrict__ t2) {
  int t = blockIdx.x * blockDim.x + threadIdx.x;
  if (t >= NB * NB) return;
  int j = t >> 6, b = t & 63;
  float a = c3b[j];
  for (int i = 0; i < HC1C; ++i) a += c3W[j * HC1C + i] * t1[i * NB + b];
  t2[t] = a > 0.f ? a : 0.f;
}

__global__ void k_info4(const float* __restrict__ t2, float* __restrict__ tt) {
  int t = blockIdx.x * blockDim.x + threadIdx.x;
  if (t >= NB * HC2C) return;
  int b = t >> 5, c = t & 31;
  float v = 0.5f * (t2[(2 * c) * NB + b] + t2[(2 * c + 1) * NB + b]);
  tt[b * HC2C + c] = v > 0.f ? v : 0.f;
}

__global__ void k_final(const float* __restrict__ sx, const float* __restrict__ tt,
                        const float* __restrict__ aW1, const float* __restrict__ ab1,
                        const float* __restrict__ aW2, const float* __restrict__ mW1,
                        const float* __restrict__ mb1, const float* __restrict__ mW2,
                        const float* __restrict__ mb2, float* __restrict__ out) {
  int b = threadIdx.x;
  if (b >= NB) return;
  const float* e0 = sx + b * HC2C;
  const float* e1 = tt + b * HC2C;
  float w[2];
#pragma unroll
  for (int r = 0; r < 2; ++r) {
    const float* eb = (r == 0) ? e0 : e1;
    float acc = 0.f;
    for (int j = 0; j < 16; ++j) {
      float z = ab1[j];
      for (int c = 0; c < HC2C; ++c) z += eb[c] * aW1[c * 16 + j];
      acc += tanhf(z) * aW2[j];
    }
    w[r] = acc;
  }
  float mx = fmaxf(w[0], w[1]);
  float x0 = expf(w[0] - mx), x1 = expf(w[1] - mx);
  float inv = 1.f / (x0 + x1);
  float b0 = x0 * inv, b1 = x1 * inv;
  float t16[16];
  for (int j = 0; j < 16; ++j) {
    float z = mb1[j];
    for (int c = 0; c < HC2C; ++c) z += (b0 * e0[c] + b1 * e1[c]) * mW1[c * 16 + j];
    t16[j] = tanhf(z);
  }
  float l0 = mb2[0], l1 = mb2[1];
  for (int j = 0; j < 16; ++j) {
    l0 += t16[j] * mW2[j * 2 + 0];
    l1 += t16[j] * mW2[j * 2 + 1];
  }
  float m2 = fmaxf(l0, l1);
  float y0 = expf(l0 - m2), y1 = expf(l1 - m2);
  float is = 1.f / (y0 + y1);
  out[b * 2 + 0] = y0 * is;
  out[b * 2 + 1] = y1 * is;
}

// ---------------- launcher ----------------
extern "C" void kernel_launch(void* const* d_in, const int* in_sizes, int n_in, void* d_out,
                              int out_size, void* d_ws, size_t ws_size, hipStream_t stream) {
  if (ws_size < WS_FLOATS * sizeof(float)) return;

  const float* s_x   = (const float*)d_in[0];
  const int*   edge  = (const int*)d_in[1];
  const int*   batch = (const int*)d_in[2];
  const int*   root  = (const int*)d_in[3];
  const float* Wv    = (const float*)d_in[8];
  const float* bv    = (const float*)d_in[9];
  const float* Wl1   = (const float*)d_in[10];
  const float* bl1   = (const float*)d_in[11];
  const float* Wr1   = (const float*)d_in[12];
  const float* br1   = (const float*)d_in[13];
  const float* att1  = (const float*)d_in[14];
  const float* bias1 = (const float*)d_in[15];
  const float* Wl2   = (const float*)d_in[16];
  const float* bl2   = (const float*)d_in[17];
  const float* Wr2   = (const float*)d_in[18];
  const float* br2   = (const float*)d_in[19];
  const float* att2  = (const float*)d_in[20];
  const float* bias2 = (const float*)d_in[21];
  const float* Wl3   = (const float*)d_in[22];
  const float* bl3   = (const float*)d_in[23];
  const float* Wr3   = (const float*)d_in[24];
  const float* br3   = (const float*)d_in[25];
  const float* att3  = (const float*)d_in[26];
  const float* bias3 = (const float*)d_in[27];
  const float* c1w   = (const float*)d_in[28];
  const float* c1b   = (const float*)d_in[29];
  const float* c2W   = (const float*)d_in[30];
  const float* c2b   = (const float*)d_in[31];
  const float* c3W   = (const float*)d_in[32];
  const float* c3b   = (const float*)d_in[33];
  const float* linW  = (const float*)d_in[34];
  const float* linb  = (const float*)d_in[35];
  const float* aW1   = (const float*)d_in[36];
  const float* ab1   = (const float*)d_in[37];
  const float* aW2   = (const float*)d_in[38];
  const float* mW1   = (const float*)d_in[39];
  const float* mb1   = (const float*)d_in[40];
  const float* mW2   = (const float*)d_in[41];
  const float* mb2   = (const float*)d_in[42];

  const int* src = edge;
  const int* dst = edge + N_EDGES;

  float*    ws      = (float*)d_ws;
  ushort_t* WT1     = (ushort_t*)(ws + OFF_WT1);
  ushort_t* WT2     = (ushort_t*)(ws + OFF_WT2);
  ushort_t* WT3     = (ushort_t*)(ws + OFF_WT3);
  float*    bc1     = ws + OFF_BC1;
  float*    bc2     = ws + OFF_BC2;
  float*    bc3     = ws + OFF_BC3;
  float*    xlr     = ws + OFF_XLR;
  float*    hbuf    = ws + OFF_H;
  int*      deg     = (int*)(ws + OFF_DEG);
  int*      row_ptr = (int*)(ws + OFF_ROWPTR);
  int*      cursor  = (int*)(ws + OFF_CURSOR);
  int*      blks    = (int*)(ws + OFF_BLKS);
  int*      blko    = (int*)(ws + OFF_BLKO);
  int*      csr_src = (int*)(ws + OFF_CSRSRC);
  float*    pooled  = ws + OFF_POOLED;
  float*    cnt     = ws + OFF_CNT;
  float*    sx      = ws + OFF_SX;
  float*    info    = ws + OFF_INFO;
  float*    t1      = ws + OFF_T1;
  float*    t2      = ws + OFF_T2;
  float*    tt      = ws + OFF_TT;
  float*    out     = (float*)d_out;

  // ---- CSR build (by dst) ----
  hipMemsetAsync(deg, 0, N_NODES * sizeof(int), stream);
  k_hist<<<(N_EDGES + 255) / 256, 256, 0, stream>>>(dst, deg);
  k_scan_local<<<SCAN_NBLK, 256, 0, stream>>>(deg, row_ptr, blks);
  k_scan_blk<<<1, 512, 0, stream>>>(blks, blko);
  k_scan_add<<<SCAN_NBLK, 256, 0, stream>>>(row_ptr, blko, cursor);
  k_fill<<<(N_EDGES + 255) / 256, 256, 0, stream>>>(src, dst, cursor, csr_src);

  // ---- weight fold / pack ----
  k_wcomb<<<(256 * 256) / 256, 256, 0, stream>>>(Wv, Wl1, Wr1, WT1);
  k_bcomb<<<1, 256, 0, stream>>>(bv, Wl1, bl1, Wr1, br1, bc1);
  k_wpack<128, 64><<<(128 * 128 + 255) / 256, 256, 0, stream>>>(Wl2, bl2, Wr2, br2, WT2, bc2);
  k_wpack<64, 32><<<(64 * 64 + 255) / 256, 256, 0, stream>>>(Wl3, bl3, Wr3, br3, WT3, bc3);

  // ---- GAT layer 1 (K=256, N=256) ----
  k_gemm_mfma<256, 256, 128><<<dim3(MB128, 2), 256, 0, stream>>>(s_x, WT1, bc1, xlr, N_NODES);
  k_gat<128><<<(N_NODES * 32 + 255) / 256, 256, 0, stream>>>(xlr, row_ptr, csr_src, att1,
                                                             bias1, hbuf);

  // ---- GAT layer 2 (K=128, N=128) ----
  k_gemm_mfma<128, 128, 128><<<dim3(MB128, 1), 256, 0, stream>>>(hbuf, WT2, bc2, xlr, N_NODES);
  k_gat<64><<<(N_NODES * 16 + 255) / 256, 256, 0, stream>>>(xlr, row_ptr, csr_src, att2,
                                                            bias2, hbuf);

  // ---- GAT layer 3 (K=64, N=64) ----
  k_gemm_mfma<64, 64, 64><<<dim3(MB128, 1), 256, 0, stream>>>(hbuf, WT3, bc3, xlr, N_NODES);
  k_gat<32><<<(N_NODES * 8 + 255) / 256, 256, 0, stream>>>(xlr, row_ptr, csr_src, att3,
                                                           bias3, hbuf);

  // ---- pooling + root concat + lin ----
  hipMemsetAsync(pooled, 0, (NB * HC2C + NB) * sizeof(float), stream);
  k_pool<<<(N_NODES + 1023) / 1024, 256, 0, stream>>>(hbuf, batch, pooled, cnt);
  k_sx<<<(NB * HC2C + 255) / 256, 256, 0, stream>>>(hbuf, root, pooled, cnt, linW, linb, sx);

  // ---- info path ----
  k_info1<<<(NB * (IN_F - 2) + 255) / 256, 256, 0, stream>>>(s_x, root, c1w, c1b, info);
  k_info2<<<(HC1C * NB + 255) / 256, 256, 0, stream>>>(info, c2W, c2b, t1);
  k_info3<<<(NB * NB + 255) / 256, 256, 0, stream>>>(t1, c3W, c3b, t2);
  k_info4<<<(NB * HC2C + 255) / 256, 256, 0, stream>>>(t2, tt);

  // ---- attention combine + classifier ----
  k_final<<<1, NB, 0, stream>>>(sx, tt, aW1, ab1, aW2, mW1, mb1, mW2, mb2, out);
}

// Round 7
// 689.117 us; speedup vs baseline: 1.1525x; 1.0666x over previous
//
#include <hip/hip_runtime.h>
#include <hip/hip_bf16.h>
#include <math.h>

typedef unsigned short ushort_t;
typedef __attribute__((ext_vector_type(8))) short bfrag;   // 8 bf16 = 4 VGPRs
typedef __attribute__((ext_vector_type(4))) float ffrag;   // 4 fp32 acc

// ---------------- problem constants ----------------
constexpr int N_NODES = 100000;
constexpr int N_EDGES = 800000;
constexpr int NB      = 64;
constexpr int IN_F    = 256;
constexpr int HC1C    = 128;
constexpr int HC2C    = 32;
constexpr int SA_D    = 350;
constexpr float NEG   = 0.2f;

constexpr int SCAN_NBLK = (N_NODES + 255) / 256;  // 391
constexpr int MB128     = (N_NODES + 127) / 128;  // 782

// ---------------- workspace layout (float-sized slots) ----------------
constexpr size_t OFF_WT1    = 0;                                   // 2*(256*256) ush = 65536 f
constexpr size_t OFF_WT2    = OFF_WT1 + 65536;                     // 2*(128*128) ush = 16384 f
constexpr size_t OFF_WT3    = OFF_WT2 + 16384;                     // 2*(64*64) ush = 4096 f
constexpr size_t OFF_BC1    = OFF_WT3 + 4096;                      // 256
constexpr size_t OFF_BC2    = OFF_BC1 + 256;                       // 128
constexpr size_t OFF_BC3    = OFF_BC2 + 128;                       // 64
constexpr size_t OFF_XLR    = OFF_BC3 + 64;                        // N*256 bf16 (N*128 f slots used)
constexpr size_t OFF_H      = OFF_XLR + (size_t)N_NODES * 256;     // N*128 fp32
constexpr size_t OFF_DEG    = OFF_H + (size_t)N_NODES * 128;       // N ints
constexpr size_t OFF_ROWPTR = OFF_DEG + N_NODES;                   // N+1 ints
constexpr size_t OFF_CURSOR = OFF_ROWPTR + N_NODES + 1;            // N ints
constexpr size_t OFF_BLKS   = OFF_CURSOR + N_NODES;                // 512 ints
constexpr size_t OFF_BLKO   = OFF_BLKS + 512;                      // 512 ints
constexpr size_t OFF_CSRSRC = OFF_BLKO + 512;                      // E ints
constexpr size_t OFF_POOLED = OFF_CSRSRC + N_EDGES;                // 64*32
constexpr size_t OFF_CNT    = OFF_POOLED + NB * HC2C;              // 64
constexpr size_t OFF_SX     = OFF_CNT + NB;                        // 64*32
constexpr size_t OFF_INFO   = OFF_SX + NB * HC2C;                  // 64*254
constexpr size_t OFF_T1     = OFF_INFO + (size_t)NB * (IN_F - 2);  // 128*64
constexpr size_t OFF_T2     = OFF_T1 + (size_t)HC1C * NB;          // 64*64
constexpr size_t OFF_TT     = OFF_T2 + (size_t)NB * NB;            // 64*32
constexpr size_t WS_FLOATS  = OFF_TT + NB * HC2C;

// ---------------- bf16 helpers ----------------
__device__ __forceinline__ ushort_t f2bf(float f) {  // RNE
  union { float f; unsigned int u; } a;
  a.f = f;
  unsigned int r = a.u + 0x7FFFu + ((a.u >> 16) & 1u);
  return (ushort_t)(r >> 16);
}
__device__ __forceinline__ float bf2f(ushort_t h) {
  union { unsigned int u; float f; } a;
  a.u = ((unsigned int)h) << 16;
  return a.f;
}
// unpack 2 bf16 packed in a dword (little-endian: low ushort first)
__device__ __forceinline__ float2 bfp(unsigned int u) {
  float2 r;
  r.x = __uint_as_float(u << 16);
  r.y = __uint_as_float(u & 0xFFFF0000u);
  return r;
}
// Truncation split of 2 floats -> packed hi dword + packed lo dword (~3 ops/elem).
__device__ __forceinline__ void split2(float a, float b, unsigned int& hi, unsigned int& lo) {
  unsigned int ua = __float_as_uint(a), ub = __float_as_uint(b);
  float la = a - __uint_as_float(ua & 0xFFFF0000u);
  float lb = b - __uint_as_float(ub & 0xFFFF0000u);
  hi = __builtin_amdgcn_perm(ub, ua, 0x07060302u);
  lo = __builtin_amdgcn_perm(__float_as_uint(lb), __float_as_uint(la), 0x07060302u);
}

// ---------------- weight fold / pack (transposed, split hi/lo, RNE) ----------------
__global__ void k_wcomb(const float* __restrict__ Wv, const float* __restrict__ Wl1,
                        const float* __restrict__ Wr1, ushort_t* __restrict__ WT) {
  int t = blockIdx.x * blockDim.x + threadIdx.x;
  if (t >= 256 * 256) return;
  int n = t & 255;
  int k = t >> 8;
  const float* Wx = (n < 128) ? Wl1 : Wr1;
  int j = n & 127;
  float a = 0.f;
  for (int kk = 0; kk < SA_D; ++kk) a += Wv[k * SA_D + kk] * Wx[kk * 128 + j];
  ushort_t h = f2bf(a);
  WT[(size_t)n * 256 + k] = h;
  WT[65536 + (size_t)n * 256 + k] = f2bf(a - bf2f(h));
}

__global__ void k_bcomb(const float* __restrict__ bv, const float* __restrict__ Wl1,
                        const float* __restrict__ bl1, const float* __restrict__ Wr1,
                        const float* __restrict__ br1, float* __restrict__ bc) {
  int n = threadIdx.x;
  if (n >= 256) return;
  const float* Wx = (n < 128) ? Wl1 : Wr1;
  const float* bx = (n < 128) ? bl1 : br1;
  int j = n & 127;
  float a = bx[j];
  for (int kk = 0; kk < SA_D; ++kk) a += bv[kk] * Wx[kk * 128 + j];
  bc[n] = a;
}

template <int K, int C>
__global__ void k_wpack(const float* __restrict__ Wl, const float* __restrict__ bl,
                        const float* __restrict__ Wr, const float* __restrict__ br,
                        ushort_t* __restrict__ WT, float* __restrict__ bc) {
  constexpr int NN = 2 * C;
  int t = blockIdx.x * blockDim.x + threadIdx.x;
  if (t < NN) bc[t] = (t < C) ? bl[t] : br[t - C];
  if (t >= NN * K) return;
  int n = t % NN;
  int k = t / NN;
  float v = (n < C) ? Wl[k * C + n] : Wr[k * C + (n - C)];
  ushort_t h = f2bf(v);
  WT[(size_t)n * K + k] = h;
  WT[(size_t)NN * K + (size_t)n * K + k] = f2bf(v - bf2f(h));
}

// ---------------- CSR build ----------------
__global__ void k_hist(const int* __restrict__ dst, int* __restrict__ deg) {
  int e = blockIdx.x * blockDim.x + threadIdx.x;
  if (e < N_EDGES) atomicAdd(deg + dst[e], 1);
}

__global__ void k_scan_local(const int* __restrict__ deg, int* __restrict__ row_ptr,
                             int* __restrict__ blk_sum) {
  __shared__ int sh[256];
  int t = threadIdx.x;
  int i = blockIdx.x * 256 + t;
  int v = (i < N_NODES) ? deg[i] : 0;
  sh[t] = v;
  __syncthreads();
  for (int off = 1; off < 256; off <<= 1) {
    int add = (t >= off) ? sh[t - off] : 0;
    __syncthreads();
    sh[t] += add;
    __syncthreads();
  }
  if (i < N_NODES) row_ptr[i] = sh[t] - v;
  if (t == 255) blk_sum[blockIdx.x] = sh[255];
}

__global__ void k_scan_blk(const int* __restrict__ blk_sum, int* __restrict__ blk_off) {
  __shared__ int sh[512];
  int t = threadIdx.x;
  int v = (t < SCAN_NBLK) ? blk_sum[t] : 0;
  sh[t] = v;
  __syncthreads();
  for (int off = 1; off < 512; off <<= 1) {
    int add = (t >= off) ? sh[t - off] : 0;
    __syncthreads();
    sh[t] += add;
    __syncthreads();
  }
  blk_off[t] = sh[t] - v;
}

__global__ void k_scan_add(int* __restrict__ row_ptr, const int* __restrict__ blk_off,
                           int* __restrict__ cursor) {
  int i = blockIdx.x * blockDim.x + threadIdx.x;
  if (i < N_NODES) {
    int v = row_ptr[i] + blk_off[i >> 8];
    row_ptr[i] = v;
    cursor[i] = v;
  }
  if (i == 0) row_ptr[N_NODES] = N_EDGES;
}

__global__ void k_fill(const int* __restrict__ src, const int* __restrict__ dst,
                       int* __restrict__ cursor, int* __restrict__ csr_src) {
  int e = blockIdx.x * blockDim.x + threadIdx.x;
  if (e >= N_EDGES) return;
  int pos = atomicAdd(cursor + dst[e], 1);
  csr_src[pos] = src[e];
}

// ---------------- split-bf16 MFMA GEMM: out_bf16[m][NN] = x[m][K] @ W + bc ----------------
// Same 2x2 wave-tiled structure as round 6 (acc[4][CT], ~12 waves/CU); epilogue now
// rounds to bf16 -> WRITE_SIZE halves and downstream gathers halve.
template <int K, int NN, int BN>
__global__ __launch_bounds__(256) void k_gemm_mfma(const float* __restrict__ x,
                                                   const ushort_t* __restrict__ WT,
                                                   const float* __restrict__ bc,
                                                   ushort_t* __restrict__ out, int M) {
  constexpr int BM  = 128;
  constexpr int BK  = 32;
  constexpr int LDA = BK + 8;
  constexpr int RT  = 4;
  constexpr int CT  = BN / 32;
  __shared__ ushort_t As[2][BM * LDA];
  __shared__ ushort_t Bs[2][BN * LDA];
  const int tid  = threadIdx.x;
  const int wave = tid >> 6;
  const int wrow = wave >> 1;
  const int wcol = wave & 1;
  const int lane = tid & 63;
  const int quad = lane >> 4;
  const int l16  = lane & 15;
  const int m0   = blockIdx.x * BM;
  const int n0   = blockIdx.y * BN;

  ffrag acc[RT][CT];
#pragma unroll
  for (int rt = 0; rt < RT; ++rt)
#pragma unroll
    for (int ct = 0; ct < CT; ++ct) acc[rt][ct] = ffrag{0.f, 0.f, 0.f, 0.f};

  for (int k0 = 0; k0 < K; k0 += BK) {
    __syncthreads();
    {
      int row = tid >> 1;
      int ks  = (tid & 1) * 16;
      int gm  = m0 + row;
      if (gm >= M) gm = M - 1;
      const float4* sp = (const float4*)(x + (size_t)gm * K + k0 + ks);
      float4 f0 = sp[0], f1 = sp[1], f2 = sp[2], f3 = sp[3];
      unsigned int hi[8], lo[8];
      split2(f0.x, f0.y, hi[0], lo[0]);
      split2(f0.z, f0.w, hi[1], lo[1]);
      split2(f1.x, f1.y, hi[2], lo[2]);
      split2(f1.z, f1.w, hi[3], lo[3]);
      split2(f2.x, f2.y, hi[4], lo[4]);
      split2(f2.z, f2.w, hi[5], lo[5]);
      split2(f3.x, f3.y, hi[6], lo[6]);
      split2(f3.z, f3.w, hi[7], lo[7]);
      *(uint4*)&As[0][row * LDA + ks]     = *(uint4*)&hi[0];
      *(uint4*)&As[0][row * LDA + ks + 8] = *(uint4*)&hi[4];
      *(uint4*)&As[1][row * LDA + ks]     = *(uint4*)&lo[0];
      *(uint4*)&As[1][row * LDA + ks + 8] = *(uint4*)&lo[4];
    }
#pragma unroll
    for (int i = tid; i < BN * 4; i += 256) {
      int n  = i >> 2;
      int ks = (i & 3) * 8;
      const ushort_t* gh = WT + (size_t)(n0 + n) * K + k0 + ks;
      *(bfrag*)&Bs[0][n * LDA + ks] = *(const bfrag*)gh;
      *(bfrag*)&Bs[1][n * LDA + ks] = *(const bfrag*)(gh + (size_t)NN * K);
    }
    __syncthreads();

    bfrag a_hi[RT], a_lo[RT];
#pragma unroll
    for (int rt = 0; rt < RT; ++rt) {
      int r = wrow * 64 + rt * 16 + l16;
      a_hi[rt] = *(const bfrag*)&As[0][r * LDA + quad * 8];
      a_lo[rt] = *(const bfrag*)&As[1][r * LDA + quad * 8];
    }
#pragma unroll
    for (int ct = 0; ct < CT; ++ct) {
      int bn = wcol * (BN / 2) + ct * 16 + l16;
      bfrag b_hi = *(const bfrag*)&Bs[0][bn * LDA + quad * 8];
      bfrag b_lo = *(const bfrag*)&Bs[1][bn * LDA + quad * 8];
#pragma unroll
      for (int rt = 0; rt < RT; ++rt) {
        acc[rt][ct] = __builtin_amdgcn_mfma_f32_16x16x32_bf16(a_hi[rt], b_hi, acc[rt][ct], 0, 0, 0);
        acc[rt][ct] = __builtin_amdgcn_mfma_f32_16x16x32_bf16(a_hi[rt], b_lo, acc[rt][ct], 0, 0, 0);
        acc[rt][ct] = __builtin_amdgcn_mfma_f32_16x16x32_bf16(a_lo[rt], b_hi, acc[rt][ct], 0, 0, 0);
      }
    }
  }

#pragma unroll
  for (int rt = 0; rt < RT; ++rt)
#pragma unroll
    for (int ct = 0; ct < CT; ++ct) {
      int n = n0 + wcol * (BN / 2) + ct * 16 + l16;
      float b = bc[n];
#pragma unroll
      for (int r = 0; r < 4; ++r) {
        int m = m0 + wrow * 64 + rt * 16 + quad * 4 + r;
        if (m < M) out[(size_t)m * NN + n] = f2bf(acc[rt][ct][r] + b);
      }
    }
}

// ---------------- fused per-node GAT edge pass (bf16 xlr, 8 ch/lane) ----------------
template <int C>
__global__ void k_gat(const ushort_t* __restrict__ xlr, const int* __restrict__ row_ptr,
                      const int* __restrict__ csr_src, const float* __restrict__ att,
                      const float* __restrict__ bias, float* __restrict__ h) {
  constexpr int G = C / 8;          // lanes per edge group, 8 channels each
  constexpr int RS = 2 * C;         // row stride in ushorts
  int t = blockIdx.x * blockDim.x + threadIdx.x;
  int d = t / G;
  int lane = t - d * G;
  if (d >= N_NODES) return;
  float xr[8], a[8];
  {
    uint4 u = *(const uint4*)(xlr + (size_t)d * RS + C + lane * 8);
    float2 p0 = bfp(u.x), p1 = bfp(u.y), p2 = bfp(u.z), p3 = bfp(u.w);
    xr[0] = p0.x; xr[1] = p0.y; xr[2] = p1.x; xr[3] = p1.y;
    xr[4] = p2.x; xr[5] = p2.y; xr[6] = p3.x; xr[7] = p3.y;
  }
  *(float4*)&a[0] = *(const float4*)(att + lane * 8);
  *(float4*)&a[4] = *(const float4*)(att + lane * 8 + 4);
  float acc[8];
#pragma unroll
  for (int j = 0; j < 8; ++j) acc[j] = 0.f;
  float den = 0.f;
  const int e0 = row_ptr[d], e1 = row_ptr[d + 1];
  for (int i = e0; i < e1; ++i) {
    int s = csr_src[i];
    uint4 u = *(const uint4*)(xlr + (size_t)s * RS + lane * 8);
    float xl[8];
    {
      float2 p0 = bfp(u.x), p1 = bfp(u.y), p2 = bfp(u.z), p3 = bfp(u.w);
      xl[0] = p0.x; xl[1] = p0.y; xl[2] = p1.x; xl[3] = p1.y;
      xl[4] = p2.x; xl[5] = p2.y; xl[6] = p3.x; xl[7] = p3.y;
    }
    float p = 0.f;
#pragma unroll
    for (int j = 0; j < 8; ++j) {
      float v = xl[j] + xr[j];
      v = v > 0.f ? v : NEG * v;
      p += a[j] * v;
    }
#pragma unroll
    for (int off = G / 2; off > 0; off >>= 1) p += __shfl_xor(p, off, 64);
    float ex = expf(p);
    den += ex;
#pragma unroll
    for (int j = 0; j < 8; ++j) acc[j] += ex * xl[j];
  }
  float inv = 1.f / fmaxf(den, 1e-16f);
  float o[8];
#pragma unroll
  for (int j = 0; j < 8; ++j)
    o[j] = fmaxf(acc[j] * inv + bias[lane * 8 + j], 0.f);
  float* hp = h + (size_t)d * C + lane * 8;
  *(float4*)hp       = *(float4*)&o[0];
  *(float4*)(hp + 4) = *(float4*)&o[4];
}

// ---------------- pooling: sorted-batch run-accumulate ----------------
__global__ void k_pool(const float* __restrict__ h3, const int* __restrict__ batch,
                       float* __restrict__ pooled, float* __restrict__ cnt) {
  constexpr int NPB = 1024;
  constexpr int NPT = NPB / 8;
  int c = threadIdx.x & 31;
  int r = threadIdx.x >> 5;
  int base = blockIdx.x * NPB + r * NPT;
  if (base >= N_NODES) return;
  int end = base + NPT;
  if (end > N_NODES) end = N_NODES;
  int cur_b = batch[base];
  float acc = 0.f, count = 0.f;
  for (int n = base; n < end; ++n) {
    int b = batch[n];
    if (b != cur_b) {
      atomicAdd(pooled + cur_b * HC2C + c, acc);
      if (c == 0) atomicAdd(cnt + cur_b, count);
      cur_b = b;
      acc = 0.f;
      count = 0.f;
    }
    acc += h3[(size_t)n * HC2C + c];
    count += 1.f;
  }
  atomicAdd(pooled + cur_b * HC2C + c, acc);
  if (c == 0) atomicAdd(cnt + cur_b, count);
}

// ---------------- tail ----------------
__global__ void k_sx(const float* __restrict__ h3, const int* __restrict__ root,
                     const float* __restrict__ pooled, const float* __restrict__ cnt,
                     const float* __restrict__ linW, const float* __restrict__ linb,
                     float* __restrict__ sx) {
  int t = blockIdx.x * blockDim.x + threadIdx.x;
  if (t >= NB * HC2C) return;
  int b = t >> 5, j = t & 31;
  int r = root[b];
  float inv = 1.f / fmaxf(cnt[b], 1.0f);
  float a = linb[j];
  for (int c = 0; c < HC2C; ++c) a += h3[(size_t)r * HC2C + c] * linW[c * HC2C + j];
  for (int c = 0; c < HC2C; ++c) a += (pooled[b * HC2C + c] * inv) * linW[(HC2C + c) * HC2C + j];
  sx[t] = a > 0.f ? a : 0.f;
}

__global__ void k_info1(const float* __restrict__ X, const int* __restrict__ root,
                        const float* __restrict__ c1w, const float* __restrict__ c1b,
                        float* __restrict__ info) {
  constexpr int L = IN_F - 2;
  int t = blockIdx.x * blockDim.x + threadIdx.x;
  if (t >= NB * L) return;
  int b = t / L, i = t - (t / L) * L;
  const float* xr = X + (size_t)root[b] * IN_F;
  info[t] = c1w[0] * xr[i] + c1w[1] * xr[i + 1] + c1w[2] * xr[i + 2] + c1b[0];
}

__global__ void k_info2(const float* __restrict__ info, const float* __restrict__ c2W,
                        const float* __restrict__ c2b, float* __restrict__ t1) {
  constexpr int L = IN_F - 2;
  int t = blockIdx.x * blockDim.x + threadIdx.x;
  if (t >= HC1C * NB) return;
  int j = t >> 6, b = t & 63;
  float a = c2b[j];
  for (int i = 0; i < L; ++i) a += c2W[j * L + i] * info[b * L + i];
  t1[t] = a > 0.f ? a : 0.f;
}

__global__ void k_info3(const float* __restrict__ t1, const float* __restrict__ c3W,
                        const float* __restrict__ c3b, float* __restrict__ t2) {
  int t = blockIdx.x * blockDim.x + threadIdx.x;
  if (t >= NB * NB) return;
  int j = t >> 6, b = t & 63;
  float a = c3b[j];
  for (int i = 0; i < HC1C; ++i) a += c3W[j * HC1C + i] * t1[i * NB + b];
  t2[t] = a > 0.f ? a : 0.f;
}

__global__ void k_info4(const float* __restrict__ t2, float* __restrict__ tt) {
  int t = blockIdx.x * blockDim.x + threadIdx.x;
  if (t >= NB * HC2C) return;
  int b = t >> 5, c = t & 31;
  float v = 0.5f * (t2[(2 * c) * NB + b] + t2[(2 * c + 1) * NB + b]);
  tt[b * HC2C + c] = v > 0.f ? v : 0.f;
}

__global__ void k_final(const float* __restrict__ sx, const float* __restrict__ tt,
                        const float* __restrict__ aW1, const float* __restrict__ ab1,
                        const float* __restrict__ aW2, const float* __restrict__ mW1,
                        const float* __restrict__ mb1, const float* __restrict__ mW2,
                        const float* __restrict__ mb2, float* __restrict__ out) {
  int b = threadIdx.x;
  if (b >= NB) return;
  const float* e0 = sx + b * HC2C;
  const float* e1 = tt + b * HC2C;
  float w[2];
#pragma unroll
  for (int r = 0; r < 2; ++r) {
    const float* eb = (r == 0) ? e0 : e1;
    float acc = 0.f;
    for (int j = 0; j < 16; ++j) {
      float z = ab1[j];
      for (int c = 0; c < HC2C; ++c) z += eb[c] * aW1[c * 16 + j];
      acc += tanhf(z) * aW2[j];
    }
    w[r] = acc;
  }
  float mx = fmaxf(w[0], w[1]);
  float x0 = expf(w[0] - mx), x1 = expf(w[1] - mx);
  float inv = 1.f / (x0 + x1);
  float b0 = x0 * inv, b1 = x1 * inv;
  float t16[16];
  for (int j = 0; j < 16; ++j) {
    float z = mb1[j];
    for (int c = 0; c < HC2C; ++c) z += (b0 * e0[c] + b1 * e1[c]) * mW1[c * 16 + j];
    t16[j] = tanhf(z);
  }
  float l0 = mb2[0], l1 = mb2[1];
  for (int j = 0; j < 16; ++j) {
    l0 += t16[j] * mW2[j * 2 + 0];
    l1 += t16[j] * mW2[j * 2 + 1];
  }
  float m2 = fmaxf(l0, l1);
  float y0 = expf(l0 - m2), y1 = expf(l1 - m2);
  float is = 1.f / (y0 + y1);
  out[b * 2 + 0] = y0 * is;
  out[b * 2 + 1] = y1 * is;
}

// ---------------- launcher ----------------
extern "C" void kernel_launch(void* const* d_in, const int* in_sizes, int n_in, void* d_out,
                              int out_size, void* d_ws, size_t ws_size, hipStream_t stream) {
  if (ws_size < WS_FLOATS * sizeof(float)) return;

  const float* s_x   = (const float*)d_in[0];
  const int*   edge  = (const int*)d_in[1];
  const int*   batch = (const int*)d_in[2];
  const int*   root  = (const int*)d_in[3];
  const float* Wv    = (const float*)d_in[8];
  const float* bv    = (const float*)d_in[9];
  const float* Wl1   = (const float*)d_in[10];
  const float* bl1   = (const float*)d_in[11];
  const float* Wr1   = (const float*)d_in[12];
  const float* br1   = (const float*)d_in[13];
  const float* att1  = (const float*)d_in[14];
  const float* bias1 = (const float*)d_in[15];
  const float* Wl2   = (const float*)d_in[16];
  const float* bl2   = (const float*)d_in[17];
  const float* Wr2   = (const float*)d_in[18];
  const float* br2   = (const float*)d_in[19];
  const float* att2  = (const float*)d_in[20];
  const float* bias2 = (const float*)d_in[21];
  const float* Wl3   = (const float*)d_in[22];
  const float* bl3   = (const float*)d_in[23];
  const float* Wr3   = (const float*)d_in[24];
  const float* br3   = (const float*)d_in[25];
  const float* att3  = (const float*)d_in[26];
  const float* bias3 = (const float*)d_in[27];
  const float* c1w   = (const float*)d_in[28];
  const float* c1b   = (const float*)d_in[29];
  const float* c2W   = (const float*)d_in[30];
  const float* c2b   = (const float*)d_in[31];
  const float* c3W   = (const float*)d_in[32];
  const float* c3b   = (const float*)d_in[33];
  const float* linW  = (const float*)d_in[34];
  const float* linb  = (const float*)d_in[35];
  const float* aW1   = (const float*)d_in[36];
  const float* ab1   = (const float*)d_in[37];
  const float* aW2   = (const float*)d_in[38];
  const float* mW1   = (const float*)d_in[39];
  const float* mb1   = (const float*)d_in[40];
  const float* mW2   = (const float*)d_in[41];
  const float* mb2   = (const float*)d_in[42];

  const int* src = edge;
  const int* dst = edge + N_EDGES;

  float*    ws      = (float*)d_ws;
  ushort_t* WT1     = (ushort_t*)(ws + OFF_WT1);
  ushort_t* WT2     = (ushort_t*)(ws + OFF_WT2);
  ushort_t* WT3     = (ushort_t*)(ws + OFF_WT3);
  float*    bc1     = ws + OFF_BC1;
  float*    bc2     = ws + OFF_BC2;
  float*    bc3     = ws + OFF_BC3;
  ushort_t* xlr     = (ushort_t*)(ws + OFF_XLR);
  float*    hbuf    = ws + OFF_H;
  int*      deg     = (int*)(ws + OFF_DEG);
  int*      row_ptr = (int*)(ws + OFF_ROWPTR);
  int*      cursor  = (int*)(ws + OFF_CURSOR);
  int*      blks    = (int*)(ws + OFF_BLKS);
  int*      blko    = (int*)(ws + OFF_BLKO);
  int*      csr_src = (int*)(ws + OFF_CSRSRC);
  float*    pooled  = ws + OFF_POOLED;
  float*    cnt     = ws + OFF_CNT;
  float*    sx      = ws + OFF_SX;
  float*    info    = ws + OFF_INFO;
  float*    t1      = ws + OFF_T1;
  float*    t2      = ws + OFF_T2;
  float*    tt      = ws + OFF_TT;
  float*    out     = (float*)d_out;

  // ---- CSR build (by dst) ----
  hipMemsetAsync(deg, 0, N_NODES * sizeof(int), stream);
  k_hist<<<(N_EDGES + 255) / 256, 256, 0, stream>>>(dst, deg);
  k_scan_local<<<SCAN_NBLK, 256, 0, stream>>>(deg, row_ptr, blks);
  k_scan_blk<<<1, 512, 0, stream>>>(blks, blko);
  k_scan_add<<<SCAN_NBLK, 256, 0, stream>>>(row_ptr, blko, cursor);
  k_fill<<<(N_EDGES + 255) / 256, 256, 0, stream>>>(src, dst, cursor, csr_src);

  // ---- weight fold / pack ----
  k_wcomb<<<(256 * 256) / 256, 256, 0, stream>>>(Wv, Wl1, Wr1, WT1);
  k_bcomb<<<1, 256, 0, stream>>>(bv, Wl1, bl1, Wr1, br1, bc1);
  k_wpack<128, 64><<<(128 * 128 + 255) / 256, 256, 0, stream>>>(Wl2, bl2, Wr2, br2, WT2, bc2);
  k_wpack<64, 32><<<(64 * 64 + 255) / 256, 256, 0, stream>>>(Wl3, bl3, Wr3, br3, WT3, bc3);

  // ---- GAT layer 1 (K=256, N=256) ----
  k_gemm_mfma<256, 256, 128><<<dim3(MB128, 2), 256, 0, stream>>>(s_x, WT1, bc1, xlr, N_NODES);
  k_gat<128><<<(N_NODES * 16 + 255) / 256, 256, 0, stream>>>(xlr, row_ptr, csr_src, att1,
                                                             bias1, hbuf);

  // ---- GAT layer 2 (K=128, N=128) ----
  k_gemm_mfma<128, 128, 128><<<dim3(MB128, 1), 256, 0, stream>>>(hbuf, WT2, bc2, xlr, N_NODES);
  k_gat<64><<<(N_NODES * 8 + 255) / 256, 256, 0, stream>>>(xlr, row_ptr, csr_src, att2,
                                                           bias2, hbuf);

  // ---- GAT layer 3 (K=64, N=64) ----
  k_gemm_mfma<64, 64, 64><<<dim3(MB128, 1), 256, 0, stream>>>(hbuf, WT3, bc3, xlr, N_NODES);
  k_gat<32><<<(N_NODES * 4 + 255) / 256, 256, 0, stream>>>(xlr, row_ptr, csr_src, att3,
                                                           bias3, hbuf);

  // ---- pooling + root concat + lin ----
  hipMemsetAsync(pooled, 0, (NB * HC2C + NB) * sizeof(float), stream);
  k_pool<<<(N_NODES + 1023) / 1024, 256, 0, stream>>>(hbuf, batch, pooled, cnt);
  k_sx<<<(NB * HC2C + 255) / 256, 256, 0, stream>>>(hbuf, root, pooled, cnt, linW, linb, sx);

  // ---- info path ----
  k_info1<<<(NB * (IN_F - 2) + 255) / 256, 256, 0, stream>>>(s_x, root, c1w, c1b, info);
  k_info2<<<(HC1C * NB + 255) / 256, 256, 0, stream>>>(info, c2W, c2b, t1);
  k_info3<<<(NB * NB + 255) / 256, 256, 0, stream>>>(t1, c3W, c3b, t2);
  k_info4<<<(NB * HC2C + 255) / 256, 256, 0, stream>>>(t2, tt);

  // ---- attention combine + classifier ----
  k_final<<<1, NB, 0, stream>>>(sx, tt, aW1, ab1, aW2, mW1, mb1, mW2, mb2, out);
}

// Round 8
// 680.806 us; speedup vs baseline: 1.1666x; 1.0122x over previous
//
#include <hip/hip_runtime.h>
#include <hip/hip_bf16.h>
#include <math.h>

typedef unsigned short ushort_t;
typedef __attribute__((ext_vector_type(8))) short bfrag;   // 8 bf16 = 4 VGPRs
typedef __attribute__((ext_vector_type(4))) float ffrag;   // 4 fp32 acc

// ---------------- problem constants ----------------
constexpr int N_NODES = 100000;
constexpr int N_EDGES = 800000;
constexpr int NB      = 64;
constexpr int IN_F    = 256;
constexpr int HC1C    = 128;
constexpr int HC2C    = 32;
constexpr int SA_D    = 350;
constexpr float NEG   = 0.2f;

constexpr int SCAN_NBLK = (N_NODES + 255) / 256;  // 391
constexpr int MB128     = (N_NODES + 127) / 128;  // 782

// ---------------- workspace layout (float-sized slots) ----------------
constexpr size_t OFF_WT1    = 0;                                   // 256*256 ush
constexpr size_t OFF_WT2    = OFF_WT1 + 65536;                     // (room)
constexpr size_t OFF_WT3    = OFF_WT2 + 16384;
constexpr size_t OFF_BC1    = OFF_WT3 + 4096;                      // 256
constexpr size_t OFF_BC2    = OFF_BC1 + 256;                       // 128
constexpr size_t OFF_BC3    = OFF_BC2 + 128;                       // 64
constexpr size_t OFF_XLR    = OFF_BC3 + 64;                        // N*256 bf16
constexpr size_t OFF_H      = OFF_XLR + (size_t)N_NODES * 256;     // N*128 bf16
constexpr size_t OFF_DEG    = OFF_H + (size_t)N_NODES * 128;       // N ints
constexpr size_t OFF_ROWPTR = OFF_DEG + N_NODES;                   // N+1 ints
constexpr size_t OFF_CURSOR = OFF_ROWPTR + N_NODES + 1;            // N ints
constexpr size_t OFF_BLKS   = OFF_CURSOR + N_NODES;                // 512 ints
constexpr size_t OFF_BLKO   = OFF_BLKS + 512;                      // 512 ints
constexpr size_t OFF_CSRSRC = OFF_BLKO + 512;                      // E ints
constexpr size_t OFF_POOLED = OFF_CSRSRC + N_EDGES;                // 64*32
constexpr size_t OFF_CNT    = OFF_POOLED + NB * HC2C;              // 64
constexpr size_t OFF_SX     = OFF_CNT + NB;                        // 64*32
constexpr size_t OFF_INFO   = OFF_SX + NB * HC2C;                  // 64*254
constexpr size_t OFF_T1     = OFF_INFO + (size_t)NB * (IN_F - 2);  // 128*64
constexpr size_t OFF_T2     = OFF_T1 + (size_t)HC1C * NB;          // 64*64
constexpr size_t OFF_TT     = OFF_T2 + (size_t)NB * NB;            // 64*32
constexpr size_t WS_FLOATS  = OFF_TT + NB * HC2C;

// ---------------- bf16 helpers ----------------
__device__ __forceinline__ ushort_t f2bf(float f) {  // RNE
  union { float f; unsigned int u; } a;
  a.f = f;
  unsigned int r = a.u + 0x7FFFu + ((a.u >> 16) & 1u);
  return (ushort_t)(r >> 16);
}
__device__ __forceinline__ float bf2f(ushort_t h) {
  union { unsigned int u; float f; } a;
  a.u = ((unsigned int)h) << 16;
  return a.f;
}
// unpack 2 bf16 packed in a dword (element order: low ushort first)
__device__ __forceinline__ float2 bfp(unsigned int u) {
  float2 r;
  r.x = __uint_as_float(u << 16);
  r.y = __uint_as_float(u & 0xFFFF0000u);
  return r;
}
// RNE-pack 2 floats (a = even/lower-address element) into one dword
__device__ __forceinline__ unsigned int pack2(float a, float b) {
  unsigned int ua = __float_as_uint(a);
  ua += 0x7FFFu + ((ua >> 16) & 1u);
  unsigned int ub = __float_as_uint(b);
  ub += 0x7FFFu + ((ub >> 16) & 1u);
  return __builtin_amdgcn_perm(ub, ua, 0x07060302u);
}

// ---------------- weight fold / pack (transposed WT[n][k], bf16 RNE) -------
__global__ void k_wcomb(const float* __restrict__ Wv, const float* __restrict__ Wl1,
                        const float* __restrict__ Wr1, ushort_t* __restrict__ WT) {
  int t = blockIdx.x * blockDim.x + threadIdx.x;
  if (t >= 256 * 256) return;
  int n = t & 255;
  int k = t >> 8;
  const float* Wx = (n < 128) ? Wl1 : Wr1;
  int j = n & 127;
  float a = 0.f;
  for (int kk = 0; kk < SA_D; ++kk) a += Wv[k * SA_D + kk] * Wx[kk * 128 + j];
  WT[(size_t)n * 256 + k] = f2bf(a);
}

__global__ void k_bcomb(const float* __restrict__ bv, const float* __restrict__ Wl1,
                        const float* __restrict__ bl1, const float* __restrict__ Wr1,
                        const float* __restrict__ br1, float* __restrict__ bc) {
  int n = threadIdx.x;
  if (n >= 256) return;
  const float* Wx = (n < 128) ? Wl1 : Wr1;
  const float* bx = (n < 128) ? bl1 : br1;
  int j = n & 127;
  float a = bx[j];
  for (int kk = 0; kk < SA_D; ++kk) a += bv[kk] * Wx[kk * 128 + j];
  bc[n] = a;
}

template <int K, int C>
__global__ void k_wpack(const float* __restrict__ Wl, const float* __restrict__ bl,
                        const float* __restrict__ Wr, const float* __restrict__ br,
                        ushort_t* __restrict__ WT, float* __restrict__ bc) {
  constexpr int NN = 2 * C;
  int t = blockIdx.x * blockDim.x + threadIdx.x;
  if (t < NN) bc[t] = (t < C) ? bl[t] : br[t - C];
  if (t >= NN * K) return;
  int n = t % NN;
  int k = t / NN;
  float v = (n < C) ? Wl[k * C + n] : Wr[k * C + (n - C)];
  WT[(size_t)n * K + k] = f2bf(v);
}

// ---------------- CSR build ----------------
__global__ void k_hist(const int* __restrict__ dst, int* __restrict__ deg) {
  int e = blockIdx.x * blockDim.x + threadIdx.x;
  if (e < N_EDGES) atomicAdd(deg + dst[e], 1);
}

__global__ void k_scan_local(const int* __restrict__ deg, int* __restrict__ row_ptr,
                             int* __restrict__ blk_sum) {
  __shared__ int sh[256];
  int t = threadIdx.x;
  int i = blockIdx.x * 256 + t;
  int v = (i < N_NODES) ? deg[i] : 0;
  sh[t] = v;
  __syncthreads();
  for (int off = 1; off < 256; off <<= 1) {
    int add = (t >= off) ? sh[t - off] : 0;
    __syncthreads();
    sh[t] += add;
    __syncthreads();
  }
  if (i < N_NODES) row_ptr[i] = sh[t] - v;
  if (t == 255) blk_sum[blockIdx.x] = sh[255];
}

__global__ void k_scan_blk(const int* __restrict__ blk_sum, int* __restrict__ blk_off) {
  __shared__ int sh[512];
  int t = threadIdx.x;
  int v = (t < SCAN_NBLK) ? blk_sum[t] : 0;
  sh[t] = v;
  __syncthreads();
  for (int off = 1; off < 512; off <<= 1) {
    int add = (t >= off) ? sh[t - off] : 0;
    __syncthreads();
    sh[t] += add;
    __syncthreads();
  }
  blk_off[t] = sh[t] - v;
}

__global__ void k_scan_add(int* __restrict__ row_ptr, const int* __restrict__ blk_off,
                           int* __restrict__ cursor) {
  int i = blockIdx.x * blockDim.x + threadIdx.x;
  if (i < N_NODES) {
    int v = row_ptr[i] + blk_off[i >> 8];
    row_ptr[i] = v;
    cursor[i] = v;
  }
  if (i == 0) row_ptr[N_NODES] = N_EDGES;
}

__global__ void k_fill(const int* __restrict__ src, const int* __restrict__ dst,
                       int* __restrict__ cursor, int* __restrict__ csr_src) {
  int e = blockIdx.x * blockDim.x + threadIdx.x;
  if (e >= N_EDGES) return;
  int pos = atomicAdd(cursor + dst[e], 1);
  csr_src[pos] = src[e];
}

// ---------------- pure-bf16 software-pipelined MFMA GEMM ----------------
// out_bf16[m][NN] = x[m][K] @ W + bc.  BM=128, BK=32, 2x2 wave grid, acc[4][CT].
// Ping-pong LDS (40KB total), register prefetch of tile i+1 issued before the
// MFMAs of tile i, ONE barrier per k-step (vs 2 in rounds 4-7 whose 93us was
// barrier/latency-structural, not pipe-bound).
template <int K, int NN, int BN, bool AF32>
__global__ __launch_bounds__(256) void k_gemm_bf16(const void* __restrict__ xin,
                                                   const ushort_t* __restrict__ WT,
                                                   const float* __restrict__ bc,
                                                   ushort_t* __restrict__ out, int M) {
  constexpr int BM    = 128;
  constexpr int BK    = 32;
  constexpr int LDA   = BK + 8;          // 40 ushorts = 80B rows
  constexpr int RT    = 4;
  constexpr int CT    = BN / 32;
  constexpr int NSTEP = K / BK;
  constexpr int NBCH  = (BN * 4) / 256;  // B chunks (8 ushorts) per thread
  __shared__ ushort_t As[2][BM * LDA];
  __shared__ ushort_t Bs[2][BN * LDA];
  const int tid  = threadIdx.x;
  const int wave = tid >> 6;
  const int wrow = wave >> 1;
  const int wcol = wave & 1;
  const int lane = tid & 63;
  const int quad = lane >> 4;
  const int l16  = lane & 15;
  const int m0   = blockIdx.x * BM;
  const int n0   = blockIdx.y * BN;

  const int arow = tid >> 1;
  const int aks  = (tid & 1) * 16;
  int gm = m0 + arow;
  if (gm >= M) gm = M - 1;

  float4 fA[4];
  uint4  uA[2];
  uint4  uB[NBCH];

  // ---- prefetch loaders ----
  auto loadT = [&](int k0) {
    if (AF32) {
      const float4* sp = (const float4*)((const float*)xin + (size_t)gm * K + k0 + aks);
      fA[0] = sp[0]; fA[1] = sp[1]; fA[2] = sp[2]; fA[3] = sp[3];
    } else {
      const uint4* sp = (const uint4*)((const ushort_t*)xin + (size_t)gm * K + k0 + aks);
      uA[0] = sp[0]; uA[1] = sp[1];
    }
#pragma unroll
    for (int c = 0; c < NBCH; ++c) {
      int ch = tid + c * 256;
      int n  = ch >> 2;
      int ks = (ch & 3) * 8;
      uB[c] = *(const uint4*)(WT + (size_t)(n0 + n) * K + k0 + ks);
    }
  };
  auto storeT = [&](int buf) {
    if (AF32) {
      uint4 p0, p1;
      p0.x = pack2(fA[0].x, fA[0].y); p0.y = pack2(fA[0].z, fA[0].w);
      p0.z = pack2(fA[1].x, fA[1].y); p0.w = pack2(fA[1].z, fA[1].w);
      p1.x = pack2(fA[2].x, fA[2].y); p1.y = pack2(fA[2].z, fA[2].w);
      p1.z = pack2(fA[3].x, fA[3].y); p1.w = pack2(fA[3].z, fA[3].w);
      *(uint4*)&As[buf][arow * LDA + aks]     = p0;
      *(uint4*)&As[buf][arow * LDA + aks + 8] = p1;
    } else {
      *(uint4*)&As[buf][arow * LDA + aks]     = uA[0];
      *(uint4*)&As[buf][arow * LDA + aks + 8] = uA[1];
    }
#pragma unroll
    for (int c = 0; c < NBCH; ++c) {
      int ch = tid + c * 256;
      int n  = ch >> 2;
      int ks = (ch & 3) * 8;
      *(uint4*)&Bs[buf][n * LDA + ks] = uB[c];
    }
  };

  ffrag acc[RT][CT];
#pragma unroll
  for (int rt = 0; rt < RT; ++rt)
#pragma unroll
    for (int ct = 0; ct < CT; ++ct) acc[rt][ct] = ffrag{0.f, 0.f, 0.f, 0.f};

  loadT(0);
  storeT(0);
  __syncthreads();

  for (int i = 0; i < NSTEP; ++i) {
    const int cur = i & 1;
    if (i + 1 < NSTEP) loadT((i + 1) * BK);   // global loads in flight over MFMAs
    bfrag a[RT], b[CT];
#pragma unroll
    for (int rt = 0; rt < RT; ++rt)
      a[rt] = *(const bfrag*)&As[cur][(wrow * 64 + rt * 16 + l16) * LDA + quad * 8];
#pragma unroll
    for (int ct = 0; ct < CT; ++ct)
      b[ct] = *(const bfrag*)&Bs[cur][(wcol * (BN / 2) + ct * 16 + l16) * LDA + quad * 8];
#pragma unroll
    for (int ct = 0; ct < CT; ++ct)
#pragma unroll
      for (int rt = 0; rt < RT; ++rt)
        acc[rt][ct] = __builtin_amdgcn_mfma_f32_16x16x32_bf16(a[rt], b[ct], acc[rt][ct], 0, 0, 0);
    if (i + 1 < NSTEP) storeT(1 - cur);
    __syncthreads();
  }

#pragma unroll
  for (int rt = 0; rt < RT; ++rt)
#pragma unroll
    for (int ct = 0; ct < CT; ++ct) {
      int n = n0 + wcol * (BN / 2) + ct * 16 + l16;
      float b = bc[n];
#pragma unroll
      for (int r = 0; r < 4; ++r) {
        int m = m0 + wrow * 64 + rt * 16 + quad * 4 + r;
        if (m < M) out[(size_t)m * NN + n] = f2bf(acc[rt][ct][r] + b);
      }
    }
}

// ---------------- fused per-node GAT edge pass (bf16 in, bf16 out) ----------------
template <int C>
__global__ void k_gat(const ushort_t* __restrict__ xlr, const int* __restrict__ row_ptr,
                      const int* __restrict__ csr_src, const float* __restrict__ att,
                      const float* __restrict__ bias, ushort_t* __restrict__ h) {
  constexpr int G = C / 8;          // lanes per edge group, 8 channels each
  constexpr int RS = 2 * C;         // row stride in ushorts
  int t = blockIdx.x * blockDim.x + threadIdx.x;
  int d = t / G;
  int lane = t - d * G;
  if (d >= N_NODES) return;
  float xr[8], a[8];
  {
    uint4 u = *(const uint4*)(xlr + (size_t)d * RS + C + lane * 8);
    float2 p0 = bfp(u.x), p1 = bfp(u.y), p2 = bfp(u.z), p3 = bfp(u.w);
    xr[0] = p0.x; xr[1] = p0.y; xr[2] = p1.x; xr[3] = p1.y;
    xr[4] = p2.x; xr[5] = p2.y; xr[6] = p3.x; xr[7] = p3.y;
  }
  *(float4*)&a[0] = *(const float4*)(att + lane * 8);
  *(float4*)&a[4] = *(const float4*)(att + lane * 8 + 4);
  float acc[8];
#pragma unroll
  for (int j = 0; j < 8; ++j) acc[j] = 0.f;
  float den = 0.f;
  const int e0 = row_ptr[d], e1 = row_ptr[d + 1];
  for (int i = e0; i < e1; ++i) {
    int s = csr_src[i];
    uint4 u = *(const uint4*)(xlr + (size_t)s * RS + lane * 8);
    float xl[8];
    {
      float2 p0 = bfp(u.x), p1 = bfp(u.y), p2 = bfp(u.z), p3 = bfp(u.w);
      xl[0] = p0.x; xl[1] = p0.y; xl[2] = p1.x; xl[3] = p1.y;
      xl[4] = p2.x; xl[5] = p2.y; xl[6] = p3.x; xl[7] = p3.y;
    }
    float p = 0.f;
#pragma unroll
    for (int j = 0; j < 8; ++j) {
      float v = xl[j] + xr[j];
      v = v > 0.f ? v : NEG * v;
      p += a[j] * v;
    }
#pragma unroll
    for (int off = G / 2; off > 0; off >>= 1) p += __shfl_xor(p, off, 64);
    float ex = expf(p);
    den += ex;
#pragma unroll
    for (int j = 0; j < 8; ++j) acc[j] += ex * xl[j];
  }
  float inv = 1.f / fmaxf(den, 1e-16f);
  float o[8];
#pragma unroll
  for (int j = 0; j < 8; ++j)
    o[j] = fmaxf(acc[j] * inv + bias[lane * 8 + j], 0.f);
  uint4 pk;
  pk.x = pack2(o[0], o[1]);
  pk.y = pack2(o[2], o[3]);
  pk.z = pack2(o[4], o[5]);
  pk.w = pack2(o[6], o[7]);
  *(uint4*)(h + (size_t)d * C + lane * 8) = pk;
}

// ---------------- pooling: sorted-batch run-accumulate (bf16 h3) ----------------
__global__ void k_pool(const ushort_t* __restrict__ h3, const int* __restrict__ batch,
                       float* __restrict__ pooled, float* __restrict__ cnt) {
  constexpr int NPB = 1024;
  constexpr int NPT = NPB / 8;
  int c = threadIdx.x & 31;
  int r = threadIdx.x >> 5;
  int base = blockIdx.x * NPB + r * NPT;
  if (base >= N_NODES) return;
  int end = base + NPT;
  if (end > N_NODES) end = N_NODES;
  int cur_b = batch[base];
  float acc = 0.f, count = 0.f;
  for (int n = base; n < end; ++n) {
    int b = batch[n];
    if (b != cur_b) {
      atomicAdd(pooled + cur_b * HC2C + c, acc);
      if (c == 0) atomicAdd(cnt + cur_b, count);
      cur_b = b;
      acc = 0.f;
      count = 0.f;
    }
    acc += bf2f(h3[(size_t)n * HC2C + c]);
    count += 1.f;
  }
  atomicAdd(pooled + cur_b * HC2C + c, acc);
  if (c == 0) atomicAdd(cnt + cur_b, count);
}

// ---------------- tail ----------------
__global__ void k_sx(const ushort_t* __restrict__ h3, const int* __restrict__ root,
                     const float* __restrict__ pooled, const float* __restrict__ cnt,
                     const float* __restrict__ linW, const float* __restrict__ linb,
                     float* __restrict__ sx) {
  int t = blockIdx.x * blockDim.x + threadIdx.x;
  if (t >= NB * HC2C) return;
  int b = t >> 5, j = t & 31;
  int r = root[b];
  float inv = 1.f / fmaxf(cnt[b], 1.0f);
  float a = linb[j];
  for (int c = 0; c < HC2C; ++c) a += bf2f(h3[(size_t)r * HC2C + c]) * linW[c * HC2C + j];
  for (int c = 0; c < HC2C; ++c) a += (pooled[b * HC2C + c] * inv) * linW[(HC2C + c) * HC2C + j];
  sx[t] = a > 0.f ? a : 0.f;
}

__global__ void k_info1(const float* __restrict__ X, const int* __restrict__ root,
                        const float* __restrict__ c1w, const float* __restrict__ c1b,
                        float* __restrict__ info) {
  constexpr int L = IN_F - 2;
  int t = blockIdx.x * blockDim.x + threadIdx.x;
  if (t >= NB * L) return;
  int b = t / L, i = t - (t / L) * L;
  const float* xr = X + (size_t)root[b] * IN_F;
  info[t] = c1w[0] * xr[i] + c1w[1] * xr[i + 1] + c1w[2] * xr[i + 2] + c1b[0];
}

__global__ void k_info2(const float* __restrict__ info, const float* __restrict__ c2W,
                        const float* __restrict__ c2b, float* __restrict__ t1) {
  constexpr int L = IN_F - 2;
  int t = blockIdx.x * blockDim.x + threadIdx.x;
  if (t >= HC1C * NB) return;
  int j = t >> 6, b = t & 63;
  float a = c2b[j];
  for (int i = 0; i < L; ++i) a += c2W[j * L + i] * info[b * L + i];
  t1[t] = a > 0.f ? a : 0.f;
}

__global__ void k_info3(const float* __restrict__ t1, const float* __restrict__ c3W,
                        const float* __restrict__ c3b, float* __restrict__ t2) {
  int t = blockIdx.x * blockDim.x + threadIdx.x;
  if (t >= NB * NB) return;
  int j = t >> 6, b = t & 63;
  float a = c3b[j];
  for (int i = 0; i < HC1C; ++i) a += c3W[j * HC1C + i] * t1[i * NB + b];
  t2[t] = a > 0.f ? a : 0.f;
}

__global__ void k_info4(const float* __restrict__ t2, float* __restrict__ tt) {
  int t = blockIdx.x * blockDim.x + threadIdx.x;
  if (t >= NB * HC2C) return;
  int b = t >> 5, c = t & 31;
  float v = 0.5f * (t2[(2 * c) * NB + b] + t2[(2 * c + 1) * NB + b]);
  tt[b * HC2C + c] = v > 0.f ? v : 0.f;
}

__global__ void k_final(const float* __restrict__ sx, const float* __restrict__ tt,
                        const float* __restrict__ aW1, const float* __restrict__ ab1,
                        const float* __restrict__ aW2, const float* __restrict__ mW1,
                        const float* __restrict__ mb1, const float* __restrict__ mW2,
                        const float* __restrict__ mb2, float* __restrict__ out) {
  int b = threadIdx.x;
  if (b >= NB) return;
  const float* e0 = sx + b * HC2C;
  const float* e1 = tt + b * HC2C;
  float w[2];
#pragma unroll
  for (int r = 0; r < 2; ++r) {
    const float* eb = (r == 0) ? e0 : e1;
    float acc = 0.f;
    for (int j = 0; j < 16; ++j) {
      float z = ab1[j];
      for (int c = 0; c < HC2C; ++c) z += eb[c] * aW1[c * 16 + j];
      acc += tanhf(z) * aW2[j];
    }
    w[r] = acc;
  }
  float mx = fmaxf(w[0], w[1]);
  float x0 = expf(w[0] - mx), x1 = expf(w[1] - mx);
  float inv = 1.f / (x0 + x1);
  float b0 = x0 * inv, b1 = x1 * inv;
  float t16[16];
  for (int j = 0; j < 16; ++j) {
    float z = mb1[j];
    for (int c = 0; c < HC2C; ++c) z += (b0 * e0[c] + b1 * e1[c]) * mW1[c * 16 + j];
    t16[j] = tanhf(z);
  }
  float l0 = mb2[0], l1 = mb2[1];
  for (int j = 0; j < 16; ++j) {
    l0 += t16[j] * mW2[j * 2 + 0];
    l1 += t16[j] * mW2[j * 2 + 1];
  }
  float m2 = fmaxf(l0, l1);
  float y0 = expf(l0 - m2), y1 = expf(l1 - m2);
  float is = 1.f / (y0 + y1);
  out[b * 2 + 0] = y0 * is;
  out[b * 2 + 1] = y1 * is;
}

// ---------------- launcher ----------------
extern "C" void kernel_launch(void* const* d_in, const int* in_sizes, int n_in, void* d_out,
                              int out_size, void* d_ws, size_t ws_size, hipStream_t stream) {
  if (ws_size < WS_FLOATS * sizeof(float)) return;

  const float* s_x   = (const float*)d_in[0];
  const int*   edge  = (const int*)d_in[1];
  const int*   batch = (const int*)d_in[2];
  const int*   root  = (const int*)d_in[3];
  const float* Wv    = (const float*)d_in[8];
  const float* bv    = (const float*)d_in[9];
  const float* Wl1   = (const float*)d_in[10];
  const float* bl1   = (const float*)d_in[11];
  const float* Wr1   = (const float*)d_in[12];
  const float* br1   = (const float*)d_in[13];
  const float* att1  = (const float*)d_in[14];
  const float* bias1 = (const float*)d_in[15];
  const float* Wl2   = (const float*)d_in[16];
  const float* bl2   = (const float*)d_in[17];
  const float* Wr2   = (const float*)d_in[18];
  const float* br2   = (const float*)d_in[19];
  const float* att2  = (const float*)d_in[20];
  const float* bias2 = (const float*)d_in[21];
  const float* Wl3   = (const float*)d_in[22];
  const float* bl3   = (const float*)d_in[23];
  const float* Wr3   = (const float*)d_in[24];
  const float* br3   = (const float*)d_in[25];
  const float* att3  = (const float*)d_in[26];
  const float* bias3 = (const float*)d_in[27];
  const float* c1w   = (const float*)d_in[28];
  const float* c1b   = (const float*)d_in[29];
  const float* c2W   = (const float*)d_in[30];
  const float* c2b   = (const float*)d_in[31];
  const float* c3W   = (const float*)d_in[32];
  const float* c3b   = (const float*)d_in[33];
  const float* linW  = (const float*)d_in[34];
  const float* linb  = (const float*)d_in[35];
  const float* aW1   = (const float*)d_in[36];
  const float* ab1   = (const float*)d_in[37];
  const float* aW2   = (const float*)d_in[38];
  const float* mW1   = (const float*)d_in[39];
  const float* mb1   = (const float*)d_in[40];
  const float* mW2   = (const float*)d_in[41];
  const float* mb2   = (const float*)d_in[42];

  const int* src = edge;
  const int* dst = edge + N_EDGES;

  float*    ws      = (float*)d_ws;
  ushort_t* WT1     = (ushort_t*)(ws + OFF_WT1);
  ushort_t* WT2     = (ushort_t*)(ws + OFF_WT2);
  ushort_t* WT3     = (ushort_t*)(ws + OFF_WT3);
  float*    bc1     = ws + OFF_BC1;
  float*    bc2     = ws + OFF_BC2;
  float*    bc3     = ws + OFF_BC3;
  ushort_t* xlr     = (ushort_t*)(ws + OFF_XLR);
  ushort_t* hbuf    = (ushort_t*)(ws + OFF_H);
  int*      deg     = (int*)(ws + OFF_DEG);
  int*      row_ptr = (int*)(ws + OFF_ROWPTR);
  int*      cursor  = (int*)(ws + OFF_CURSOR);
  int*      blks    = (int*)(ws + OFF_BLKS);
  int*      blko    = (int*)(ws + OFF_BLKO);
  int*      csr_src = (int*)(ws + OFF_CSRSRC);
  float*    pooled  = ws + OFF_POOLED;
  float*    cnt     = ws + OFF_CNT;
  float*    sx      = ws + OFF_SX;
  float*    info    = ws + OFF_INFO;
  float*    t1      = ws + OFF_T1;
  float*    t2      = ws + OFF_T2;
  float*    tt      = ws + OFF_TT;
  float*    out     = (float*)d_out;

  // ---- CSR build (by dst) ----
  hipMemsetAsync(deg, 0, N_NODES * sizeof(int), stream);
  k_hist<<<(N_EDGES + 255) / 256, 256, 0, stream>>>(dst, deg);
  k_scan_local<<<SCAN_NBLK, 256, 0, stream>>>(deg, row_ptr, blks);
  k_scan_blk<<<1, 512, 0, stream>>>(blks, blko);
  k_scan_add<<<SCAN_NBLK, 256, 0, stream>>>(row_ptr, blko, cursor);
  k_fill<<<(N_EDGES + 255) / 256, 256, 0, stream>>>(src, dst, cursor, csr_src);

  // ---- weight fold / pack ----
  k_wcomb<<<(256 * 256) / 256, 256, 0, stream>>>(Wv, Wl1, Wr1, WT1);
  k_bcomb<<<1, 256, 0, stream>>>(bv, Wl1, bl1, Wr1, br1, bc1);
  k_wpack<128, 64><<<(128 * 128 + 255) / 256, 256, 0, stream>>>(Wl2, bl2, Wr2, br2, WT2, bc2);
  k_wpack<64, 32><<<(64 * 64 + 255) / 256, 256, 0, stream>>>(Wl3, bl3, Wr3, br3, WT3, bc3);

  // ---- GAT layer 1 (K=256, N=256) ----
  k_gemm_bf16<256, 256, 128, true><<<dim3(MB128, 2), 256, 0, stream>>>(s_x, WT1, bc1, xlr,
                                                                       N_NODES);
  k_gat<128><<<(N_NODES * 16 + 255) / 256, 256, 0, stream>>>(xlr, row_ptr, csr_src, att1,
                                                             bias1, hbuf);

  // ---- GAT layer 2 (K=128, N=128) ----
  k_gemm_bf16<128, 128, 128, false><<<dim3(MB128, 1), 256, 0, stream>>>(hbuf, WT2, bc2, xlr,
                                                                        N_NODES);
  k_gat<64><<<(N_NODES * 8 + 255) / 256, 256, 0, stream>>>(xlr, row_ptr, csr_src, att2,
                                                           bias2, hbuf);

  // ---- GAT layer 3 (K=64, N=64) ----
  k_gemm_bf16<64, 64, 64, false><<<dim3(MB128, 1), 256, 0, stream>>>(hbuf, WT3, bc3, xlr,
                                                                     N_NODES);
  k_gat<32><<<(N_NODES * 4 + 255) / 256, 256, 0, stream>>>(xlr, row_ptr, csr_src, att3,
                                                           bias3, hbuf);

  // ---- pooling + root concat + lin ----
  hipMemsetAsync(pooled, 0, (NB * HC2C + NB) * sizeof(float), stream);
  k_pool<<<(N_NODES + 1023) / 1024, 256, 0, stream>>>(hbuf, batch, pooled, cnt);
  k_sx<<<(NB * HC2C + 255) / 256, 256, 0, stream>>>(hbuf, root, pooled, cnt, linW, linb, sx);

  // ---- info path ----
  k_info1<<<(NB * (IN_F - 2) + 255) / 256, 256, 0, stream>>>(s_x, root, c1w, c1b, info);
  k_info2<<<(HC1C * NB + 255) / 256, 256, 0, stream>>>(info, c2W, c2b, t1);
  k_info3<<<(NB * NB + 255) / 256, 256, 0, stream>>>(t1, c3W, c3b, t2);
  k_info4<<<(NB * HC2C + 255) / 256, 256, 0, stream>>>(t2, tt);

  // ---- attention combine + classifier ----
  k_final<<<1, NB, 0, stream>>>(sx, tt, aW1, ab1, aW2, mW1, mb1, mW2, mb2, out);
}

// Round 9
// 655.095 us; speedup vs baseline: 1.2124x; 1.0392x over previous
//
#include <hip/hip_runtime.h>
#include <hip/hip_bf16.h>
#include <math.h>

typedef unsigned short ushort_t;
typedef __attribute__((ext_vector_type(8))) short bfrag;   // 8 bf16 = 4 VGPRs
typedef __attribute__((ext_vector_type(4))) float ffrag;   // 4 fp32 acc

// ---------------- problem constants ----------------
constexpr int N_NODES = 100000;
constexpr int N_EDGES = 800000;
constexpr int NB      = 64;
constexpr int IN_F    = 256;
constexpr int HC1C    = 128;
constexpr int HC2C    = 32;
constexpr int SA_D    = 350;
constexpr float NEG   = 0.2f;

constexpr int SCAN_NBLK = (N_NODES + 255) / 256;  // 391
constexpr int MB128     = (N_NODES + 127) / 128;  // 782

// ---------------- workspace layout (float-sized slots) ----------------
constexpr size_t OFF_WT1    = 0;                                   // 256*256 ush
constexpr size_t OFF_WT2    = OFF_WT1 + 65536;
constexpr size_t OFF_WT3    = OFF_WT2 + 16384;
constexpr size_t OFF_BC1    = OFF_WT3 + 4096;                      // 256
constexpr size_t OFF_BC2    = OFF_BC1 + 256;                       // 128
constexpr size_t OFF_BC3    = OFF_BC2 + 128;                       // 64
constexpr size_t OFF_XLR    = OFF_BC3 + 64;                        // N*256 bf16
constexpr size_t OFF_H      = OFF_XLR + (size_t)N_NODES * 256;     // N*128 bf16
constexpr size_t OFF_DEG    = OFF_H + (size_t)N_NODES * 128;       // N ints
constexpr size_t OFF_ROWPTR = OFF_DEG + N_NODES;                   // N+1 ints
constexpr size_t OFF_CURSOR = OFF_ROWPTR + N_NODES + 1;            // N ints
constexpr size_t OFF_BLKS   = OFF_CURSOR + N_NODES;                // 512 ints
constexpr size_t OFF_BLKO   = OFF_BLKS + 512;                      // 512 ints
constexpr size_t OFF_CSRSRC = OFF_BLKO + 512;                      // E ints
constexpr size_t OFF_POOLED = OFF_CSRSRC + N_EDGES;                // 64*32
constexpr size_t OFF_CNT    = OFF_POOLED + NB * HC2C;              // 64
constexpr size_t OFF_SX     = OFF_CNT + NB;                        // 64*32
constexpr size_t OFF_INFO   = OFF_SX + NB * HC2C;                  // 64*254
constexpr size_t OFF_T1     = OFF_INFO + (size_t)NB * (IN_F - 2);  // 128*64
constexpr size_t OFF_T2     = OFF_T1 + (size_t)HC1C * NB;          // 64*64
constexpr size_t OFF_TT     = OFF_T2 + (size_t)NB * NB;            // 64*32
constexpr size_t WS_FLOATS  = OFF_TT + NB * HC2C;

// ---------------- bf16 helpers ----------------
__device__ __forceinline__ ushort_t f2bf(float f) {  // RNE
  union { float f; unsigned int u; } a;
  a.f = f;
  unsigned int r = a.u + 0x7FFFu + ((a.u >> 16) & 1u);
  return (ushort_t)(r >> 16);
}
__device__ __forceinline__ float bf2f(ushort_t h) {
  union { unsigned int u; float f; } a;
  a.u = ((unsigned int)h) << 16;
  return a.f;
}
// unpack 2 bf16 packed in a dword (element order: low ushort first)
__device__ __forceinline__ float2 bfp(unsigned int u) {
  float2 r;
  r.x = __uint_as_float(u << 16);
  r.y = __uint_as_float(u & 0xFFFF0000u);
  return r;
}
// RNE-pack 2 floats (a = even/lower-address element) into one dword
__device__ __forceinline__ unsigned int pack2(float a, float b) {
  unsigned int ua = __float_as_uint(a);
  ua += 0x7FFFu + ((ua >> 16) & 1u);
  unsigned int ub = __float_as_uint(b);
  ub += 0x7FFFu + ((ub >> 16) & 1u);
  return __builtin_amdgcn_perm(ub, ua, 0x07060302u);
}

// ---------------- weight fold / pack (transposed WT[n][k], bf16 RNE) -------
__global__ void k_wcomb(const float* __restrict__ Wv, const float* __restrict__ Wl1,
                        const float* __restrict__ Wr1, ushort_t* __restrict__ WT) {
  int t = blockIdx.x * blockDim.x + threadIdx.x;
  if (t >= 256 * 256) return;
  int n = t & 255;
  int k = t >> 8;
  const float* Wx = (n < 128) ? Wl1 : Wr1;
  int j = n & 127;
  float a = 0.f;
  for (int kk = 0; kk < SA_D; ++kk) a += Wv[k * SA_D + kk] * Wx[kk * 128 + j];
  WT[(size_t)n * 256 + k] = f2bf(a);
}

__global__ void k_bcomb(const float* __restrict__ bv, const float* __restrict__ Wl1,
                        const float* __restrict__ bl1, const float* __restrict__ Wr1,
                        const float* __restrict__ br1, float* __restrict__ bc) {
  int n = threadIdx.x;
  if (n >= 256) return;
  const float* Wx = (n < 128) ? Wl1 : Wr1;
  const float* bx = (n < 128) ? bl1 : br1;
  int j = n & 127;
  float a = bx[j];
  for (int kk = 0; kk < SA_D; ++kk) a += bv[kk] * Wx[kk * 128 + j];
  bc[n] = a;
}

template <int K, int C>
__global__ void k_wpack(const float* __restrict__ Wl, const float* __restrict__ bl,
                        const float* __restrict__ Wr, const float* __restrict__ br,
                        ushort_t* __restrict__ WT, float* __restrict__ bc) {
  constexpr int NN = 2 * C;
  int t = blockIdx.x * blockDim.x + threadIdx.x;
  if (t < NN) bc[t] = (t < C) ? bl[t] : br[t - C];
  if (t >= NN * K) return;
  int n = t % NN;
  int k = t / NN;
  float v = (n < C) ? Wl[k * C + n] : Wr[k * C + (n - C)];
  WT[(size_t)n * K + k] = f2bf(v);
}

// ---------------- CSR build ----------------
__global__ void k_hist(const int* __restrict__ dst, int* __restrict__ deg) {
  int e = blockIdx.x * blockDim.x + threadIdx.x;
  if (e < N_EDGES) atomicAdd(deg + dst[e], 1);
}

__global__ void k_scan_local(const int* __restrict__ deg, int* __restrict__ row_ptr,
                             int* __restrict__ blk_sum) {
  __shared__ int sh[256];
  int t = threadIdx.x;
  int i = blockIdx.x * 256 + t;
  int v = (i < N_NODES) ? deg[i] : 0;
  sh[t] = v;
  __syncthreads();
  for (int off = 1; off < 256; off <<= 1) {
    int add = (t >= off) ? sh[t - off] : 0;
    __syncthreads();
    sh[t] += add;
    __syncthreads();
  }
  if (i < N_NODES) row_ptr[i] = sh[t] - v;
  if (t == 255) blk_sum[blockIdx.x] = sh[255];
}

__global__ void k_scan_blk(const int* __restrict__ blk_sum, int* __restrict__ blk_off) {
  __shared__ int sh[512];
  int t = threadIdx.x;
  int v = (t < SCAN_NBLK) ? blk_sum[t] : 0;
  sh[t] = v;
  __syncthreads();
  for (int off = 1; off < 512; off <<= 1) {
    int add = (t >= off) ? sh[t - off] : 0;
    __syncthreads();
    sh[t] += add;
    __syncthreads();
  }
  blk_off[t] = sh[t] - v;
}

__global__ void k_scan_add(int* __restrict__ row_ptr, const int* __restrict__ blk_off,
                           int* __restrict__ cursor) {
  int i = blockIdx.x * blockDim.x + threadIdx.x;
  if (i < N_NODES) {
    int v = row_ptr[i] + blk_off[i >> 8];
    row_ptr[i] = v;
    cursor[i] = v;
  }
  if (i == 0) row_ptr[N_NODES] = N_EDGES;
}

__global__ void k_fill(const int* __restrict__ src, const int* __restrict__ dst,
                       int* __restrict__ cursor, int* __restrict__ csr_src) {
  int e = blockIdx.x * blockDim.x + threadIdx.x;
  if (e >= N_EDGES) return;
  int pos = atomicAdd(cursor + dst[e], 1);
  csr_src[pos] = src[e];
}

// ---------------- pure-bf16 MFMA GEMM, BK=64, single LDS buffer ----------------
// out_bf16[m][NN] = x[m][K] @ W + bc.  BM=128, 2x2 wave grid, acc[4][CT].
// Simple 2-barrier k-step (round-8's register-prefetch pipeline SPILLED:
// WRITE_SIZE 50->126MB at VGPR=76 -- scratch traffic ate the pipeline gain).
// BK=64 halves barrier count vs BK=32; staging = 8 independent float4
// loads/thread (MLP without holding regs across MFMAs); LDS 37KB -> 4 blocks/CU.
template <int K, int NN, int BN, bool AF32>
__global__ __launch_bounds__(256) void k_gemm_bf16(const void* __restrict__ xin,
                                                   const ushort_t* __restrict__ WT,
                                                   const float* __restrict__ bc,
                                                   ushort_t* __restrict__ out, int M) {
  constexpr int BM    = 128;
  constexpr int BK    = 64;
  constexpr int LDA   = BK + 8;          // 72 ushorts = 144B rows (16B aligned)
  constexpr int RT    = 4;
  constexpr int CT    = BN / 32;
  constexpr int NSTEP = K / BK;
  __shared__ ushort_t As[BM * LDA];
  __shared__ ushort_t Bs[BN * LDA];
  const int tid  = threadIdx.x;
  const int wave = tid >> 6;
  const int wrow = wave >> 1;
  const int wcol = wave & 1;
  const int lane = tid & 63;
  const int quad = lane >> 4;
  const int l16  = lane & 15;
  const int m0   = blockIdx.x * BM;
  const int n0   = blockIdx.y * BN;

  const int arow = tid >> 1;         // 2 threads per row
  const int aks  = (tid & 1) * 32;   // each owns 32 k-elements
  int gm = m0 + arow;
  if (gm >= M) gm = M - 1;

  ffrag acc[RT][CT];
#pragma unroll
  for (int rt = 0; rt < RT; ++rt)
#pragma unroll
    for (int ct = 0; ct < CT; ++ct) acc[rt][ct] = ffrag{0.f, 0.f, 0.f, 0.f};

  for (int i = 0; i < NSTEP; ++i) {
    const int k0 = i * BK;
    if (i) __syncthreads();   // LDS reuse: previous step's reads done
    // ---- stage A (128 x 64) ----
    if (AF32) {
      const float4* sp = (const float4*)((const float*)xin + (size_t)gm * K + k0 + aks);
      float4 f[8];
#pragma unroll
      for (int j = 0; j < 8; ++j) f[j] = sp[j];
      unsigned int d[16];
#pragma unroll
      for (int j = 0; j < 8; ++j) {
        d[2 * j]     = pack2(f[j].x, f[j].y);
        d[2 * j + 1] = pack2(f[j].z, f[j].w);
      }
#pragma unroll
      for (int j = 0; j < 4; ++j)
        *(uint4*)&As[arow * LDA + aks + j * 8] = *(uint4*)&d[j * 4];
    } else {
      const uint4* sp = (const uint4*)((const ushort_t*)xin + (size_t)gm * K + k0 + aks);
      uint4 u[4];
#pragma unroll
      for (int j = 0; j < 4; ++j) u[j] = sp[j];
#pragma unroll
      for (int j = 0; j < 4; ++j)
        *(uint4*)&As[arow * LDA + aks + j * 8] = u[j];
    }
    // ---- stage B (BN x 64) ----
#pragma unroll
    for (int c = 0; c < BN / 32; ++c) {
      int ch = tid + c * 256;
      int n  = ch >> 3;
      int ks = (ch & 7) * 8;
      *(uint4*)&Bs[n * LDA + ks] = *(const uint4*)(WT + (size_t)(n0 + n) * K + k0 + ks);
    }
    __syncthreads();
    // ---- compute: 2 k-halves of 32 ----
#pragma unroll
    for (int kh = 0; kh < 2; ++kh) {
      bfrag a[RT], b[CT];
#pragma unroll
      for (int rt = 0; rt < RT; ++rt)
        a[rt] = *(const bfrag*)&As[(wrow * 64 + rt * 16 + l16) * LDA + kh * 32 + quad * 8];
#pragma unroll
      for (int ct = 0; ct < CT; ++ct)
        b[ct] = *(const bfrag*)&Bs[(wcol * (BN / 2) + ct * 16 + l16) * LDA + kh * 32 + quad * 8];
#pragma unroll
      for (int ct = 0; ct < CT; ++ct)
#pragma unroll
        for (int rt = 0; rt < RT; ++rt)
          acc[rt][ct] = __builtin_amdgcn_mfma_f32_16x16x32_bf16(a[rt], b[ct], acc[rt][ct], 0, 0, 0);
    }
  }

#pragma unroll
  for (int rt = 0; rt < RT; ++rt)
#pragma unroll
    for (int ct = 0; ct < CT; ++ct) {
      int n = n0 + wcol * (BN / 2) + ct * 16 + l16;
      float b = bc[n];
#pragma unroll
      for (int r = 0; r < 4; ++r) {
        int m = m0 + wrow * 64 + rt * 16 + quad * 4 + r;
        if (m < M) out[(size_t)m * NN + n] = f2bf(acc[rt][ct][r] + b);
      }
    }
}

// ---------------- fused per-node GAT edge pass (bf16, 2-edge unrolled) -------
// Edge loop was a serial load->use chain (1 gather in flight per lane group);
// 2-edge unroll doubles L3-latency-bound MLP.
template <int C>
__global__ void k_gat(const ushort_t* __restrict__ xlr, const int* __restrict__ row_ptr,
                      const int* __restrict__ csr_src, const float* __restrict__ att,
                      const float* __restrict__ bias, ushort_t* __restrict__ h) {
  constexpr int G = C / 8;          // lanes per edge group, 8 channels each
  constexpr int RS = 2 * C;         // row stride in ushorts
  int t = blockIdx.x * blockDim.x + threadIdx.x;
  int d = t / G;
  int lane = t - d * G;
  if (d >= N_NODES) return;
  float xr[8], a[8];
  {
    uint4 u = *(const uint4*)(xlr + (size_t)d * RS + C + lane * 8);
    float2 p0 = bfp(u.x), p1 = bfp(u.y), p2 = bfp(u.z), p3 = bfp(u.w);
    xr[0] = p0.x; xr[1] = p0.y; xr[2] = p1.x; xr[3] = p1.y;
    xr[4] = p2.x; xr[5] = p2.y; xr[6] = p3.x; xr[7] = p3.y;
  }
  *(float4*)&a[0] = *(const float4*)(att + lane * 8);
  *(float4*)&a[4] = *(const float4*)(att + lane * 8 + 4);
  float acc[8];
#pragma unroll
  for (int j = 0; j < 8; ++j) acc[j] = 0.f;
  float den = 0.f;
  const int e0 = row_ptr[d], e1 = row_ptr[d + 1];
  int i = e0;
  for (; i + 2 <= e1; i += 2) {
    int s0 = csr_src[i];
    int s1 = csr_src[i + 1];
    uint4 u0 = *(const uint4*)(xlr + (size_t)s0 * RS + lane * 8);
    uint4 u1 = *(const uint4*)(xlr + (size_t)s1 * RS + lane * 8);
    float xl0[8], xl1[8];
    {
      float2 q0 = bfp(u0.x), q1 = bfp(u0.y), q2 = bfp(u0.z), q3 = bfp(u0.w);
      xl0[0] = q0.x; xl0[1] = q0.y; xl0[2] = q1.x; xl0[3] = q1.y;
      xl0[4] = q2.x; xl0[5] = q2.y; xl0[6] = q3.x; xl0[7] = q3.y;
      float2 r0 = bfp(u1.x), r1 = bfp(u1.y), r2 = bfp(u1.z), r3 = bfp(u1.w);
      xl1[0] = r0.x; xl1[1] = r0.y; xl1[2] = r1.x; xl1[3] = r1.y;
      xl1[4] = r2.x; xl1[5] = r2.y; xl1[6] = r3.x; xl1[7] = r3.y;
    }
    float p0 = 0.f, p1 = 0.f;
#pragma unroll
    for (int j = 0; j < 8; ++j) {
      float v0 = xl0[j] + xr[j];
      v0 = v0 > 0.f ? v0 : NEG * v0;
      p0 += a[j] * v0;
      float v1 = xl1[j] + xr[j];
      v1 = v1 > 0.f ? v1 : NEG * v1;
      p1 += a[j] * v1;
    }
#pragma unroll
    for (int off = G / 2; off > 0; off >>= 1) {
      p0 += __shfl_xor(p0, off, 64);
      p1 += __shfl_xor(p1, off, 64);
    }
    float ex0 = expf(p0);
    float ex1 = expf(p1);
    den += ex0 + ex1;
#pragma unroll
    for (int j = 0; j < 8; ++j) acc[j] += ex0 * xl0[j] + ex1 * xl1[j];
  }
  if (i < e1) {
    int s = csr_src[i];
    uint4 u = *(const uint4*)(xlr + (size_t)s * RS + lane * 8);
    float xl[8];
    {
      float2 q0 = bfp(u.x), q1 = bfp(u.y), q2 = bfp(u.z), q3 = bfp(u.w);
      xl[0] = q0.x; xl[1] = q0.y; xl[2] = q1.x; xl[3] = q1.y;
      xl[4] = q2.x; xl[5] = q2.y; xl[6] = q3.x; xl[7] = q3.y;
    }
    float p = 0.f;
#pragma unroll
    for (int j = 0; j < 8; ++j) {
      float v = xl[j] + xr[j];
      v = v > 0.f ? v : NEG * v;
      p += a[j] * v;
    }
#pragma unroll
    for (int off = G / 2; off > 0; off >>= 1) p += __shfl_xor(p, off, 64);
    float ex = expf(p);
    den += ex;
#pragma unroll
    for (int j = 0; j < 8; ++j) acc[j] += ex * xl[j];
  }
  float inv = 1.f / fmaxf(den, 1e-16f);
  float o[8];
#pragma unroll
  for (int j = 0; j < 8; ++j)
    o[j] = fmaxf(acc[j] * inv + bias[lane * 8 + j], 0.f);
  uint4 pk;
  pk.x = pack2(o[0], o[1]);
  pk.y = pack2(o[2], o[3]);
  pk.z = pack2(o[4], o[5]);
  pk.w = pack2(o[6], o[7]);
  *(uint4*)(h + (size_t)d * C + lane * 8) = pk;
}

// ---------------- pooling: sorted-batch run-accumulate (bf16 h3) ----------------
__global__ void k_pool(const ushort_t* __restrict__ h3, const int* __restrict__ batch,
                       float* __restrict__ pooled, float* __restrict__ cnt) {
  constexpr int NPB = 1024;
  constexpr int NPT = NPB / 8;
  int c = threadIdx.x & 31;
  int r = threadIdx.x >> 5;
  int base = blockIdx.x * NPB + r * NPT;
  if (base >= N_NODES) return;
  int end = base + NPT;
  if (end > N_NODES) end = N_NODES;
  int cur_b = batch[base];
  float acc = 0.f, count = 0.f;
  for (int n = base; n < end; ++n) {
    int b = batch[n];
    if (b != cur_b) {
      atomicAdd(pooled + cur_b * HC2C + c, acc);
      if (c == 0) atomicAdd(cnt + cur_b, count);
      cur_b = b;
      acc = 0.f;
      count = 0.f;
    }
    acc += bf2f(h3[(size_t)n * HC2C + c]);
    count += 1.f;
  }
  atomicAdd(pooled + cur_b * HC2C + c, acc);
  if (c == 0) atomicAdd(cnt + cur_b, count);
}

// ---------------- tail ----------------
__global__ void k_sx(const ushort_t* __restrict__ h3, const int* __restrict__ root,
                     const float* __restrict__ pooled, const float* __restrict__ cnt,
                     const float* __restrict__ linW, const float* __restrict__ linb,
                     float* __restrict__ sx) {
  int t = blockIdx.x * blockDim.x + threadIdx.x;
  if (t >= NB * HC2C) return;
  int b = t >> 5, j = t & 31;
  int r = root[b];
  float inv = 1.f / fmaxf(cnt[b], 1.0f);
  float a = linb[j];
  for (int c = 0; c < HC2C; ++c) a += bf2f(h3[(size_t)r * HC2C + c]) * linW[c * HC2C + j];
  for (int c = 0; c < HC2C; ++c) a += (pooled[b * HC2C + c] * inv) * linW[(HC2C + c) * HC2C + j];
  sx[t] = a > 0.f ? a : 0.f;
}

__global__ void k_info1(const float* __restrict__ X, const int* __restrict__ root,
                        const float* __restrict__ c1w, const float* __restrict__ c1b,
                        float* __restrict__ info) {
  constexpr int L = IN_F - 2;
  int t = blockIdx.x * blockDim.x + threadIdx.x;
  if (t >= NB * L) return;
  int b = t / L, i = t - (t / L) * L;
  const float* xr = X + (size_t)root[b] * IN_F;
  info[t] = c1w[0] * xr[i] + c1w[1] * xr[i + 1] + c1w[2] * xr[i + 2] + c1b[0];
}

__global__ void k_info2(const float* __restrict__ info, const float* __restrict__ c2W,
                        const float* __restrict__ c2b, float* __restrict__ t1) {
  constexpr int L = IN_F - 2;
  int t = blockIdx.x * blockDim.x + threadIdx.x;
  if (t >= HC1C * NB) return;
  int j = t >> 6, b = t & 63;
  float a = c2b[j];
  for (int i = 0; i < L; ++i) a += c2W[j * L + i] * info[b * L + i];
  t1[t] = a > 0.f ? a : 0.f;
}

__global__ void k_info3(const float* __restrict__ t1, const float* __restrict__ c3W,
                        const float* __restrict__ c3b, float* __restrict__ t2) {
  int t = blockIdx.x * blockDim.x + threadIdx.x;
  if (t >= NB * NB) return;
  int j = t >> 6, b = t & 63;
  float a = c3b[j];
  for (int i = 0; i < HC1C; ++i) a += c3W[j * HC1C + i] * t1[i * NB + b];
  t2[t] = a > 0.f ? a : 0.f;
}

__global__ void k_info4(const float* __restrict__ t2, float* __restrict__ tt) {
  int t = blockIdx.x * blockDim.x + threadIdx.x;
  if (t >= NB * HC2C) return;
  int b = t >> 5, c = t & 31;
  float v = 0.5f * (t2[(2 * c) * NB + b] + t2[(2 * c + 1) * NB + b]);
  tt[b * HC2C + c] = v > 0.f ? v : 0.f;
}

__global__ void k_final(const float* __restrict__ sx, const float* __restrict__ tt,
                        const float* __restrict__ aW1, const float* __restrict__ ab1,
                        const float* __restrict__ aW2, const float* __restrict__ mW1,
                        const float* __restrict__ mb1, const float* __restrict__ mW2,
                        const float* __restrict__ mb2, float* __restrict__ out) {
  int b = threadIdx.x;
  if (b >= NB) return;
  const float* e0 = sx + b * HC2C;
  const float* e1 = tt + b * HC2C;
  float w[2];
#pragma unroll
  for (int r = 0; r < 2; ++r) {
    const float* eb = (r == 0) ? e0 : e1;
    float acc = 0.f;
    for (int j = 0; j < 16; ++j) {
      float z = ab1[j];
      for (int c = 0; c < HC2C; ++c) z += eb[c] * aW1[c * 16 + j];
      acc += tanhf(z) * aW2[j];
    }
    w[r] = acc;
  }
  float mx = fmaxf(w[0], w[1]);
  float x0 = expf(w[0] - mx), x1 = expf(w[1] - mx);
  float inv = 1.f / (x0 + x1);
  float b0 = x0 * inv, b1 = x1 * inv;
  float t16[16];
  for (int j = 0; j < 16; ++j) {
    float z = mb1[j];
    for (int c = 0; c < HC2C; ++c) z += (b0 * e0[c] + b1 * e1[c]) * mW1[c * 16 + j];
    t16[j] = tanhf(z);
  }
  float l0 = mb2[0], l1 = mb2[1];
  for (int j = 0; j < 16; ++j) {
    l0 += t16[j] * mW2[j * 2 + 0];
    l1 += t16[j] * mW2[j * 2 + 1];
  }
  float m2 = fmaxf(l0, l1);
  float y0 = expf(l0 - m2), y1 = expf(l1 - m2);
  float is = 1.f / (y0 + y1);
  out[b * 2 + 0] = y0 * is;
  out[b * 2 + 1] = y1 * is;
}

// ---------------- launcher ----------------
extern "C" void kernel_launch(void* const* d_in, const int* in_sizes, int n_in, void* d_out,
                              int out_size, void* d_ws, size_t ws_size, hipStream_t stream) {
  if (ws_size < WS_FLOATS * sizeof(float)) return;

  const float* s_x   = (const float*)d_in[0];
  const int*   edge  = (const int*)d_in[1];
  const int*   batch = (const int*)d_in[2];
  const int*   root  = (const int*)d_in[3];
  const float* Wv    = (const float*)d_in[8];
  const float* bv    = (const float*)d_in[9];
  const float* Wl1   = (const float*)d_in[10];
  const float* bl1   = (const float*)d_in[11];
  const float* Wr1   = (const float*)d_in[12];
  const float* br1   = (const float*)d_in[13];
  const float* att1  = (const float*)d_in[14];
  const float* bias1 = (const float*)d_in[15];
  const float* Wl2   = (const float*)d_in[16];
  const float* bl2   = (const float*)d_in[17];
  const float* Wr2   = (const float*)d_in[18];
  const float* br2   = (const float*)d_in[19];
  const float* att2  = (const float*)d_in[20];
  const float* bias2 = (const float*)d_in[21];
  const float* Wl3   = (const float*)d_in[22];
  const float* bl3   = (const float*)d_in[23];
  const float* Wr3   = (const float*)d_in[24];
  const float* br3   = (const float*)d_in[25];
  const float* att3  = (const float*)d_in[26];
  const float* bias3 = (const float*)d_in[27];
  const float* c1w   = (const float*)d_in[28];
  const float* c1b   = (const float*)d_in[29];
  const float* c2W   = (const float*)d_in[30];
  const float* c2b   = (const float*)d_in[31];
  const float* c3W   = (const float*)d_in[32];
  const float* c3b   = (const float*)d_in[33];
  const float* linW  = (const float*)d_in[34];
  const float* linb  = (const float*)d_in[35];
  const float* aW1   = (const float*)d_in[36];
  const float* ab1   = (const float*)d_in[37];
  const float* aW2   = (const float*)d_in[38];
  const float* mW1   = (const float*)d_in[39];
  const float* mb1   = (const float*)d_in[40];
  const float* mW2   = (const float*)d_in[41];
  const float* mb2   = (const float*)d_in[42];

  const int* src = edge;
  const int* dst = edge + N_EDGES;

  float*    ws      = (float*)d_ws;
  ushort_t* WT1     = (ushort_t*)(ws + OFF_WT1);
  ushort_t* WT2     = (ushort_t*)(ws + OFF_WT2);
  ushort_t* WT3     = (ushort_t*)(ws + OFF_WT3);
  float*    bc1     = ws + OFF_BC1;
  float*    bc2     = ws + OFF_BC2;
  float*    bc3     = ws + OFF_BC3;
  ushort_t* xlr     = (ushort_t*)(ws + OFF_XLR);
  ushort_t* hbuf    = (ushort_t*)(ws + OFF_H);
  int*      deg     = (int*)(ws + OFF_DEG);
  int*      row_ptr = (int*)(ws + OFF_ROWPTR);
  int*      cursor  = (int*)(ws + OFF_CURSOR);
  int*      blks    = (int*)(ws + OFF_BLKS);
  int*      blko    = (int*)(ws + OFF_BLKO);
  int*      csr_src = (int*)(ws + OFF_CSRSRC);
  float*    pooled  = ws + OFF_POOLED;
  float*    cnt     = ws + OFF_CNT;
  float*    sx      = ws + OFF_SX;
  float*    info    = ws + OFF_INFO;
  float*    t1      = ws + OFF_T1;
  float*    t2      = ws + OFF_T2;
  float*    tt      = ws + OFF_TT;
  float*    out     = (float*)d_out;

  // ---- CSR build (by dst) ----
  hipMemsetAsync(deg, 0, N_NODES * sizeof(int), stream);
  k_hist<<<(N_EDGES + 255) / 256, 256, 0, stream>>>(dst, deg);
  k_scan_local<<<SCAN_NBLK, 256, 0, stream>>>(deg, row_ptr, blks);
  k_scan_blk<<<1, 512, 0, stream>>>(blks, blko);
  k_scan_add<<<SCAN_NBLK, 256, 0, stream>>>(row_ptr, blko, cursor);
  k_fill<<<(N_EDGES + 255) / 256, 256, 0, stream>>>(src, dst, cursor, csr_src);

  // ---- weight fold / pack ----
  k_wcomb<<<(256 * 256) / 256, 256, 0, stream>>>(Wv, Wl1, Wr1, WT1);
  k_bcomb<<<1, 256, 0, stream>>>(bv, Wl1, bl1, Wr1, br1, bc1);
  k_wpack<128, 64><<<(128 * 128 + 255) / 256, 256, 0, stream>>>(Wl2, bl2, Wr2, br2, WT2, bc2);
  k_wpack<64, 32><<<(64 * 64 + 255) / 256, 256, 0, stream>>>(Wl3, bl3, Wr3, br3, WT3, bc3);

  // ---- GAT layer 1 (K=256, N=256) ----
  k_gemm_bf16<256, 256, 128, true><<<dim3(MB128, 2), 256, 0, stream>>>(s_x, WT1, bc1, xlr,
                                                                       N_NODES);
  k_gat<128><<<(N_NODES * 16 + 255) / 256, 256, 0, stream>>>(xlr, row_ptr, csr_src, att1,
                                                             bias1, hbuf);

  // ---- GAT layer 2 (K=128, N=128) ----
  k_gemm_bf16<128, 128, 128, false><<<dim3(MB128, 1), 256, 0, stream>>>(hbuf, WT2, bc2, xlr,
                                                                        N_NODES);
  k_gat<64><<<(N_NODES * 8 + 255) / 256, 256, 0, stream>>>(xlr, row_ptr, csr_src, att2,
                                                           bias2, hbuf);

  // ---- GAT layer 3 (K=64, N=64) ----
  k_gemm_bf16<64, 64, 64, false><<<dim3(MB128, 1), 256, 0, stream>>>(hbuf, WT3, bc3, xlr,
                                                                     N_NODES);
  k_gat<32><<<(N_NODES * 4 + 255) / 256, 256, 0, stream>>>(xlr, row_ptr, csr_src, att3,
                                                           bias3, hbuf);

  // ---- pooling + root concat + lin ----
  hipMemsetAsync(pooled, 0, (NB * HC2C + NB) * sizeof(float), stream);
  k_pool<<<(N_NODES + 1023) / 1024, 256, 0, stream>>>(hbuf, batch, pooled, cnt);
  k_sx<<<(NB * HC2C + 255) / 256, 256, 0, stream>>>(hbuf, root, pooled, cnt, linW, linb, sx);

  // ---- info path ----
  k_info1<<<(NB * (IN_F - 2) + 255) / 256, 256, 0, stream>>>(s_x, root, c1w, c1b, info);
  k_info2<<<(HC1C * NB + 255) / 256, 256, 0, stream>>>(info, c2W, c2b, t1);
  k_info3<<<(NB * NB + 255) / 256, 256, 0, stream>>>(t1, c3W, c3b, t2);
  k_info4<<<(NB * HC2C + 255) / 256, 256, 0, stream>>>(t2, tt);

  // ---- attention combine + classifier ----
  k_final<<<1, NB, 0, stream>>>(sx, tt, aW1, ab1, aW2, mW1, mb1, mW2, mb2, out);
}

// Round 10
// 638.797 us; speedup vs baseline: 1.2433x; 1.0255x over previous
//
#include <hip/hip_runtime.h>
#include <hip/hip_bf16.h>
#include <math.h>

typedef unsigned short ushort_t;
typedef __attribute__((ext_vector_type(8))) short bfrag;   // 8 bf16 = 4 VGPRs
typedef __attribute__((ext_vector_type(4))) float ffrag;   // 4 fp32 acc

// ---------------- problem constants ----------------
constexpr int N_NODES = 100000;
constexpr int N_EDGES = 800000;
constexpr int NB      = 64;
constexpr int IN_F    = 256;
constexpr int HC1C    = 128;
constexpr int HC2C    = 32;
constexpr int SA_D    = 350;
constexpr float NEG   = 0.2f;

constexpr int SCAN_NBLK = (N_NODES + 255) / 256;  // 391
constexpr int MB128     = (N_NODES + 127) / 128;  // 782

// ---------------- workspace layout (float-sized slots) ----------------
constexpr size_t OFF_WT1    = 0;                                   // 256*256 ush
constexpr size_t OFF_WT2    = OFF_WT1 + 65536;
constexpr size_t OFF_WT3    = OFF_WT2 + 16384;
constexpr size_t OFF_BC1    = OFF_WT3 + 4096;                      // 256
constexpr size_t OFF_BC2    = OFF_BC1 + 256;                       // 128
constexpr size_t OFF_BC3    = OFF_BC2 + 128;                       // 64
constexpr size_t OFF_XLR    = OFF_BC3 + 64;                        // N*256 bf16
constexpr size_t OFF_H      = OFF_XLR + (size_t)N_NODES * 256;     // N*128 bf16
constexpr size_t OFF_DEG    = OFF_H + (size_t)N_NODES * 128;       // N ints
constexpr size_t OFF_ROWPTR = OFF_DEG + N_NODES;                   // N+1 ints
constexpr size_t OFF_CURSOR = OFF_ROWPTR + N_NODES + 1;            // N ints
constexpr size_t OFF_BLKS   = OFF_CURSOR + N_NODES;                // 512 ints
constexpr size_t OFF_BLKO   = OFF_BLKS + 512;                      // 512 ints
constexpr size_t OFF_CSRSRC = OFF_BLKO + 512;                      // E ints
constexpr size_t OFF_POOLED = OFF_CSRSRC + N_EDGES;                // 64*32
constexpr size_t OFF_CNT    = OFF_POOLED + NB * HC2C;              // 64
constexpr size_t WS_FLOATS  = OFF_CNT + NB;

// ---------------- bf16 helpers ----------------
__device__ __forceinline__ ushort_t f2bf(float f) {  // RNE
  union { float f; unsigned int u; } a;
  a.f = f;
  unsigned int r = a.u + 0x7FFFu + ((a.u >> 16) & 1u);
  return (ushort_t)(r >> 16);
}
__device__ __forceinline__ float bf2f(ushort_t h) {
  union { unsigned int u; float f; } a;
  a.u = ((unsigned int)h) << 16;
  return a.f;
}
__device__ __forceinline__ float2 bfp(unsigned int u) {
  float2 r;
  r.x = __uint_as_float(u << 16);
  r.y = __uint_as_float(u & 0xFFFF0000u);
  return r;
}
__device__ __forceinline__ unsigned int pack2(float a, float b) {
  unsigned int ua = __float_as_uint(a);
  ua += 0x7FFFu + ((ua >> 16) & 1u);
  unsigned int ub = __float_as_uint(b);
  ub += 0x7FFFu + ((ub >> 16) & 1u);
  return __builtin_amdgcn_perm(ub, ua, 0x07060302u);
}
__device__ __forceinline__ void unp8(uint4 u, float* x) {
  float2 p0 = bfp(u.x), p1 = bfp(u.y), p2 = bfp(u.z), p3 = bfp(u.w);
  x[0] = p0.x; x[1] = p0.y; x[2] = p1.x; x[3] = p1.y;
  x[4] = p2.x; x[5] = p2.y; x[6] = p3.x; x[7] = p3.y;
}

// ---------------- fused weight fold/pack (4 kernels -> 1) ----------------
__global__ void k_pack_all(const float* __restrict__ Wv, const float* __restrict__ bv,
                           const float* __restrict__ Wl1, const float* __restrict__ bl1,
                           const float* __restrict__ Wr1, const float* __restrict__ br1,
                           const float* __restrict__ Wl2, const float* __restrict__ bl2,
                           const float* __restrict__ Wr2, const float* __restrict__ br2,
                           const float* __restrict__ Wl3, const float* __restrict__ bl3,
                           const float* __restrict__ Wr3, const float* __restrict__ br3,
                           ushort_t* __restrict__ WT1, float* __restrict__ bc1,
                           ushort_t* __restrict__ WT2, float* __restrict__ bc2,
                           ushort_t* __restrict__ WT3, float* __restrict__ bc3) {
  int blk = blockIdx.x;
  int tid = threadIdx.x;
  if (blk < 256) {            // WT1 fold: (Wv@W{l,r}1)^T, 65536 elements
    int t = blk * 256 + tid;
    int n = t & 255, k = t >> 8;
    const float* Wx = (n < 128) ? Wl1 : Wr1;
    int j = n & 127;
    float a = 0.f;
    for (int kk = 0; kk < SA_D; ++kk) a += Wv[k * SA_D + kk] * Wx[kk * 128 + j];
    WT1[(size_t)n * 256 + k] = f2bf(a);
  } else if (blk == 256) {    // bc1
    int n = tid;
    const float* Wx = (n < 128) ? Wl1 : Wr1;
    const float* bx = (n < 128) ? bl1 : br1;
    int j = n & 127;
    float a = bx[j];
    for (int kk = 0; kk < SA_D; ++kk) a += bv[kk] * Wx[kk * 128 + j];
    bc1[n] = a;
  } else if (blk < 321) {     // WT2 transpose pack: 16384 elements
    int t = (blk - 257) * 256 + tid;
    int n = t & 127, k = t >> 7;
    if (t < 128) bc2[t] = (t < 64) ? bl2[t] : br2[t - 64];
    float v = (n < 64) ? Wl2[k * 64 + n] : Wr2[k * 64 + (n - 64)];
    WT2[(size_t)n * 128 + k] = f2bf(v);
  } else {                    // WT3 transpose pack: 4096 elements
    int t = (blk - 321) * 256 + tid;
    int n = t & 63, k = t >> 6;
    if (t < 64) bc3[t] = (t < 32) ? bl3[t] : br3[t - 32];
    float v = (n < 32) ? Wl3[k * 32 + n] : Wr3[k * 32 + (n - 32)];
    WT3[(size_t)n * 64 + k] = f2bf(v);
  }
}

// ---------------- CSR build ----------------
__global__ void k_hist(const int* __restrict__ dst, int* __restrict__ deg) {
  int e = blockIdx.x * blockDim.x + threadIdx.x;
  if (e < N_EDGES) atomicAdd(deg + dst[e], 1);
}

__global__ void k_scan_local(const int* __restrict__ deg, int* __restrict__ row_ptr,
                             int* __restrict__ blk_sum) {
  __shared__ int sh[256];
  int t = threadIdx.x;
  int i = blockIdx.x * 256 + t;
  int v = (i < N_NODES) ? deg[i] : 0;
  sh[t] = v;
  __syncthreads();
  for (int off = 1; off < 256; off <<= 1) {
    int add = (t >= off) ? sh[t - off] : 0;
    __syncthreads();
    sh[t] += add;
    __syncthreads();
  }
  if (i < N_NODES) row_ptr[i] = sh[t] - v;
  if (t == 255) blk_sum[blockIdx.x] = sh[255];
}

__global__ void k_scan_blk(const int* __restrict__ blk_sum, int* __restrict__ blk_off) {
  __shared__ int sh[512];
  int t = threadIdx.x;
  int v = (t < SCAN_NBLK) ? blk_sum[t] : 0;
  sh[t] = v;
  __syncthreads();
  for (int off = 1; off < 512; off <<= 1) {
    int add = (t >= off) ? sh[t - off] : 0;
    __syncthreads();
    sh[t] += add;
    __syncthreads();
  }
  blk_off[t] = sh[t] - v;
}

__global__ void k_scan_add(int* __restrict__ row_ptr, const int* __restrict__ blk_off,
                           int* __restrict__ cursor) {
  int i = blockIdx.x * blockDim.x + threadIdx.x;
  if (i < N_NODES) {
    int v = row_ptr[i] + blk_off[i >> 8];
    row_ptr[i] = v;
    cursor[i] = v;
  }
  if (i == 0) row_ptr[N_NODES] = N_EDGES;
}

__global__ void k_fill(const int* __restrict__ src, const int* __restrict__ dst,
                       int* __restrict__ cursor, int* __restrict__ csr_src) {
  int e = blockIdx.x * blockDim.x + threadIdx.x;
  if (e >= N_EDGES) return;
  int pos = atomicAdd(cursor + dst[e], 1);
  csr_src[pos] = src[e];
}

// ---------------- pure-bf16 MFMA GEMM, BK=32, single 20.5KB LDS buffer -------
// 6 blocks/CU (vs 4 at BK=64): more resident blocks stagger the barrier
// phases and raise the HBM duty cycle (r9: 1.9 TB/s, no pipe >27%).
template <int K, int NN, int BN, bool AF32>
__global__ __launch_bounds__(256) void k_gemm_bf16(const void* __restrict__ xin,
                                                   const ushort_t* __restrict__ WT,
                                                   const float* __restrict__ bc,
                                                   ushort_t* __restrict__ out, int M) {
  constexpr int BM    = 128;
  constexpr int BK    = 32;
  constexpr int LDA   = BK + 8;          // 40 ushorts = 80B rows
  constexpr int RT    = 4;
  constexpr int CT    = BN / 32;
  constexpr int NSTEP = K / BK;
  __shared__ ushort_t As[BM * LDA];
  __shared__ ushort_t Bs[BN * LDA];
  const int tid  = threadIdx.x;
  const int wave = tid >> 6;
  const int wrow = wave >> 1;
  const int wcol = wave & 1;
  const int lane = tid & 63;
  const int quad = lane >> 4;
  const int l16  = lane & 15;
  const int m0   = blockIdx.x * BM;
  const int n0   = blockIdx.y * BN;

  const int arow = tid >> 1;         // 2 threads per row, 16 k each
  const int aks  = (tid & 1) * 16;
  int gm = m0 + arow;
  if (gm >= M) gm = M - 1;

  ffrag acc[RT][CT];
#pragma unroll
  for (int rt = 0; rt < RT; ++rt)
#pragma unroll
    for (int ct = 0; ct < CT; ++ct) acc[rt][ct] = ffrag{0.f, 0.f, 0.f, 0.f};

  for (int i = 0; i < NSTEP; ++i) {
    const int k0 = i * BK;
    if (i) __syncthreads();
    // ---- stage A (128 x 32) ----
    if (AF32) {
      const float4* sp = (const float4*)((const float*)xin + (size_t)gm * K + k0 + aks);
      float4 f[4];
#pragma unroll
      for (int j = 0; j < 4; ++j) f[j] = sp[j];
      unsigned int d[8];
#pragma unroll
      for (int j = 0; j < 4; ++j) {
        d[2 * j]     = pack2(f[j].x, f[j].y);
        d[2 * j + 1] = pack2(f[j].z, f[j].w);
      }
      *(uint4*)&As[arow * LDA + aks]     = *(uint4*)&d[0];
      *(uint4*)&As[arow * LDA + aks + 8] = *(uint4*)&d[4];
    } else {
      const uint4* sp = (const uint4*)((const ushort_t*)xin + (size_t)gm * K + k0 + aks);
      uint4 u0 = sp[0], u1 = sp[1];
      *(uint4*)&As[arow * LDA + aks]     = u0;
      *(uint4*)&As[arow * LDA + aks + 8] = u1;
    }
    // ---- stage B (BN x 32) ----
    if (BN == 128) {
      int bn  = tid >> 1;
      int bks = (tid & 1) * 16;
      const ushort_t* gp = WT + (size_t)(n0 + bn) * K + k0 + bks;
      *(uint4*)&Bs[bn * LDA + bks]     = *(const uint4*)gp;
      *(uint4*)&Bs[bn * LDA + bks + 8] = *(const uint4*)(gp + 8);
    } else {  // BN == 64
      int bn  = tid >> 2;
      int bks = (tid & 3) * 8;
      *(uint4*)&Bs[bn * LDA + bks] = *(const uint4*)(WT + (size_t)(n0 + bn) * K + k0 + bks);
    }
    __syncthreads();
    // ---- compute ----
    bfrag a[RT], b[CT];
#pragma unroll
    for (int rt = 0; rt < RT; ++rt)
      a[rt] = *(const bfrag*)&As[(wrow * 64 + rt * 16 + l16) * LDA + quad * 8];
#pragma unroll
    for (int ct = 0; ct < CT; ++ct)
      b[ct] = *(const bfrag*)&Bs[(wcol * (BN / 2) + ct * 16 + l16) * LDA + quad * 8];
#pragma unroll
    for (int ct = 0; ct < CT; ++ct)
#pragma unroll
      for (int rt = 0; rt < RT; ++rt)
        acc[rt][ct] = __builtin_amdgcn_mfma_f32_16x16x32_bf16(a[rt], b[ct], acc[rt][ct], 0, 0, 0);
  }

#pragma unroll
  for (int rt = 0; rt < RT; ++rt)
#pragma unroll
    for (int ct = 0; ct < CT; ++ct) {
      int n = n0 + wcol * (BN / 2) + ct * 16 + l16;
      float b = bc[n];
#pragma unroll
      for (int r = 0; r < 4; ++r) {
        int m = m0 + wrow * 64 + rt * 16 + quad * 4 + r;
        if (m < M) out[(size_t)m * NN + n] = f2bf(acc[rt][ct][r] + b);
      }
    }
}

// ---------------- fused per-node GAT edge pass (bf16, 4-edge unrolled) -------
template <int C>
__global__ void k_gat(const ushort_t* __restrict__ xlr, const int* __restrict__ row_ptr,
                      const int* __restrict__ csr_src, const float* __restrict__ att,
                      const float* __restrict__ bias, ushort_t* __restrict__ h) {
  constexpr int G = C / 8;          // lanes per edge group, 8 channels each
  constexpr int RS = 2 * C;         // row stride in ushorts
  int t = blockIdx.x * blockDim.x + threadIdx.x;
  int d = t / G;
  int lane = t - d * G;
  if (d >= N_NODES) return;
  float xr[8], a[8];
  unp8(*(const uint4*)(xlr + (size_t)d * RS + C + lane * 8), xr);
  *(float4*)&a[0] = *(const float4*)(att + lane * 8);
  *(float4*)&a[4] = *(const float4*)(att + lane * 8 + 4);
  float acc[8];
#pragma unroll
  for (int j = 0; j < 8; ++j) acc[j] = 0.f;
  float den = 0.f;
  const int e0 = row_ptr[d], e1 = row_ptr[d + 1];
  int i = e0;
  for (; i + 4 <= e1; i += 4) {
    uint4 u[4];
#pragma unroll
    for (int q = 0; q < 4; ++q)
      u[q] = *(const uint4*)(xlr + (size_t)csr_src[i + q] * RS + lane * 8);
    float xl[4][8];
#pragma unroll
    for (int q = 0; q < 4; ++q) unp8(u[q], xl[q]);
    float p[4] = {0.f, 0.f, 0.f, 0.f};
#pragma unroll
    for (int j = 0; j < 8; ++j) {
#pragma unroll
      for (int q = 0; q < 4; ++q) {
        float v = xl[q][j] + xr[j];
        v = v > 0.f ? v : NEG * v;
        p[q] += a[j] * v;
      }
    }
#pragma unroll
    for (int off = G / 2; off > 0; off >>= 1) {
#pragma unroll
      for (int q = 0; q < 4; ++q) p[q] += __shfl_xor(p[q], off, 64);
    }
    float ex[4];
#pragma unroll
    for (int q = 0; q < 4; ++q) ex[q] = expf(p[q]);
    den += (ex[0] + ex[1]) + (ex[2] + ex[3]);
#pragma unroll
    for (int j = 0; j < 8; ++j)
      acc[j] += (ex[0] * xl[0][j] + ex[1] * xl[1][j]) + (ex[2] * xl[2][j] + ex[3] * xl[3][j]);
  }
  for (; i < e1; ++i) {
    int s = csr_src[i];
    float xl[8];
    unp8(*(const uint4*)(xlr + (size_t)s * RS + lane * 8), xl);
    float p = 0.f;
#pragma unroll
    for (int j = 0; j < 8; ++j) {
      float v = xl[j] + xr[j];
      v = v > 0.f ? v : NEG * v;
      p += a[j] * v;
    }
#pragma unroll
    for (int off = G / 2; off > 0; off >>= 1) p += __shfl_xor(p, off, 64);
    float ex = expf(p);
    den += ex;
#pragma unroll
    for (int j = 0; j < 8; ++j) acc[j] += ex * xl[j];
  }
  float inv = 1.f / fmaxf(den, 1e-16f);
  float o[8];
#pragma unroll
  for (int j = 0; j < 8; ++j)
    o[j] = fmaxf(acc[j] * inv + bias[lane * 8 + j], 0.f);
  uint4 pk;
  pk.x = pack2(o[0], o[1]);
  pk.y = pack2(o[2], o[3]);
  pk.z = pack2(o[4], o[5]);
  pk.w = pack2(o[6], o[7]);
  *(uint4*)(h + (size_t)d * C + lane * 8) = pk;
}

// ---------------- pooling: sorted-batch run-accumulate (bf16 h3) -------------
__global__ void k_pool(const ushort_t* __restrict__ h3, const int* __restrict__ batch,
                       float* __restrict__ pooled, float* __restrict__ cnt) {
  constexpr int NPB = 1024;
  constexpr int NPT = NPB / 8;
  int c = threadIdx.x & 31;
  int r = threadIdx.x >> 5;
  int base = blockIdx.x * NPB + r * NPT;
  if (base >= N_NODES) return;
  int end = base + NPT;
  if (end > N_NODES) end = N_NODES;
  int cur_b = batch[base];
  float acc = 0.f, count = 0.f;
  for (int n = base; n < end; ++n) {
    int b = batch[n];
    if (b != cur_b) {
      atomicAdd(pooled + cur_b * HC2C + c, acc);
      if (c == 0) atomicAdd(cnt + cur_b, count);
      cur_b = b;
      acc = 0.f;
      count = 0.f;
    }
    acc += bf2f(h3[(size_t)n * HC2C + c]);
    count += 1.f;
  }
  atomicAdd(pooled + cur_b * HC2C + c, acc);
  if (c == 0) atomicAdd(cnt + cur_b, count);
}

// ---------------- fused tail: sx + info path + attention + classifier -------
// One block per batch element (the whole tail is independent per b given
// pooled/cnt).  Replaces 6 kernels (k_sx, k_info1-4, k_final).
__global__ __launch_bounds__(256) void k_tail(
    const ushort_t* __restrict__ h3, const int* __restrict__ root,
    const float* __restrict__ pooled, const float* __restrict__ cnt,
    const float* __restrict__ linW, const float* __restrict__ linb,
    const float* __restrict__ X, const float* __restrict__ c1w,
    const float* __restrict__ c1b, const float* __restrict__ c2W,
    const float* __restrict__ c2b, const float* __restrict__ c3W,
    const float* __restrict__ c3b, const float* __restrict__ aW1,
    const float* __restrict__ ab1, const float* __restrict__ aW2,
    const float* __restrict__ mW1, const float* __restrict__ mb1,
    const float* __restrict__ mW2, const float* __restrict__ mb2,
    float* __restrict__ out) {
  constexpr int L = IN_F - 2;  // 254
  __shared__ float s_info[L];
  __shared__ float s_t1[HC1C];
  __shared__ float s_t2[HC1C / 2];
  __shared__ float s_e0[HC2C];  // sx
  __shared__ float s_e1[HC2C];  // tt
  const int b = blockIdx.x;
  const int tid = threadIdx.x;
  const int r = root[b];
  const float* xr = X + (size_t)r * IN_F;
  for (int i = tid; i < L; i += 256)
    s_info[i] = c1w[0] * xr[i] + c1w[1] * xr[i + 1] + c1w[2] * xr[i + 2] + c1b[0];
  __syncthreads();
  if (tid < HC1C) {
    float a = c2b[tid];
    for (int i = 0; i < L; ++i) a += c2W[tid * L + i] * s_info[i];
    s_t1[tid] = fmaxf(a, 0.f);
  }
  __syncthreads();
  if (tid < HC1C / 2) {
    float a = c3b[tid];
    for (int i = 0; i < HC1C; ++i) a += c3W[tid * HC1C + i] * s_t1[i];
    s_t2[tid] = fmaxf(a, 0.f);
  }
  __syncthreads();
  if (tid < HC2C) {
    float v = 0.5f * (s_t2[2 * tid] + s_t2[2 * tid + 1]);
    s_e1[tid] = fmaxf(v, 0.f);
  } else if (tid < 2 * HC2C) {
    int j = tid - HC2C;
    float inv = 1.f / fmaxf(cnt[b], 1.f);
    float a = linb[j];
    for (int c = 0; c < HC2C; ++c) a += bf2f(h3[(size_t)r * HC2C + c]) * linW[c * HC2C + j];
    for (int c = 0; c < HC2C; ++c) a += pooled[b * HC2C + c] * inv * linW[(HC2C + c) * HC2C + j];
    s_e0[j] = fmaxf(a, 0.f);
  }
  __syncthreads();
  if (tid == 0) {
    float w0 = 0.f, w1 = 0.f;
    for (int j = 0; j < 16; ++j) {
      float z0 = ab1[j], z1 = ab1[j];
      for (int c = 0; c < HC2C; ++c) {
        z0 += s_e0[c] * aW1[c * 16 + j];
        z1 += s_e1[c] * aW1[c * 16 + j];
      }
      w0 += tanhf(z0) * aW2[j];
      w1 += tanhf(z1) * aW2[j];
    }
    float mx = fmaxf(w0, w1);
    float x0 = expf(w0 - mx), x1 = expf(w1 - mx);
    float inv = 1.f / (x0 + x1);
    float b0 = x0 * inv, b1 = x1 * inv;
    float l0 = mb2[0], l1 = mb2[1];
    for (int j = 0; j < 16; ++j) {
      float z = mb1[j];
      for (int c = 0; c < HC2C; ++c) z += (b0 * s_e0[c] + b1 * s_e1[c]) * mW1[c * 16 + j];
      float tz = tanhf(z);
      l0 += tz * mW2[j * 2 + 0];
      l1 += tz * mW2[j * 2 + 1];
    }
    float m2 = fmaxf(l0, l1);
    float y0 = expf(l0 - m2), y1 = expf(l1 - m2);
    float is = 1.f / (y0 + y1);
    out[b * 2 + 0] = y0 * is;
    out[b * 2 + 1] = y1 * is;
  }
}

// ---------------- launcher ----------------
extern "C" void kernel_launch(void* const* d_in, const int* in_sizes, int n_in, void* d_out,
                              int out_size, void* d_ws, size_t ws_size, hipStream_t stream) {
  if (ws_size < WS_FLOATS * sizeof(float)) return;

  const float* s_x   = (const float*)d_in[0];
  const int*   edge  = (const int*)d_in[1];
  const int*   batch = (const int*)d_in[2];
  const int*   root  = (const int*)d_in[3];
  const float* Wv    = (const float*)d_in[8];
  const float* bv    = (const float*)d_in[9];
  const float* Wl1   = (const float*)d_in[10];
  const float* bl1   = (const float*)d_in[11];
  const float* Wr1   = (const float*)d_in[12];
  const float* br1   = (const float*)d_in[13];
  const float* att1  = (const float*)d_in[14];
  const float* bias1 = (const float*)d_in[15];
  const float* Wl2   = (const float*)d_in[16];
  const float* bl2   = (const float*)d_in[17];
  const float* Wr2   = (const float*)d_in[18];
  const float* br2   = (const float*)d_in[19];
  const float* att2  = (const float*)d_in[20];
  const float* bias2 = (const float*)d_in[21];
  const float* Wl3   = (const float*)d_in[22];
  const float* bl3   = (const float*)d_in[23];
  const float* Wr3   = (const float*)d_in[24];
  const float* br3   = (const float*)d_in[25];
  const float* att3  = (const float*)d_in[26];
  const float* bias3 = (const float*)d_in[27];
  const float* c1w   = (const float*)d_in[28];
  const float* c1b   = (const float*)d_in[29];
  const float* c2W   = (const float*)d_in[30];
  const float* c2b   = (const float*)d_in[31];
  const float* c3W   = (const float*)d_in[32];
  const float* c3b   = (const float*)d_in[33];
  const float* linW  = (const float*)d_in[34];
  const float* linb  = (const float*)d_in[35];
  const float* aW1   = (const float*)d_in[36];
  const float* ab1   = (const float*)d_in[37];
  const float* aW2   = (const float*)d_in[38];
  const float* mW1   = (const float*)d_in[39];
  const float* mb1   = (const float*)d_in[40];
  const float* mW2   = (const float*)d_in[41];
  const float* mb2   = (const float*)d_in[42];

  const int* src = edge;
  const int* dst = edge + N_EDGES;

  float*    ws      = (float*)d_ws;
  ushort_t* WT1     = (ushort_t*)(ws + OFF_WT1);
  ushort_t* WT2     = (ushort_t*)(ws + OFF_WT2);
  ushort_t* WT3     = (ushort_t*)(ws + OFF_WT3);
  float*    bc1     = ws + OFF_BC1;
  float*    bc2     = ws + OFF_BC2;
  float*    bc3     = ws + OFF_BC3;
  ushort_t* xlr     = (ushort_t*)(ws + OFF_XLR);
  ushort_t* hbuf    = (ushort_t*)(ws + OFF_H);
  int*      deg     = (int*)(ws + OFF_DEG);
  int*      row_ptr = (int*)(ws + OFF_ROWPTR);
  int*      cursor  = (int*)(ws + OFF_CURSOR);
  int*      blks    = (int*)(ws + OFF_BLKS);
  int*      blko    = (int*)(ws + OFF_BLKO);
  int*      csr_src = (int*)(ws + OFF_CSRSRC);
  float*    pooled  = ws + OFF_POOLED;
  float*    cnt     = ws + OFF_CNT;
  float*    out     = (float*)d_out;

  // ---- CSR build (by dst) ----
  hipMemsetAsync(deg, 0, N_NODES * sizeof(int), stream);
  k_hist<<<(N_EDGES + 255) / 256, 256, 0, stream>>>(dst, deg);
  k_scan_local<<<SCAN_NBLK, 256, 0, stream>>>(deg, row_ptr, blks);
  k_scan_blk<<<1, 512, 0, stream>>>(blks, blko);
  k_scan_add<<<SCAN_NBLK, 256, 0, stream>>>(row_ptr, blko, cursor);
  k_fill<<<(N_EDGES + 255) / 256, 256, 0, stream>>>(src, dst, cursor, csr_src);

  // ---- fused weight fold / pack ----
  k_pack_all<<<337, 256, 0, stream>>>(Wv, bv, Wl1, bl1, Wr1, br1, Wl2, bl2, Wr2, br2, Wl3,
                                      bl3, Wr3, br3, WT1, bc1, WT2, bc2, WT3, bc3);

  // ---- GAT layer 1 (K=256, N=256) ----
  k_gemm_bf16<256, 256, 128, true><<<dim3(MB128, 2), 256, 0, stream>>>(s_x, WT1, bc1, xlr,
                                                                       N_NODES);
  k_gat<128><<<(N_NODES * 16 + 255) / 256, 256, 0, stream>>>(xlr, row_ptr, csr_src, att1,
                                                             bias1, hbuf);

  // ---- GAT layer 2 (K=128, N=128) ----
  k_gemm_bf16<128, 128, 128, false><<<dim3(MB128, 1), 256, 0, stream>>>(hbuf, WT2, bc2, xlr,
                                                                        N_NODES);
  k_gat<64><<<(N_NODES * 8 + 255) / 256, 256, 0, stream>>>(xlr, row_ptr, csr_src, att2,
                                                           bias2, hbuf);

  // ---- GAT layer 3 (K=64, N=64) ----
  k_gemm_bf16<64, 64, 64, false><<<dim3(MB128, 1), 256, 0, stream>>>(hbuf, WT3, bc3, xlr,
                                                                     N_NODES);
  k_gat<32><<<(N_NODES * 4 + 255) / 256, 256, 0, stream>>>(xlr, row_ptr, csr_src, att3,
                                                           bias3, hbuf);

  // ---- pooling + fused tail ----
  hipMemsetAsync(pooled, 0, (NB * HC2C + NB) * sizeof(float), stream);
  k_pool<<<(N_NODES + 1023) / 1024, 256, 0, stream>>>(hbuf, batch, pooled, cnt);
  k_tail<<<NB, 256, 0, stream>>>(hbuf, root, pooled, cnt, linW, linb, s_x, c1w, c1b, c2W,
                                 c2b, c3W, c3b, aW1, ab1, aW2, mW1, mb1, mW2, mb2, out);
}

// Round 11
// 629.404 us; speedup vs baseline: 1.2618x; 1.0149x over previous
//
#include <hip/hip_runtime.h>
#include <hip/hip_bf16.h>
#include <math.h>

typedef unsigned short ushort_t;
typedef __attribute__((ext_vector_type(8))) short bfrag;   // 8 bf16 = 4 VGPRs
typedef __attribute__((ext_vector_type(4))) float ffrag;   // 4 fp32 acc

// ---------------- problem constants ----------------
constexpr int N_NODES = 100000;
constexpr int N_EDGES = 800000;
constexpr int NB      = 64;
constexpr int IN_F    = 256;
constexpr int HC1C    = 128;
constexpr int HC2C    = 32;
constexpr int SA_D    = 350;
constexpr float NEG   = 0.2f;

constexpr int SCAN_NBLK = (N_NODES + 255) / 256;  // 391
constexpr int MB64      = (N_NODES + 63) / 64;    // 1563

// ---------------- workspace layout (float-sized slots) ----------------
constexpr size_t OFF_WT1    = 0;                                   // 256*256 ush
constexpr size_t OFF_WT2    = OFF_WT1 + 65536;
constexpr size_t OFF_WT3    = OFF_WT2 + 16384;
constexpr size_t OFF_BC1    = OFF_WT3 + 4096;                      // 256
constexpr size_t OFF_BC2    = OFF_BC1 + 256;                       // 128
constexpr size_t OFF_BC3    = OFF_BC2 + 128;                       // 64
constexpr size_t OFF_XLR    = OFF_BC3 + 64;                        // N*256 bf16
constexpr size_t OFF_H      = OFF_XLR + (size_t)N_NODES * 256;     // N*128 bf16
constexpr size_t OFF_DEG    = OFF_H + (size_t)N_NODES * 128;       // N ints
constexpr size_t OFF_ROWPTR = OFF_DEG + N_NODES;                   // N+1 ints
constexpr size_t OFF_CURSOR = OFF_ROWPTR + N_NODES + 1;            // N ints
constexpr size_t OFF_BLKS   = OFF_CURSOR + N_NODES;                // 512 ints
constexpr size_t OFF_BLKO   = OFF_BLKS + 512;                      // 512 ints
constexpr size_t OFF_CSRSRC = OFF_BLKO + 512;                      // E ints
constexpr size_t OFF_POOLED = OFF_CSRSRC + N_EDGES;                // 64*32
constexpr size_t OFF_CNT    = OFF_POOLED + NB * HC2C;              // 64
constexpr size_t WS_FLOATS  = OFF_CNT + NB;

// ---------------- bf16 helpers ----------------
__device__ __forceinline__ ushort_t f2bf(float f) {  // RNE
  union { float f; unsigned int u; } a;
  a.f = f;
  unsigned int r = a.u + 0x7FFFu + ((a.u >> 16) & 1u);
  return (ushort_t)(r >> 16);
}
__device__ __forceinline__ float bf2f(ushort_t h) {
  union { unsigned int u; float f; } a;
  a.u = ((unsigned int)h) << 16;
  return a.f;
}
__device__ __forceinline__ float2 bfp(unsigned int u) {
  float2 r;
  r.x = __uint_as_float(u << 16);
  r.y = __uint_as_float(u & 0xFFFF0000u);
  return r;
}
__device__ __forceinline__ unsigned int pack2(float a, float b) {
  unsigned int ua = __float_as_uint(a);
  ua += 0x7FFFu + ((ua >> 16) & 1u);
  unsigned int ub = __float_as_uint(b);
  ub += 0x7FFFu + ((ub >> 16) & 1u);
  return __builtin_amdgcn_perm(ub, ua, 0x07060302u);
}
__device__ __forceinline__ void unp8(uint4 u, float* x) {
  float2 p0 = bfp(u.x), p1 = bfp(u.y), p2 = bfp(u.z), p3 = bfp(u.w);
  x[0] = p0.x; x[1] = p0.y; x[2] = p1.x; x[3] = p1.y;
  x[4] = p2.x; x[5] = p2.y; x[6] = p3.x; x[7] = p3.y;
}

// ---------------- fused weight fold/pack ----------------
__global__ void k_pack_all(const float* __restrict__ Wv, const float* __restrict__ bv,
                           const float* __restrict__ Wl1, const float* __restrict__ bl1,
                           const float* __restrict__ Wr1, const float* __restrict__ br1,
                           const float* __restrict__ Wl2, const float* __restrict__ bl2,
                           const float* __restrict__ Wr2, const float* __restrict__ br2,
                           const float* __restrict__ Wl3, const float* __restrict__ bl3,
                           const float* __restrict__ Wr3, const float* __restrict__ br3,
                           ushort_t* __restrict__ WT1, float* __restrict__ bc1,
                           ushort_t* __restrict__ WT2, float* __restrict__ bc2,
                           ushort_t* __restrict__ WT3, float* __restrict__ bc3) {
  int blk = blockIdx.x;
  int tid = threadIdx.x;
  if (blk < 256) {            // WT1 fold: (Wv@W{l,r}1)^T
    int t = blk * 256 + tid;
    int n = t & 255, k = t >> 8;
    const float* Wx = (n < 128) ? Wl1 : Wr1;
    int j = n & 127;
    float a = 0.f;
    for (int kk = 0; kk < SA_D; ++kk) a += Wv[k * SA_D + kk] * Wx[kk * 128 + j];
    WT1[(size_t)n * 256 + k] = f2bf(a);
  } else if (blk == 256) {    // bc1
    int n = tid;
    const float* Wx = (n < 128) ? Wl1 : Wr1;
    const float* bx = (n < 128) ? bl1 : br1;
    int j = n & 127;
    float a = bx[j];
    for (int kk = 0; kk < SA_D; ++kk) a += bv[kk] * Wx[kk * 128 + j];
    bc1[n] = a;
  } else if (blk < 321) {     // WT2 transpose pack
    int t = (blk - 257) * 256 + tid;
    int n = t & 127, k = t >> 7;
    if (t < 128) bc2[t] = (t < 64) ? bl2[t] : br2[t - 64];
    float v = (n < 64) ? Wl2[k * 64 + n] : Wr2[k * 64 + (n - 64)];
    WT2[(size_t)n * 128 + k] = f2bf(v);
  } else {                    // WT3 transpose pack
    int t = (blk - 321) * 256 + tid;
    int n = t & 63, k = t >> 6;
    if (t < 64) bc3[t] = (t < 32) ? bl3[t] : br3[t - 32];
    float v = (n < 32) ? Wl3[k * 32 + n] : Wr3[k * 32 + (n - 32)];
    WT3[(size_t)n * 64 + k] = f2bf(v);
  }
}

// ---------------- CSR build ----------------
__global__ void k_hist(const int* __restrict__ dst, int* __restrict__ deg) {
  int e = blockIdx.x * blockDim.x + threadIdx.x;
  if (e < N_EDGES) atomicAdd(deg + dst[e], 1);
}

__global__ void k_scan_local(const int* __restrict__ deg, int* __restrict__ row_ptr,
                             int* __restrict__ blk_sum) {
  __shared__ int sh[256];
  int t = threadIdx.x;
  int i = blockIdx.x * 256 + t;
  int v = (i < N_NODES) ? deg[i] : 0;
  sh[t] = v;
  __syncthreads();
  for (int off = 1; off < 256; off <<= 1) {
    int add = (t >= off) ? sh[t - off] : 0;
    __syncthreads();
    sh[t] += add;
    __syncthreads();
  }
  if (i < N_NODES) row_ptr[i] = sh[t] - v;
  if (t == 255) blk_sum[blockIdx.x] = sh[255];
}

__global__ void k_scan_blk(const int* __restrict__ blk_sum, int* __restrict__ blk_off) {
  __shared__ int sh[512];
  int t = threadIdx.x;
  int v = (t < SCAN_NBLK) ? blk_sum[t] : 0;
  sh[t] = v;
  __syncthreads();
  for (int off = 1; off < 512; off <<= 1) {
    int add = (t >= off) ? sh[t - off] : 0;
    __syncthreads();
    sh[t] += add;
    __syncthreads();
  }
  blk_off[t] = sh[t] - v;
}

__global__ void k_scan_add(int* __restrict__ row_ptr, const int* __restrict__ blk_off,
                           int* __restrict__ cursor) {
  int i = blockIdx.x * blockDim.x + threadIdx.x;
  if (i < N_NODES) {
    int v = row_ptr[i] + blk_off[i >> 8];
    row_ptr[i] = v;
    cursor[i] = v;
  }
  if (i == 0) row_ptr[N_NODES] = N_EDGES;
}

__global__ void k_fill(const int* __restrict__ src, const int* __restrict__ dst,
                       int* __restrict__ cursor, int* __restrict__ csr_src) {
  int e = blockIdx.x * blockDim.x + threadIdx.x;
  if (e >= N_EDGES) return;
  int pos = atomicAdd(cursor + dst[e], 1);
  csr_src[pos] = src[e];
}

// ---------------- pure-bf16 MFMA GEMM, BM=64 / RT=2 ----------------
// acc file quartered vs r10 (8 ffrag = 32 AGPR, ~95 unified regs -> 5
// waves/SIMD) and LDS 15KB -> ~5 resident blocks/CU (r10: 3, occupancy
// stuck at 26%).  More out-of-phase blocks = higher HBM duty cycle for a
// latency-stagger-bound kernel.  Same numerics as r10 (same BK order).
template <int K, int NN, int BN, bool AF32>
__global__ __launch_bounds__(256) void k_gemm_bf16(const void* __restrict__ xin,
                                                   const ushort_t* __restrict__ WT,
                                                   const float* __restrict__ bc,
                                                   ushort_t* __restrict__ out, int M) {
  constexpr int BM    = 64;
  constexpr int BK    = 32;
  constexpr int LDA   = BK + 8;          // 40 ushorts = 80B rows
  constexpr int RT    = 2;
  constexpr int CT    = BN / 32;
  constexpr int NSTEP = K / BK;
  __shared__ ushort_t As[BM * LDA];
  __shared__ ushort_t Bs[BN * LDA];
  const int tid  = threadIdx.x;
  const int wave = tid >> 6;
  const int wrow = wave >> 1;
  const int wcol = wave & 1;
  const int lane = tid & 63;
  const int quad = lane >> 4;
  const int l16  = lane & 15;
  const int m0   = blockIdx.x * BM;
  const int n0   = blockIdx.y * BN;

  const int arow = tid >> 2;         // 4 threads per row, 8 k each
  const int aks  = (tid & 3) * 8;
  int gm = m0 + arow;
  if (gm >= M) gm = M - 1;

  ffrag acc[RT][CT];
#pragma unroll
  for (int rt = 0; rt < RT; ++rt)
#pragma unroll
    for (int ct = 0; ct < CT; ++ct) acc[rt][ct] = ffrag{0.f, 0.f, 0.f, 0.f};

  for (int i = 0; i < NSTEP; ++i) {
    const int k0 = i * BK;
    if (i) __syncthreads();
    // ---- stage A (64 x 32): thread owns 8 k-elems ----
    if (AF32) {
      const float4* sp = (const float4*)((const float*)xin + (size_t)gm * K + k0 + aks);
      float4 f0 = sp[0], f1 = sp[1];
      unsigned int d[4];
      d[0] = pack2(f0.x, f0.y);
      d[1] = pack2(f0.z, f0.w);
      d[2] = pack2(f1.x, f1.y);
      d[3] = pack2(f1.z, f1.w);
      *(uint4*)&As[arow * LDA + aks] = *(uint4*)&d[0];
    } else {
      *(uint4*)&As[arow * LDA + aks] =
          *(const uint4*)((const ushort_t*)xin + (size_t)gm * K + k0 + aks);
    }
    // ---- stage B (BN x 32) ----
    if (BN == 128) {
      int bn  = tid >> 1;
      int bks = (tid & 1) * 16;
      const ushort_t* gp = WT + (size_t)(n0 + bn) * K + k0 + bks;
      *(uint4*)&Bs[bn * LDA + bks]     = *(const uint4*)gp;
      *(uint4*)&Bs[bn * LDA + bks + 8] = *(const uint4*)(gp + 8);
    } else {  // BN == 64
      int bn  = tid >> 2;
      int bks = (tid & 3) * 8;
      *(uint4*)&Bs[bn * LDA + bks] = *(const uint4*)(WT + (size_t)(n0 + bn) * K + k0 + bks);
    }
    __syncthreads();
    // ---- compute ----
    bfrag a[RT], b[CT];
#pragma unroll
    for (int rt = 0; rt < RT; ++rt)
      a[rt] = *(const bfrag*)&As[(wrow * 32 + rt * 16 + l16) * LDA + quad * 8];
#pragma unroll
    for (int ct = 0; ct < CT; ++ct)
      b[ct] = *(const bfrag*)&Bs[(wcol * (BN / 2) + ct * 16 + l16) * LDA + quad * 8];
#pragma unroll
    for (int ct = 0; ct < CT; ++ct)
#pragma unroll
      for (int rt = 0; rt < RT; ++rt)
        acc[rt][ct] = __builtin_amdgcn_mfma_f32_16x16x32_bf16(a[rt], b[ct], acc[rt][ct], 0, 0, 0);
  }

#pragma unroll
  for (int rt = 0; rt < RT; ++rt)
#pragma unroll
    for (int ct = 0; ct < CT; ++ct) {
      int n = n0 + wcol * (BN / 2) + ct * 16 + l16;
      float b = bc[n];
#pragma unroll
      for (int r = 0; r < 4; ++r) {
        int m = m0 + wrow * 32 + rt * 16 + quad * 4 + r;
        if (m < M) out[(size_t)m * NN + n] = f2bf(acc[rt][ct][r] + b);
      }
    }
}

// ---------------- fused per-node GAT edge pass (bf16, 4-edge unrolled) -------
template <int C>
__global__ void k_gat(const ushort_t* __restrict__ xlr, const int* __restrict__ row_ptr,
                      const int* __restrict__ csr_src, const float* __restrict__ att,
                      const float* __restrict__ bias, ushort_t* __restrict__ h) {
  constexpr int G = C / 8;          // lanes per edge group, 8 channels each
  constexpr int RS = 2 * C;         // row stride in ushorts
  int t = blockIdx.x * blockDim.x + threadIdx.x;
  int d = t / G;
  int lane = t - d * G;
  if (d >= N_NODES) return;
  float xr[8], a[8];
  unp8(*(const uint4*)(xlr + (size_t)d * RS + C + lane * 8), xr);
  *(float4*)&a[0] = *(const float4*)(att + lane * 8);
  *(float4*)&a[4] = *(const float4*)(att + lane * 8 + 4);
  float acc[8];
#pragma unroll
  for (int j = 0; j < 8; ++j) acc[j] = 0.f;
  float den = 0.f;
  const int e0 = row_ptr[d], e1 = row_ptr[d + 1];
  int i = e0;
  for (; i + 4 <= e1; i += 4) {
    uint4 u[4];
#pragma unroll
    for (int q = 0; q < 4; ++q)
      u[q] = *(const uint4*)(xlr + (size_t)csr_src[i + q] * RS + lane * 8);
    float xl[4][8];
#pragma unroll
    for (int q = 0; q < 4; ++q) unp8(u[q], xl[q]);
    float p[4] = {0.f, 0.f, 0.f, 0.f};
#pragma unroll
    for (int j = 0; j < 8; ++j) {
#pragma unroll
      for (int q = 0; q < 4; ++q) {
        float v = xl[q][j] + xr[j];
        v = v > 0.f ? v : NEG * v;
        p[q] += a[j] * v;
      }
    }
#pragma unroll
    for (int off = G / 2; off > 0; off >>= 1) {
#pragma unroll
      for (int q = 0; q < 4; ++q) p[q] += __shfl_xor(p[q], off, 64);
    }
    float ex[4];
#pragma unroll
    for (int q = 0; q < 4; ++q) ex[q] = expf(p[q]);
    den += (ex[0] + ex[1]) + (ex[2] + ex[3]);
#pragma unroll
    for (int j = 0; j < 8; ++j)
      acc[j] += (ex[0] * xl[0][j] + ex[1] * xl[1][j]) + (ex[2] * xl[2][j] + ex[3] * xl[3][j]);
  }
  for (; i < e1; ++i) {
    int s = csr_src[i];
    float xl[8];
    unp8(*(const uint4*)(xlr + (size_t)s * RS + lane * 8), xl);
    float p = 0.f;
#pragma unroll
    for (int j = 0; j < 8; ++j) {
      float v = xl[j] + xr[j];
      v = v > 0.f ? v : NEG * v;
      p += a[j] * v;
    }
#pragma unroll
    for (int off = G / 2; off > 0; off >>= 1) p += __shfl_xor(p, off, 64);
    float ex = expf(p);
    den += ex;
#pragma unroll
    for (int j = 0; j < 8; ++j) acc[j] += ex * xl[j];
  }
  float inv = 1.f / fmaxf(den, 1e-16f);
  float o[8];
#pragma unroll
  for (int j = 0; j < 8; ++j)
    o[j] = fmaxf(acc[j] * inv + bias[lane * 8 + j], 0.f);
  uint4 pk;
  pk.x = pack2(o[0], o[1]);
  pk.y = pack2(o[2], o[3]);
  pk.z = pack2(o[4], o[5]);
  pk.w = pack2(o[6], o[7]);
  *(uint4*)(h + (size_t)d * C + lane * 8) = pk;
}

// ---------------- pooling: sorted-batch run-accumulate (bf16 h3) -------------
__global__ void k_pool(const ushort_t* __restrict__ h3, const int* __restrict__ batch,
                       float* __restrict__ pooled, float* __restrict__ cnt) {
  constexpr int NPB = 1024;
  constexpr int NPT = NPB / 8;
  int c = threadIdx.x & 31;
  int r = threadIdx.x >> 5;
  int base = blockIdx.x * NPB + r * NPT;
  if (base >= N_NODES) return;
  int end = base + NPT;
  if (end > N_NODES) end = N_NODES;
  int cur_b = batch[base];
  float acc = 0.f, count = 0.f;
  for (int n = base; n < end; ++n) {
    int b = batch[n];
    if (b != cur_b) {
      atomicAdd(pooled + cur_b * HC2C + c, acc);
      if (c == 0) atomicAdd(cnt + cur_b, count);
      cur_b = b;
      acc = 0.f;
      count = 0.f;
    }
    acc += bf2f(h3[(size_t)n * HC2C + c]);
    count += 1.f;
  }
  atomicAdd(pooled + cur_b * HC2C + c, acc);
  if (c == 0) atomicAdd(cnt + cur_b, count);
}

// ---------------- fused tail ----------------
__global__ __launch_bounds__(256) void k_tail(
    const ushort_t* __restrict__ h3, const int* __restrict__ root,
    const float* __restrict__ pooled, const float* __restrict__ cnt,
    const float* __restrict__ linW, const float* __restrict__ linb,
    const float* __restrict__ X, const float* __restrict__ c1w,
    const float* __restrict__ c1b, const float* __restrict__ c2W,
    const float* __restrict__ c2b, const float* __restrict__ c3W,
    const float* __restrict__ c3b, const float* __restrict__ aW1,
    const float* __restrict__ ab1, const float* __restrict__ aW2,
    const float* __restrict__ mW1, const float* __restrict__ mb1,
    const float* __restrict__ mW2, const float* __restrict__ mb2,
    float* __restrict__ out) {
  constexpr int L = IN_F - 2;  // 254
  __shared__ float s_info[L];
  __shared__ float s_t1[HC1C];
  __shared__ float s_t2[HC1C / 2];
  __shared__ float s_e0[HC2C];  // sx
  __shared__ float s_e1[HC2C];  // tt
  const int b = blockIdx.x;
  const int tid = threadIdx.x;
  const int r = root[b];
  const float* xr = X + (size_t)r * IN_F;
  for (int i = tid; i < L; i += 256)
    s_info[i] = c1w[0] * xr[i] + c1w[1] * xr[i + 1] + c1w[2] * xr[i + 2] + c1b[0];
  __syncthreads();
  if (tid < HC1C) {
    float a = c2b[tid];
    for (int i = 0; i < L; ++i) a += c2W[tid * L + i] * s_info[i];
    s_t1[tid] = fmaxf(a, 0.f);
  }
  __syncthreads();
  if (tid < HC1C / 2) {
    float a = c3b[tid];
    for (int i = 0; i < HC1C; ++i) a += c3W[tid * HC1C + i] * s_t1[i];
    s_t2[tid] = fmaxf(a, 0.f);
  }
  __syncthreads();
  if (tid < HC2C) {
    float v = 0.5f * (s_t2[2 * tid] + s_t2[2 * tid + 1]);
    s_e1[tid] = fmaxf(v, 0.f);
  } else if (tid < 2 * HC2C) {
    int j = tid - HC2C;
    float inv = 1.f / fmaxf(cnt[b], 1.f);
    float a = linb[j];
    for (int c = 0; c < HC2C; ++c) a += bf2f(h3[(size_t)r * HC2C + c]) * linW[c * HC2C + j];
    for (int c = 0; c < HC2C; ++c) a += pooled[b * HC2C + c] * inv * linW[(HC2C + c) * HC2C + j];
    s_e0[j] = fmaxf(a, 0.f);
  }
  __syncthreads();
  if (tid == 0) {
    float w0 = 0.f, w1 = 0.f;
    for (int j = 0; j < 16; ++j) {
      float z0 = ab1[j], z1 = ab1[j];
      for (int c = 0; c < HC2C; ++c) {
        z0 += s_e0[c] * aW1[c * 16 + j];
        z1 += s_e1[c] * aW1[c * 16 + j];
      }
      w0 += tanhf(z0) * aW2[j];
      w1 += tanhf(z1) * aW2[j];
    }
    float mx = fmaxf(w0, w1);
    float x0 = expf(w0 - mx), x1 = expf(w1 - mx);
    float inv = 1.f / (x0 + x1);
    float b0 = x0 * inv, b1 = x1 * inv;
    float l0 = mb2[0], l1 = mb2[1];
    for (int j = 0; j < 16; ++j) {
      float z = mb1[j];
      for (int c = 0; c < HC2C; ++c) z += (b0 * s_e0[c] + b1 * s_e1[c]) * mW1[c * 16 + j];
      float tz = tanhf(z);
      l0 += tz * mW2[j * 2 + 0];
      l1 += tz * mW2[j * 2 + 1];
    }
    float m2 = fmaxf(l0, l1);
    float y0 = expf(l0 - m2), y1 = expf(l1 - m2);
    float is = 1.f / (y0 + y1);
    out[b * 2 + 0] = y0 * is;
    out[b * 2 + 1] = y1 * is;
  }
}

// ---------------- launcher ----------------
extern "C" void kernel_launch(void* const* d_in, const int* in_sizes, int n_in, void* d_out,
                              int out_size, void* d_ws, size_t ws_size, hipStream_t stream) {
  if (ws_size < WS_FLOATS * sizeof(float)) return;

  const float* s_x   = (const float*)d_in[0];
  const int*   edge  = (const int*)d_in[1];
  const int*   batch = (const int*)d_in[2];
  const int*   root  = (const int*)d_in[3];
  const float* Wv    = (const float*)d_in[8];
  const float* bv    = (const float*)d_in[9];
  const float* Wl1   = (const float*)d_in[10];
  const float* bl1   = (const float*)d_in[11];
  const float* Wr1   = (const float*)d_in[12];
  const float* br1   = (const float*)d_in[13];
  const float* att1  = (const float*)d_in[14];
  const float* bias1 = (const float*)d_in[15];
  const float* Wl2   = (const float*)d_in[16];
  const float* bl2   = (const float*)d_in[17];
  const float* Wr2   = (const float*)d_in[18];
  const float* br2   = (const float*)d_in[19];
  const float* att2  = (const float*)d_in[20];
  const float* bias2 = (const float*)d_in[21];
  const float* Wl3   = (const float*)d_in[22];
  const float* bl3   = (const float*)d_in[23];
  const float* Wr3   = (const float*)d_in[24];
  const float* br3   = (const float*)d_in[25];
  const float* att3  = (const float*)d_in[26];
  const float* bias3 = (const float*)d_in[27];
  const float* c1w   = (const float*)d_in[28];
  const float* c1b   = (const float*)d_in[29];
  const float* c2W   = (const float*)d_in[30];
  const float* c2b   = (const float*)d_in[31];
  const float* c3W   = (const float*)d_in[32];
  const float* c3b   = (const float*)d_in[33];
  const float* linW  = (const float*)d_in[34];
  const float* linb  = (const float*)d_in[35];
  const float* aW1   = (const float*)d_in[36];
  const float* ab1   = (const float*)d_in[37];
  const float* aW2   = (const float*)d_in[38];
  const float* mW1   = (const float*)d_in[39];
  const float* mb1   = (const float*)d_in[40];
  const float* mW2   = (const float*)d_in[41];
  const float* mb2   = (const float*)d_in[42];

  const int* src = edge;
  const int* dst = edge + N_EDGES;

  float*    ws      = (float*)d_ws;
  ushort_t* WT1     = (ushort_t*)(ws + OFF_WT1);
  ushort_t* WT2     = (ushort_t*)(ws + OFF_WT2);
  ushort_t* WT3     = (ushort_t*)(ws + OFF_WT3);
  float*    bc1     = ws + OFF_BC1;
  float*    bc2     = ws + OFF_BC2;
  float*    bc3     = ws + OFF_BC3;
  ushort_t* xlr     = (ushort_t*)(ws + OFF_XLR);
  ushort_t* hbuf    = (ushort_t*)(ws + OFF_H);
  int*      deg     = (int*)(ws + OFF_DEG);
  int*      row_ptr = (int*)(ws + OFF_ROWPTR);
  int*      cursor  = (int*)(ws + OFF_CURSOR);
  int*      blks    = (int*)(ws + OFF_BLKS);
  int*      blko    = (int*)(ws + OFF_BLKO);
  int*      csr_src = (int*)(ws + OFF_CSRSRC);
  float*    pooled  = ws + OFF_POOLED;
  float*    cnt     = ws + OFF_CNT;
  float*    out     = (float*)d_out;

  // ---- CSR build (by dst) ----
  hipMemsetAsync(deg, 0, N_NODES * sizeof(int), stream);
  k_hist<<<(N_EDGES + 255) / 256, 256, 0, stream>>>(dst, deg);
  k_scan_local<<<SCAN_NBLK, 256, 0, stream>>>(deg, row_ptr, blks);
  k_scan_blk<<<1, 512, 0, stream>>>(blks, blko);
  k_scan_add<<<SCAN_NBLK, 256, 0, stream>>>(row_ptr, blko, cursor);
  k_fill<<<(N_EDGES + 255) / 256, 256, 0, stream>>>(src, dst, cursor, csr_src);

  // ---- fused weight fold / pack ----
  k_pack_all<<<337, 256, 0, stream>>>(Wv, bv, Wl1, bl1, Wr1, br1, Wl2, bl2, Wr2, br2, Wl3,
                                      bl3, Wr3, br3, WT1, bc1, WT2, bc2, WT3, bc3);

  // ---- GAT layer 1 (K=256, N=256) ----
  k_gemm_bf16<256, 256, 128, true><<<dim3(MB64, 2), 256, 0, stream>>>(s_x, WT1, bc1, xlr,
                                                                      N_NODES);
  k_gat<128><<<(N_NODES * 16 + 255) / 256, 256, 0, stream>>>(xlr, row_ptr, csr_src, att1,
                                                             bias1, hbuf);

  // ---- GAT layer 2 (K=128, N=128) ----
  k_gemm_bf16<128, 128, 128, false><<<dim3(MB64, 1), 256, 0, stream>>>(hbuf, WT2, bc2, xlr,
                                                                       N_NODES);
  k_gat<64><<<(N_NODES * 8 + 255) / 256, 256, 0, stream>>>(xlr, row_ptr, csr_src, att2,
                                                           bias2, hbuf);

  // ---- GAT layer 3 (K=64, N=64) ----
  k_gemm_bf16<64, 64, 64, false><<<dim3(MB64, 1), 256, 0, stream>>>(hbuf, WT3, bc3, xlr,
                                                                    N_NODES);
  k_gat<32><<<(N_NODES * 4 + 255) / 256, 256, 0, stream>>>(xlr, row_ptr, csr_src, att3,
                                                           bias3, hbuf);

  // ---- pooling + fused tail ----
  hipMemsetAsync(pooled, 0, (NB * HC2C + NB) * sizeof(float), stream);
  k_pool<<<(N_NODES + 1023) / 1024, 256, 0, stream>>>(hbuf, batch, pooled, cnt);
  k_tail<<<NB, 256, 0, stream>>>(hbuf, root, pooled, cnt, linW, linb, s_x, c1w, c1b, c2W,
                                 c2b, c3W, c3b, aW1, ab1, aW2, mW1, mb1, mW2, mb2, out);
}